// Round 1
// baseline (1544.085 us; speedup 1.0000x reference)
//
#include <hip/hip_runtime.h>
#include <cstddef>

// Problem constants
constexpr int CB  = 4;
constexpr int CC  = 192;
constexpr int CH  = 64;
constexpr int CW  = 64;
constexpr int CL  = CH * CW;        // 4096
constexpr int DIN = 384;
constexpr int NST = 16;
constexpr int DTR = 12;

// Workspace layout (in floats)
constexpr int WS_PART  = 0;                         // 512
constexpr int WS_STAT  = 512;                       // 8
constexpr int WS_WTIN  = 1024;                      // 192*768 = 147456
constexpr int WS_WTXP  = WS_WTIN + 192 * 768;       // 384*44  = 16896
constexpr int WS_WTDT  = WS_WTXP + 384 * 44;        // 12*384  = 4608
constexpr int WS_WTOUT = WS_WTDT + 12 * 384;        // 384*192 = 73728
constexpr int WS_WTPO  = WS_WTOUT + 384 * 192;      // 192*192 = 36864
constexpr int WS_BIG   = 281600;
constexpr size_t NBL   = (size_t)CB * CL;           // 16384
constexpr size_t BIGSZ = NBL * DIN;                 // 6291456 floats

__device__ __forceinline__ float sigm(float v) { return 1.f / (1.f + __expf(-v)); }
__device__ __forceinline__ float silu_f(float v) { return v * sigm(v); }
__device__ __forceinline__ float softplus_f(float v) { return v > 20.f ? v : log1pf(__expf(v)); }

// ---------------------------------------------------------------------------
// GroupNorm(1, C): per-batch mean/var over C*H*W, two-stage deterministic.
// ---------------------------------------------------------------------------
__global__ __launch_bounds__(256) void gn_partial(const float* __restrict__ x,
                                                  float* __restrict__ part) {
  int b = blockIdx.x >> 6;          // 64 blocks per batch
  int chunk = blockIdx.x & 63;
  const float* px = x + (size_t)b * CC * CL + (size_t)chunk * 12288;
  float s = 0.f, s2 = 0.f;
  for (int i = threadIdx.x; i < 12288 / 4; i += 256) {
    float4 v = ((const float4*)px)[i];
    s  += v.x + v.y + v.z + v.w;
    s2 += v.x * v.x + v.y * v.y + v.z * v.z + v.w * v.w;
  }
  __shared__ float ls[4], ls2[4];
  for (int off = 32; off; off >>= 1) { s += __shfl_down(s, off); s2 += __shfl_down(s2, off); }
  int wid = threadIdx.x >> 6, lane = threadIdx.x & 63;
  if (lane == 0) { ls[wid] = s; ls2[wid] = s2; }
  __syncthreads();
  if (threadIdx.x == 0) {
    float t = 0.f, t2 = 0.f;
    for (int i = 0; i < 4; i++) { t += ls[i]; t2 += ls2[i]; }
    part[blockIdx.x * 2] = t;
    part[blockIdx.x * 2 + 1] = t2;
  }
}

__global__ __launch_bounds__(256) void gn_final(const float* __restrict__ part,
                                                float* __restrict__ stat) {
  int b = threadIdx.x >> 6;   // wave id == batch
  int i = threadIdx.x & 63;
  float s = part[(b * 64 + i) * 2];
  float s2 = part[(b * 64 + i) * 2 + 1];
  for (int off = 32; off; off >>= 1) { s += __shfl_down(s, off); s2 += __shfl_down(s2, off); }
  if (i == 0) {
    float n = (float)(CC * CL);
    float mu = s / n;
    float var = s2 / n - mu * mu;
    stat[b * 2] = mu;
    stat[b * 2 + 1] = rsqrtf(var + 1e-5f);
  }
}

// ---------------------------------------------------------------------------
// Transpose all weight matrices into ws (coalesced B-tiles for the GEMMs).
// ---------------------------------------------------------------------------
__global__ __launch_bounds__(256) void transpose_all(
    const float* __restrict__ in_proj_w, const float* __restrict__ x_proj_w,
    const float* __restrict__ dt_proj_w, const float* __restrict__ out_proj_w,
    const float* __restrict__ proj_out_w, float* __restrict__ ws) {
  int idx = blockIdx.x * 256 + threadIdx.x;
  if (idx < 147456) {                 // wT_in[c][d] = in_proj_w[d][c]
    int c = idx / 768, d = idx % 768;
    ws[WS_WTIN + idx] = in_proj_w[d * 192 + c];
    return;
  }
  idx -= 147456;
  if (idx < 16896) {                  // wT_xp[k][e] = x_proj_w[e][k]
    int k = idx / 44, e = idx % 44;
    ws[WS_WTXP + idx] = x_proj_w[e * 384 + k];
    return;
  }
  idx -= 16896;
  if (idx < 4608) {                   // wT_dt[r][d] = dt_proj_w[d][r]
    int r = idx / 384, d = idx % 384;
    ws[WS_WTDT + idx] = dt_proj_w[d * 12 + r];
    return;
  }
  idx -= 4608;
  if (idx < 73728) {                  // wT_out[k][c] = out_proj_w[c][k]
    int k = idx / 192, c = idx % 192;
    ws[WS_WTOUT + idx] = out_proj_w[c * 384 + k];
    return;
  }
  idx -= 73728;
  if (idx < 36864) {                  // wT_po[c][o] = proj_out_w[o][c]
    int c = idx / 192, o = idx % 192;
    ws[WS_WTPO + idx] = proj_out_w[o * 192 + c];
  }
}

// ---------------------------------------------------------------------------
// in_proj GEMM: xn (computed on the fly from x + GN stats) @ wT_in.
// M=16384 (b,l raster), N=768, K=192. 64x64 tiles. Epilogue routes u (snake)
// and z (raster).
// ---------------------------------------------------------------------------
__global__ __launch_bounds__(256) void gemm_inproj(
    const float* __restrict__ x, const float* __restrict__ wT,
    const float* __restrict__ stat, const float* __restrict__ gamma,
    const float* __restrict__ beta, float* __restrict__ u, float* __restrict__ z) {
  int mt = blockIdx.x & 255, nt = blockIdx.x >> 8;   // nt 0..11
  int m0 = mt * 64, n0 = nt * 64;
  int b = m0 >> 12, l0 = m0 & 4095;
  float mu = stat[b * 2], rs = stat[b * 2 + 1];
  __shared__ float As[16][64];
  __shared__ float Bs[16][64];
  int tid = threadIdx.x;
  int ty = tid >> 4, tx = tid & 15;
  float acc[4][4] = {};
  for (int k0 = 0; k0 < 192; k0 += 16) {
    int mi = tid & 63, kkb = tid >> 6;
#pragma unroll
    for (int i = 0; i < 4; i++) {
      int kk = kkb * 4 + i;
      int c = k0 + kk;
      float xv = x[((size_t)(b * 192 + c) << 12) + l0 + mi];
      As[kk][mi] = (xv - mu) * rs * gamma[c] + beta[c];
      Bs[kk][mi] = wT[(size_t)c * 768 + n0 + mi];
    }
    __syncthreads();
#pragma unroll
    for (int kk = 0; kk < 16; kk++) {
      float a[4], bb[4];
#pragma unroll
      for (int i = 0; i < 4; i++) a[i] = As[kk][ty + 16 * i];
#pragma unroll
      for (int j = 0; j < 4; j++) bb[j] = Bs[kk][tx + 16 * j];
#pragma unroll
      for (int i = 0; i < 4; i++)
#pragma unroll
        for (int j = 0; j < 4; j++) acc[i][j] = fmaf(a[i], bb[j], acc[i][j]);
    }
    __syncthreads();
  }
  int hrow = l0 >> 6;
  bool odd = hrow & 1;
#pragma unroll
  for (int i = 0; i < 4; i++) {
    int w = ty + 16 * i;
    int ls = odd ? (hrow << 6) + (63 - w) : l0 + w;   // snake position
#pragma unroll
    for (int j = 0; j < 4; j++) {
      int d = n0 + tx + 16 * j;
      float v = acc[i][j];
      if (d < DIN)
        u[((size_t)(b << 12) + ls) * DIN + d] = v;
      else
        z[((size_t)(b << 12) + l0 + w) * DIN + (d - DIN)] = v;
    }
  }
}

// ---------------------------------------------------------------------------
// Causal depthwise conv1d (kernel 4) along snake sequence + SiLU.
// ---------------------------------------------------------------------------
__global__ __launch_bounds__(256) void conv_silu(
    const float* __restrict__ u, const float* __restrict__ cw,
    const float* __restrict__ cb, float* __restrict__ uc) {
  int gid = blockIdx.x * 256 + threadIdx.x;   // over 16384*96
  int g = gid % 96;
  int bl = gid / 96;
  int b = bl >> 12, l = bl & 4095;
  int d0 = g << 2;
  float4 acc = *(const float4*)&cb[d0];
#pragma unroll
  for (int k = 0; k < 4; k++) {
    int lk = l - 3 + k;
    if (lk >= 0) {
      const float4 v = *(const float4*)&u[((size_t)(b << 12) + lk) * DIN + d0];
      acc.x = fmaf(v.x, cw[(d0 + 0) * 4 + k], acc.x);
      acc.y = fmaf(v.y, cw[(d0 + 1) * 4 + k], acc.y);
      acc.z = fmaf(v.z, cw[(d0 + 2) * 4 + k], acc.z);
      acc.w = fmaf(v.w, cw[(d0 + 3) * 4 + k], acc.w);
    }
  }
  acc.x = silu_f(acc.x);
  acc.y = silu_f(acc.y);
  acc.z = silu_f(acc.z);
  acc.w = silu_f(acc.w);
  *(float4*)&uc[(size_t)bl * DIN + d0] = acc;
}

// ---------------------------------------------------------------------------
// x_proj: uc [16384,384] @ wT_xp [384,44] -> dt[12] / B[16] / C[16].
// Block: 32 rows x 44 cols, k-chunks of 64.
// ---------------------------------------------------------------------------
__global__ __launch_bounds__(256) void xproj(
    const float* __restrict__ uc, const float* __restrict__ wT,
    float* __restrict__ dtb, float* __restrict__ Bmb, float* __restrict__ Cmb) {
  __shared__ float As[64][33];
  __shared__ float Bs[64][48];
  int m0 = blockIdx.x << 5;
  int tid = threadIdx.x;
  int r = tid & 31, q = tid >> 5;
  float acc[6] = {};
  for (int k0 = 0; k0 < 384; k0 += 64) {
    int rl = tid >> 3, kl = (tid & 7) << 3;
    const float4 v0 = *(const float4*)&uc[(size_t)(m0 + rl) * DIN + k0 + kl];
    const float4 v1 = *(const float4*)&uc[(size_t)(m0 + rl) * DIN + k0 + kl + 4];
    As[kl + 0][rl] = v0.x; As[kl + 1][rl] = v0.y; As[kl + 2][rl] = v0.z; As[kl + 3][rl] = v0.w;
    As[kl + 4][rl] = v1.x; As[kl + 5][rl] = v1.y; As[kl + 6][rl] = v1.z; As[kl + 7][rl] = v1.w;
    for (int i = tid; i < 64 * 48; i += 256) {
      int kk = i / 48, nn = i % 48;
      Bs[kk][nn] = (nn < 44) ? wT[(size_t)(k0 + kk) * 44 + nn] : 0.f;
    }
    __syncthreads();
#pragma unroll 8
    for (int kk = 0; kk < 64; kk++) {
      float a = As[kk][r];
#pragma unroll
      for (int j = 0; j < 6; j++) acc[j] = fmaf(a, Bs[kk][q + 8 * j], acc[j]);
    }
    __syncthreads();
  }
  size_t m = m0 + r;
#pragma unroll
  for (int j = 0; j < 6; j++) {
    int n = q + 8 * j;
    if (n < 12) dtb[m * 12 + n] = acc[j];
    else if (n < 28) Bmb[m * 16 + (n - 12)] = acc[j];
    else if (n < 44) Cmb[m * 16 + (n - 28)] = acc[j];
  }
}

// ---------------------------------------------------------------------------
// dt_proj + softplus: delta[m,d] = softplus(dt[m,:12] @ wT_dt[:, d] + bias[d])
// ---------------------------------------------------------------------------
__global__ __launch_bounds__(256) void dtproj(
    const float* __restrict__ dtb, const float* __restrict__ wT,
    const float* __restrict__ bias, float* __restrict__ delta) {
  int gid = blockIdx.x * 256 + threadIdx.x;   // 16384*96
  int g = gid % 96;
  int m = gid / 96;
  int d0 = g << 2;
  float4 acc = *(const float4*)&bias[d0];
  const float* dtr = &dtb[(size_t)m * 12];
#pragma unroll
  for (int r = 0; r < 12; r++) {
    float t = dtr[r];
    const float4 wv = *(const float4*)&wT[(size_t)r * DIN + d0];
    acc.x = fmaf(t, wv.x, acc.x);
    acc.y = fmaf(t, wv.y, acc.y);
    acc.z = fmaf(t, wv.z, acc.z);
    acc.w = fmaf(t, wv.w, acc.w);
  }
  acc.x = softplus_f(acc.x);
  acc.y = softplus_f(acc.y);
  acc.z = softplus_f(acc.z);
  acc.w = softplus_f(acc.w);
  *(float4*)&delta[(size_t)m * DIN + d0] = acc;
}

// ---------------------------------------------------------------------------
// Selective scan, fused with +uc*Dskip, un-snake, and z-gating.
// 96 blocks = (b, 16-channel group). Threads: (dl 0..15) x (n 0..15).
// LDS-chunked 64 steps (one image row) at a time.
// ---------------------------------------------------------------------------
__global__ __launch_bounds__(256) void scan_kernel(
    const float* __restrict__ delta, const float* __restrict__ uc,
    const float* __restrict__ Bmb, const float* __restrict__ Cmb,
    const float* __restrict__ A_log, const float* __restrict__ Dskip,
    const float* __restrict__ z, float* __restrict__ yr) {
  int b = blockIdx.x / 24;
  int dg = blockIdx.x % 24;
  int tid = threadIdx.x;
  int dl = tid >> 4, n = tid & 15;
  int d = dg * 16 + dl;
  float a_dn = -__expf(A_log[d * 16 + n]);
  float dsk = Dskip[d];
  __shared__ float sD[64][16], sU[64][16], sB[64][16], sC[64][16], sZ[64][16], sY[64][16];
  float h = 0.f;
  size_t baseBL = (size_t)b << 12;
  int li = tid >> 2, ds = (tid & 3) << 2;
  for (int l0 = 0; l0 < 4096; l0 += 64) {
    size_t rowoff = baseBL + l0 + li;
    {
      float4 v;
      v = *(const float4*)&delta[rowoff * DIN + dg * 16 + ds];
      sD[li][ds] = v.x; sD[li][ds + 1] = v.y; sD[li][ds + 2] = v.z; sD[li][ds + 3] = v.w;
      v = *(const float4*)&uc[rowoff * DIN + dg * 16 + ds];
      sU[li][ds] = v.x; sU[li][ds + 1] = v.y; sU[li][ds + 2] = v.z; sU[li][ds + 3] = v.w;
      v = *(const float4*)&z[rowoff * DIN + dg * 16 + ds];
      sZ[li][ds] = v.x; sZ[li][ds + 1] = v.y; sZ[li][ds + 2] = v.z; sZ[li][ds + 3] = v.w;
      v = *(const float4*)&Bmb[rowoff * 16 + ds];
      sB[li][ds] = v.x; sB[li][ds + 1] = v.y; sB[li][ds + 2] = v.z; sB[li][ds + 3] = v.w;
      v = *(const float4*)&Cmb[rowoff * 16 + ds];
      sC[li][ds] = v.x; sC[li][ds + 1] = v.y; sC[li][ds + 2] = v.z; sC[li][ds + 3] = v.w;
    }
    __syncthreads();
    int hrow = l0 >> 6;
    bool odd = hrow & 1;
#pragma unroll 4
    for (int ll = 0; ll < 64; ll++) {
      float dv = sD[ll][dl];
      float uv = sU[ll][dl];
      float dA = __expf(dv * a_dn);
      h = fmaf(dA, h, dv * uv * sB[ll][n]);
      float yp = h * sC[ll][n];
      yp += __shfl_xor(yp, 8, 16);
      yp += __shfl_xor(yp, 4, 16);
      yp += __shfl_xor(yp, 2, 16);
      yp += __shfl_xor(yp, 1, 16);
      if (n == 0) {
        int wr = odd ? 63 - ll : ll;    // raster column for this snake step
        float zv = sZ[wr][dl];
        sY[wr][dl] = (yp + uv * dsk) * silu_f(zv);
      }
    }
    __syncthreads();
    {
      float4 v;
      v.x = sY[li][ds]; v.y = sY[li][ds + 1]; v.z = sY[li][ds + 2]; v.w = sY[li][ds + 3];
      *(float4*)&yr[rowoff * DIN + dg * 16 + ds] = v;
    }
    __syncthreads();
  }
}

// ---------------------------------------------------------------------------
// Depthwise 3x3 local enhancement + residual (raster space).
// ---------------------------------------------------------------------------
__global__ __launch_bounds__(256) void le_conv(
    const float* __restrict__ yr, const float* __restrict__ lw, float* __restrict__ y2) {
  int gid = blockIdx.x * 256 + threadIdx.x;   // 16384*96
  int g = gid % 96;
  int bl = gid / 96;
  int b = bl >> 12, l = bl & 4095;
  int hrow = l >> 6, w = l & 63;
  int d0 = g << 2;
  float4 acc = *(const float4*)&yr[(size_t)bl * DIN + d0];   // residual
#pragma unroll
  for (int ki = 0; ki < 3; ki++) {
    int hh = hrow + ki - 1;
    if ((unsigned)hh >= 64u) continue;
#pragma unroll
    for (int kj = 0; kj < 3; kj++) {
      int ww = w + kj - 1;
      if ((unsigned)ww >= 64u) continue;
      const float4 v = *(const float4*)&yr[((size_t)((b << 12) + (hh << 6) + ww)) * DIN + d0];
      int wi = ki * 3 + kj;
      acc.x = fmaf(v.x, lw[(d0 + 0) * 9 + wi], acc.x);
      acc.y = fmaf(v.y, lw[(d0 + 1) * 9 + wi], acc.y);
      acc.z = fmaf(v.z, lw[(d0 + 2) * 9 + wi], acc.z);
      acc.w = fmaf(v.w, lw[(d0 + 3) * 9 + wi], acc.w);
    }
  }
  *(float4*)&y2[(size_t)bl * DIN + d0] = acc;
}

// ---------------------------------------------------------------------------
// Generic 64x64-tile fp32 GEMM: C[M,N] = A[M,K] @ Bw[K,N] (Bw pre-transposed).
// TRANSOUT: write C transposed per batch into [B, N, 4096] layout (proj_out).
// ---------------------------------------------------------------------------
template <int KDIM, int NDIM, bool TRANSOUT>
__global__ __launch_bounds__(256) void gemm64(
    const float* __restrict__ A, const float* __restrict__ Bw, float* __restrict__ C) {
  int mt = blockIdx.x & 255, nt = blockIdx.x >> 8;
  int m0 = mt * 64, n0 = nt * 64;
  __shared__ float As[16][65];
  __shared__ float Bs[16][64];
  int tid = threadIdx.x;
  int ty = tid >> 4, tx = tid & 15;
  float acc[4][4] = {};
  for (int k0 = 0; k0 < KDIM; k0 += 16) {
    {
      int row = tid >> 2, ks = (tid & 3) * 4;
      const float4 v = *(const float4*)&A[(size_t)(m0 + row) * KDIM + k0 + ks];
      As[ks + 0][row] = v.x; As[ks + 1][row] = v.y; As[ks + 2][row] = v.z; As[ks + 3][row] = v.w;
    }
    {
      int ni = tid & 63, kkb = tid >> 6;
#pragma unroll
      for (int i = 0; i < 4; i++) {
        int kk = kkb * 4 + i;
        Bs[kk][ni] = Bw[(size_t)(k0 + kk) * NDIM + n0 + ni];
      }
    }
    __syncthreads();
#pragma unroll
    for (int kk = 0; kk < 16; kk++) {
      float a[4], bb[4];
#pragma unroll
      for (int i = 0; i < 4; i++) a[i] = As[kk][ty + 16 * i];
#pragma unroll
      for (int j = 0; j < 4; j++) bb[j] = Bs[kk][tx + 16 * j];
#pragma unroll
      for (int i = 0; i < 4; i++)
#pragma unroll
        for (int j = 0; j < 4; j++) acc[i][j] = fmaf(a[i], bb[j], acc[i][j]);
    }
    __syncthreads();
  }
  if constexpr (!TRANSOUT) {
#pragma unroll
    for (int i = 0; i < 4; i++) {
      size_t m = m0 + ty + 16 * i;
#pragma unroll
      for (int j = 0; j < 4; j++) C[m * NDIM + n0 + tx + 16 * j] = acc[i][j];
    }
  } else {
    __shared__ float Cs[64][65];
#pragma unroll
    for (int i = 0; i < 4; i++)
#pragma unroll
      for (int j = 0; j < 4; j++) Cs[tx + 16 * j][ty + 16 * i] = acc[i][j];
    __syncthreads();
    int b = m0 >> 12, l0 = m0 & 4095;
    int li = tid & 63;
#pragma unroll
    for (int rr = 0; rr < 16; rr++) {
      int o = rr * 4 + (tid >> 6);
      C[(size_t)(b * CC + n0 + o) * CL + l0 + li] = Cs[o][li];
    }
  }
}

// ---------------------------------------------------------------------------
extern "C" void kernel_launch(void* const* d_in, const int* in_sizes, int n_in,
                              void* d_out, int out_size, void* d_ws, size_t ws_size,
                              hipStream_t stream) {
  const float* x          = (const float*)d_in[0];
  const float* gn_gamma   = (const float*)d_in[1];
  const float* gn_beta    = (const float*)d_in[2];
  const float* in_proj_w  = (const float*)d_in[3];
  const float* conv1d_w   = (const float*)d_in[4];
  const float* conv1d_b   = (const float*)d_in[5];
  const float* x_proj_w   = (const float*)d_in[6];
  const float* dt_proj_w  = (const float*)d_in[7];
  const float* dt_proj_b  = (const float*)d_in[8];
  const float* A_log      = (const float*)d_in[9];
  const float* Dskip      = (const float*)d_in[10];
  const float* le_w       = (const float*)d_in[11];
  const float* out_proj_w = (const float*)d_in[12];
  const float* proj_out_w = (const float*)d_in[13];
  float* out = (float*)d_out;

  float* ws     = (float*)d_ws;
  float* part   = ws + WS_PART;
  float* stat   = ws + WS_STAT;
  float* wT_in  = ws + WS_WTIN;
  float* wT_xp  = ws + WS_WTXP;
  float* wT_dt  = ws + WS_WTDT;
  float* wT_out = ws + WS_WTOUT;
  float* wT_po  = ws + WS_WTPO;
  float* u      = ws + WS_BIG;
  float* zb     = u + BIGSZ;
  float* uc     = zb + BIGSZ;
  float* delta  = uc + BIGSZ;
  float* yr     = delta + BIGSZ;
  float* dtb    = yr + BIGSZ;
  float* Bmb    = dtb + NBL * DTR;
  float* Cmb    = Bmb + NBL * NST;
  float* y2     = uc;      // reuse: uc dead after scan
  float* outseq = u;       // reuse: u dead after conv

  gn_partial<<<256, 256, 0, stream>>>(x, part);
  gn_final<<<1, 256, 0, stream>>>(part, stat);
  transpose_all<<<1092, 256, 0, stream>>>(in_proj_w, x_proj_w, dt_proj_w,
                                          out_proj_w, proj_out_w, ws);
  gemm_inproj<<<256 * 12, 256, 0, stream>>>(x, wT_in, stat, gn_gamma, gn_beta, u, zb);
  conv_silu<<<6144, 256, 0, stream>>>(u, conv1d_w, conv1d_b, uc);
  xproj<<<512, 256, 0, stream>>>(uc, wT_xp, dtb, Bmb, Cmb);
  dtproj<<<6144, 256, 0, stream>>>(dtb, wT_dt, dt_proj_b, delta);
  scan_kernel<<<96, 256, 0, stream>>>(delta, uc, Bmb, Cmb, A_log, Dskip, zb, yr);
  le_conv<<<6144, 256, 0, stream>>>(yr, le_w, y2);
  gemm64<384, 192, false><<<256 * 3, 256, 0, stream>>>(y2, wT_out, outseq);
  gemm64<192, 192, true><<<256 * 3, 256, 0, stream>>>(outseq, wT_po, out);
}

// Round 2
// 587.450 us; speedup vs baseline: 2.6285x; 2.6285x over previous
//
#include <hip/hip_runtime.h>
#include <cstddef>

// Problem constants
constexpr int CB  = 4;
constexpr int CC  = 192;
constexpr int CH  = 64;
constexpr int CW  = 64;
constexpr int CL  = CH * CW;        // 4096
constexpr int DIN = 384;
constexpr int NST = 16;
constexpr int DTR = 12;

constexpr int NCHUNK = 64;          // chunks per sequence (= image rows)
constexpr int NELEM  = CB * 24 * 256; // 24576 independent (b,d,n) recurrences

// Workspace layout (in floats)
constexpr int WS_PART  = 0;                         // 512
constexpr int WS_STAT  = 512;                       // 8
constexpr int WS_WTIN  = 1024;                      // 192*768 = 147456
constexpr int WS_WTXP  = WS_WTIN + 192 * 768;       // 384*44  = 16896
constexpr int WS_WTDT  = WS_WTXP + 384 * 44;        // 12*384  = 4608
constexpr int WS_WTOUT = WS_WTDT + 12 * 384;        // 384*192 = 73728
constexpr int WS_WTPO  = WS_WTOUT + 384 * 192;      // 192*192 = 36864
constexpr int WS_BIG   = 281600;
constexpr size_t NBL   = (size_t)CB * CL;           // 16384
constexpr size_t BIGSZ = NBL * DIN;                 // 6291456 floats

__device__ __forceinline__ float sigm(float v) { return 1.f / (1.f + __expf(-v)); }
__device__ __forceinline__ float silu_f(float v) { return v * sigm(v); }
__device__ __forceinline__ float softplus_f(float v) { return v > 20.f ? v : log1pf(__expf(v)); }

// ---------------------------------------------------------------------------
// GroupNorm(1, C): per-batch mean/var over C*H*W, two-stage deterministic.
// ---------------------------------------------------------------------------
__global__ __launch_bounds__(256) void gn_partial(const float* __restrict__ x,
                                                  float* __restrict__ part) {
  int b = blockIdx.x >> 6;          // 64 blocks per batch
  int chunk = blockIdx.x & 63;
  const float* px = x + (size_t)b * CC * CL + (size_t)chunk * 12288;
  float s = 0.f, s2 = 0.f;
  for (int i = threadIdx.x; i < 12288 / 4; i += 256) {
    float4 v = ((const float4*)px)[i];
    s  += v.x + v.y + v.z + v.w;
    s2 += v.x * v.x + v.y * v.y + v.z * v.z + v.w * v.w;
  }
  __shared__ float ls[4], ls2[4];
  for (int off = 32; off; off >>= 1) { s += __shfl_down(s, off); s2 += __shfl_down(s2, off); }
  int wid = threadIdx.x >> 6, lane = threadIdx.x & 63;
  if (lane == 0) { ls[wid] = s; ls2[wid] = s2; }
  __syncthreads();
  if (threadIdx.x == 0) {
    float t = 0.f, t2 = 0.f;
    for (int i = 0; i < 4; i++) { t += ls[i]; t2 += ls2[i]; }
    part[blockIdx.x * 2] = t;
    part[blockIdx.x * 2 + 1] = t2;
  }
}

__global__ __launch_bounds__(256) void gn_final(const float* __restrict__ part,
                                                float* __restrict__ stat) {
  int b = threadIdx.x >> 6;   // wave id == batch
  int i = threadIdx.x & 63;
  float s = part[(b * 64 + i) * 2];
  float s2 = part[(b * 64 + i) * 2 + 1];
  for (int off = 32; off; off >>= 1) { s += __shfl_down(s, off); s2 += __shfl_down(s2, off); }
  if (i == 0) {
    float n = (float)(CC * CL);
    float mu = s / n;
    float var = s2 / n - mu * mu;
    stat[b * 2] = mu;
    stat[b * 2 + 1] = rsqrtf(var + 1e-5f);
  }
}

// ---------------------------------------------------------------------------
// Transpose all weight matrices into ws (coalesced B-tiles for the GEMMs).
// ---------------------------------------------------------------------------
__global__ __launch_bounds__(256) void transpose_all(
    const float* __restrict__ in_proj_w, const float* __restrict__ x_proj_w,
    const float* __restrict__ dt_proj_w, const float* __restrict__ out_proj_w,
    const float* __restrict__ proj_out_w, float* __restrict__ ws) {
  int idx = blockIdx.x * 256 + threadIdx.x;
  if (idx < 147456) {                 // wT_in[c][d] = in_proj_w[d][c]
    int c = idx / 768, d = idx % 768;
    ws[WS_WTIN + idx] = in_proj_w[d * 192 + c];
    return;
  }
  idx -= 147456;
  if (idx < 16896) {                  // wT_xp[k][e] = x_proj_w[e][k]
    int k = idx / 44, e = idx % 44;
    ws[WS_WTXP + idx] = x_proj_w[e * 384 + k];
    return;
  }
  idx -= 16896;
  if (idx < 4608) {                   // wT_dt[r][d] = dt_proj_w[d][r]
    int r = idx / 384, d = idx % 384;
    ws[WS_WTDT + idx] = dt_proj_w[d * 12 + r];
    return;
  }
  idx -= 4608;
  if (idx < 73728) {                  // wT_out[k][c] = out_proj_w[c][k]
    int k = idx / 192, c = idx % 192;
    ws[WS_WTOUT + idx] = out_proj_w[c * 384 + k];
    return;
  }
  idx -= 73728;
  if (idx < 36864) {                  // wT_po[c][o] = proj_out_w[o][c]
    int c = idx / 192, o = idx % 192;
    ws[WS_WTPO + idx] = proj_out_w[o * 192 + c];
  }
}

// ---------------------------------------------------------------------------
// in_proj GEMM: xn (computed on the fly from x + GN stats) @ wT_in.
// M=16384 (b,l raster), N=768, K=192. 64x64 tiles. Epilogue routes u (snake)
// and z (raster).
// ---------------------------------------------------------------------------
__global__ __launch_bounds__(256) void gemm_inproj(
    const float* __restrict__ x, const float* __restrict__ wT,
    const float* __restrict__ stat, const float* __restrict__ gamma,
    const float* __restrict__ beta, float* __restrict__ u, float* __restrict__ z) {
  int mt = blockIdx.x & 255, nt = blockIdx.x >> 8;   // nt 0..11
  int m0 = mt * 64, n0 = nt * 64;
  int b = m0 >> 12, l0 = m0 & 4095;
  float mu = stat[b * 2], rs = stat[b * 2 + 1];
  __shared__ float As[16][64];
  __shared__ float Bs[16][64];
  int tid = threadIdx.x;
  int ty = tid >> 4, tx = tid & 15;
  float acc[4][4] = {};
  for (int k0 = 0; k0 < 192; k0 += 16) {
    int mi = tid & 63, kkb = tid >> 6;
#pragma unroll
    for (int i = 0; i < 4; i++) {
      int kk = kkb * 4 + i;
      int c = k0 + kk;
      float xv = x[((size_t)(b * 192 + c) << 12) + l0 + mi];
      As[kk][mi] = (xv - mu) * rs * gamma[c] + beta[c];
      Bs[kk][mi] = wT[(size_t)c * 768 + n0 + mi];
    }
    __syncthreads();
#pragma unroll
    for (int kk = 0; kk < 16; kk++) {
      float a[4], bb[4];
#pragma unroll
      for (int i = 0; i < 4; i++) a[i] = As[kk][ty + 16 * i];
#pragma unroll
      for (int j = 0; j < 4; j++) bb[j] = Bs[kk][tx + 16 * j];
#pragma unroll
      for (int i = 0; i < 4; i++)
#pragma unroll
        for (int j = 0; j < 4; j++) acc[i][j] = fmaf(a[i], bb[j], acc[i][j]);
    }
    __syncthreads();
  }
  int hrow = l0 >> 6;
  bool odd = hrow & 1;
#pragma unroll
  for (int i = 0; i < 4; i++) {
    int w = ty + 16 * i;
    int ls = odd ? (hrow << 6) + (63 - w) : l0 + w;   // snake position
#pragma unroll
    for (int j = 0; j < 4; j++) {
      int d = n0 + tx + 16 * j;
      float v = acc[i][j];
      if (d < DIN)
        u[((size_t)(b << 12) + ls) * DIN + d] = v;
      else
        z[((size_t)(b << 12) + l0 + w) * DIN + (d - DIN)] = v;
    }
  }
}

// ---------------------------------------------------------------------------
// Causal depthwise conv1d (kernel 4) along snake sequence + SiLU.
// ---------------------------------------------------------------------------
__global__ __launch_bounds__(256) void conv_silu(
    const float* __restrict__ u, const float* __restrict__ cw,
    const float* __restrict__ cb, float* __restrict__ uc) {
  int gid = blockIdx.x * 256 + threadIdx.x;   // over 16384*96
  int g = gid % 96;
  int bl = gid / 96;
  int b = bl >> 12, l = bl & 4095;
  int d0 = g << 2;
  float4 acc = *(const float4*)&cb[d0];
#pragma unroll
  for (int k = 0; k < 4; k++) {
    int lk = l - 3 + k;
    if (lk >= 0) {
      const float4 v = *(const float4*)&u[((size_t)(b << 12) + lk) * DIN + d0];
      acc.x = fmaf(v.x, cw[(d0 + 0) * 4 + k], acc.x);
      acc.y = fmaf(v.y, cw[(d0 + 1) * 4 + k], acc.y);
      acc.z = fmaf(v.z, cw[(d0 + 2) * 4 + k], acc.z);
      acc.w = fmaf(v.w, cw[(d0 + 3) * 4 + k], acc.w);
    }
  }
  acc.x = silu_f(acc.x);
  acc.y = silu_f(acc.y);
  acc.z = silu_f(acc.z);
  acc.w = silu_f(acc.w);
  *(float4*)&uc[(size_t)bl * DIN + d0] = acc;
}

// ---------------------------------------------------------------------------
// x_proj: uc [16384,384] @ wT_xp [384,44] -> dt[12] / B[16] / C[16].
// ---------------------------------------------------------------------------
__global__ __launch_bounds__(256) void xproj(
    const float* __restrict__ uc, const float* __restrict__ wT,
    float* __restrict__ dtb, float* __restrict__ Bmb, float* __restrict__ Cmb) {
  __shared__ float As[64][33];
  __shared__ float Bs[64][48];
  int m0 = blockIdx.x << 5;
  int tid = threadIdx.x;
  int r = tid & 31, q = tid >> 5;
  float acc[6] = {};
  for (int k0 = 0; k0 < 384; k0 += 64) {
    int rl = tid >> 3, kl = (tid & 7) << 3;
    const float4 v0 = *(const float4*)&uc[(size_t)(m0 + rl) * DIN + k0 + kl];
    const float4 v1 = *(const float4*)&uc[(size_t)(m0 + rl) * DIN + k0 + kl + 4];
    As[kl + 0][rl] = v0.x; As[kl + 1][rl] = v0.y; As[kl + 2][rl] = v0.z; As[kl + 3][rl] = v0.w;
    As[kl + 4][rl] = v1.x; As[kl + 5][rl] = v1.y; As[kl + 6][rl] = v1.z; As[kl + 7][rl] = v1.w;
    for (int i = tid; i < 64 * 48; i += 256) {
      int kk = i / 48, nn = i % 48;
      Bs[kk][nn] = (nn < 44) ? wT[(size_t)(k0 + kk) * 44 + nn] : 0.f;
    }
    __syncthreads();
#pragma unroll 8
    for (int kk = 0; kk < 64; kk++) {
      float a = As[kk][r];
#pragma unroll
      for (int j = 0; j < 6; j++) acc[j] = fmaf(a, Bs[kk][q + 8 * j], acc[j]);
    }
    __syncthreads();
  }
  size_t m = m0 + r;
#pragma unroll
  for (int j = 0; j < 6; j++) {
    int n = q + 8 * j;
    if (n < 12) dtb[m * 12 + n] = acc[j];
    else if (n < 28) Bmb[m * 16 + (n - 12)] = acc[j];
    else if (n < 44) Cmb[m * 16 + (n - 28)] = acc[j];
  }
}

// ---------------------------------------------------------------------------
// dt_proj + softplus
// ---------------------------------------------------------------------------
__global__ __launch_bounds__(256) void dtproj(
    const float* __restrict__ dtb, const float* __restrict__ wT,
    const float* __restrict__ bias, float* __restrict__ delta) {
  int gid = blockIdx.x * 256 + threadIdx.x;   // 16384*96
  int g = gid % 96;
  int m = gid / 96;
  int d0 = g << 2;
  float4 acc = *(const float4*)&bias[d0];
  const float* dtr = &dtb[(size_t)m * 12];
#pragma unroll
  for (int r = 0; r < 12; r++) {
    float t = dtr[r];
    const float4 wv = *(const float4*)&wT[(size_t)r * DIN + d0];
    acc.x = fmaf(t, wv.x, acc.x);
    acc.y = fmaf(t, wv.y, acc.y);
    acc.z = fmaf(t, wv.z, acc.z);
    acc.w = fmaf(t, wv.w, acc.w);
  }
  acc.x = softplus_f(acc.x);
  acc.y = softplus_f(acc.y);
  acc.z = softplus_f(acc.z);
  acc.w = softplus_f(acc.w);
  *(float4*)&delta[(size_t)m * DIN + d0] = acc;
}

// ---------------------------------------------------------------------------
// Chunked selective scan. Chunk = one image row (64 steps).
// Phase A: per-chunk local scan from h=0; emit h_end and decay product
//          P = exp(a_dn * sum(delta)) (product of exps collapses to one exp).
// Phase B: sequential combine over 64 chunks -> h_in per chunk.
// Phase C: redo chunk with correct h_in; fused y/Dskip/un-snake/z-gate.
// Block = (b, 16-channel group, chunk); thread = (dl, n).
// ---------------------------------------------------------------------------
__global__ __launch_bounds__(256) void scan_partial(
    const float* __restrict__ delta, const float* __restrict__ uc,
    const float* __restrict__ Bmb, const float* __restrict__ A_log,
    float* __restrict__ hend, float* __restrict__ Pbuf) {
  int blk = blockIdx.x;
  int chunk = blk & 63;
  int bdg = blk >> 6;               // 0..95 = b*24+dg
  int b = bdg / 24, dg = bdg % 24;
  int tid = threadIdx.x;
  int dl = tid >> 4, n = tid & 15;
  int d = dg * 16 + dl;
  float a_dn = -__expf(A_log[d * 16 + n]);
  __shared__ float sD[64][16], sU[64][16], sB[64][16];
  size_t baseBL = ((size_t)b << 12) + chunk * 64;
  int li = tid >> 2, ds = (tid & 3) << 2;
  {
    size_t rowoff = baseBL + li;
    float4 v;
    v = *(const float4*)&delta[rowoff * DIN + dg * 16 + ds];
    sD[li][ds] = v.x; sD[li][ds + 1] = v.y; sD[li][ds + 2] = v.z; sD[li][ds + 3] = v.w;
    v = *(const float4*)&uc[rowoff * DIN + dg * 16 + ds];
    sU[li][ds] = v.x; sU[li][ds + 1] = v.y; sU[li][ds + 2] = v.z; sU[li][ds + 3] = v.w;
    v = *(const float4*)&Bmb[rowoff * 16 + ds];
    sB[li][ds] = v.x; sB[li][ds + 1] = v.y; sB[li][ds + 2] = v.z; sB[li][ds + 3] = v.w;
  }
  __syncthreads();
  float h = 0.f, sdel = 0.f;
#pragma unroll 8
  for (int ll = 0; ll < 64; ll++) {
    float dv = sD[ll][dl];
    float uv = sU[ll][dl];
    float dA = __expf(dv * a_dn);
    h = fmaf(dA, h, dv * uv * sB[ll][n]);
    sdel += dv;
  }
  int e = bdg * 256 + tid;
  hend[(size_t)chunk * NELEM + e] = h;
  Pbuf[(size_t)chunk * NELEM + e] = __expf(a_dn * sdel);
}

__global__ __launch_bounds__(256) void scan_combine(
    const float* __restrict__ hend, const float* __restrict__ Pbuf,
    float* __restrict__ hin) {
  int e = blockIdx.x * 256 + threadIdx.x;   // 0..24575
  float h = 0.f;
  float Pc = Pbuf[e], Hc = hend[e];
#pragma unroll 8
  for (int c = 0; c < NCHUNK; c++) {
    float Pn = 0.f, Hn = 0.f;
    if (c < NCHUNK - 1) {
      Pn = Pbuf[(size_t)(c + 1) * NELEM + e];
      Hn = hend[(size_t)(c + 1) * NELEM + e];
    }
    hin[(size_t)c * NELEM + e] = h;
    h = fmaf(Pc, h, Hc);
    Pc = Pn; Hc = Hn;
  }
}

__global__ __launch_bounds__(256) void scan_final(
    const float* __restrict__ delta, const float* __restrict__ uc,
    const float* __restrict__ Bmb, const float* __restrict__ Cmb,
    const float* __restrict__ A_log, const float* __restrict__ Dskip,
    const float* __restrict__ z, const float* __restrict__ hin,
    float* __restrict__ yr) {
  int blk = blockIdx.x;
  int chunk = blk & 63;
  int bdg = blk >> 6;
  int b = bdg / 24, dg = bdg % 24;
  int tid = threadIdx.x;
  int dl = tid >> 4, n = tid & 15;
  int d = dg * 16 + dl;
  float a_dn = -__expf(A_log[d * 16 + n]);
  float dsk = Dskip[d];
  float h = hin[(size_t)chunk * NELEM + bdg * 256 + tid];
  __shared__ float sD[64][16], sU[64][16], sB[64][16], sC[64][16], sZ[64][16], sY[64][16];
  size_t baseBL = ((size_t)b << 12) + chunk * 64;
  int li = tid >> 2, ds = (tid & 3) << 2;
  {
    size_t rowoff = baseBL + li;
    float4 v;
    v = *(const float4*)&delta[rowoff * DIN + dg * 16 + ds];
    sD[li][ds] = v.x; sD[li][ds + 1] = v.y; sD[li][ds + 2] = v.z; sD[li][ds + 3] = v.w;
    v = *(const float4*)&uc[rowoff * DIN + dg * 16 + ds];
    sU[li][ds] = v.x; sU[li][ds + 1] = v.y; sU[li][ds + 2] = v.z; sU[li][ds + 3] = v.w;
    v = *(const float4*)&z[rowoff * DIN + dg * 16 + ds];
    sZ[li][ds] = v.x; sZ[li][ds + 1] = v.y; sZ[li][ds + 2] = v.z; sZ[li][ds + 3] = v.w;
    v = *(const float4*)&Bmb[rowoff * 16 + ds];
    sB[li][ds] = v.x; sB[li][ds + 1] = v.y; sB[li][ds + 2] = v.z; sB[li][ds + 3] = v.w;
    v = *(const float4*)&Cmb[rowoff * 16 + ds];
    sC[li][ds] = v.x; sC[li][ds + 1] = v.y; sC[li][ds + 2] = v.z; sC[li][ds + 3] = v.w;
  }
  __syncthreads();
  bool odd = chunk & 1;
#pragma unroll 4
  for (int ll = 0; ll < 64; ll++) {
    float dv = sD[ll][dl];
    float uv = sU[ll][dl];
    float dA = __expf(dv * a_dn);
    h = fmaf(dA, h, dv * uv * sB[ll][n]);
    float yp = h * sC[ll][n];
    yp += __shfl_xor(yp, 8, 16);
    yp += __shfl_xor(yp, 4, 16);
    yp += __shfl_xor(yp, 2, 16);
    yp += __shfl_xor(yp, 1, 16);
    if (n == 0) {
      int wr = odd ? 63 - ll : ll;    // raster column for this snake step
      float zv = sZ[wr][dl];
      sY[wr][dl] = (yp + uv * dsk) * silu_f(zv);
    }
  }
  __syncthreads();
  {
    size_t rowoff = baseBL + li;
    float4 v;
    v.x = sY[li][ds]; v.y = sY[li][ds + 1]; v.z = sY[li][ds + 2]; v.w = sY[li][ds + 3];
    *(float4*)&yr[rowoff * DIN + dg * 16 + ds] = v;
  }
}

// ---------------------------------------------------------------------------
// Depthwise 3x3 local enhancement + residual (raster space).
// ---------------------------------------------------------------------------
__global__ __launch_bounds__(256) void le_conv(
    const float* __restrict__ yr, const float* __restrict__ lw, float* __restrict__ y2) {
  int gid = blockIdx.x * 256 + threadIdx.x;   // 16384*96
  int g = gid % 96;
  int bl = gid / 96;
  int b = bl >> 12, l = bl & 4095;
  int hrow = l >> 6, w = l & 63;
  int d0 = g << 2;
  float4 acc = *(const float4*)&yr[(size_t)bl * DIN + d0];   // residual
#pragma unroll
  for (int ki = 0; ki < 3; ki++) {
    int hh = hrow + ki - 1;
    if ((unsigned)hh >= 64u) continue;
#pragma unroll
    for (int kj = 0; kj < 3; kj++) {
      int ww = w + kj - 1;
      if ((unsigned)ww >= 64u) continue;
      const float4 v = *(const float4*)&yr[((size_t)((b << 12) + (hh << 6) + ww)) * DIN + d0];
      int wi = ki * 3 + kj;
      acc.x = fmaf(v.x, lw[(d0 + 0) * 9 + wi], acc.x);
      acc.y = fmaf(v.y, lw[(d0 + 1) * 9 + wi], acc.y);
      acc.z = fmaf(v.z, lw[(d0 + 2) * 9 + wi], acc.z);
      acc.w = fmaf(v.w, lw[(d0 + 3) * 9 + wi], acc.w);
    }
  }
  *(float4*)&y2[(size_t)bl * DIN + d0] = acc;
}

// ---------------------------------------------------------------------------
// Generic 64x64-tile fp32 GEMM: C[M,N] = A[M,K] @ Bw[K,N] (Bw pre-transposed).
// TRANSOUT: write C transposed per batch into [B, N, 4096] layout (proj_out).
// ---------------------------------------------------------------------------
template <int KDIM, int NDIM, bool TRANSOUT>
__global__ __launch_bounds__(256) void gemm64(
    const float* __restrict__ A, const float* __restrict__ Bw, float* __restrict__ C) {
  int mt = blockIdx.x & 255, nt = blockIdx.x >> 8;
  int m0 = mt * 64, n0 = nt * 64;
  __shared__ float As[16][65];
  __shared__ float Bs[16][64];
  int tid = threadIdx.x;
  int ty = tid >> 4, tx = tid & 15;
  float acc[4][4] = {};
  for (int k0 = 0; k0 < KDIM; k0 += 16) {
    {
      int row = tid >> 2, ks = (tid & 3) * 4;
      const float4 v = *(const float4*)&A[(size_t)(m0 + row) * KDIM + k0 + ks];
      As[ks + 0][row] = v.x; As[ks + 1][row] = v.y; As[ks + 2][row] = v.z; As[ks + 3][row] = v.w;
    }
    {
      int ni = tid & 63, kkb = tid >> 6;
#pragma unroll
      for (int i = 0; i < 4; i++) {
        int kk = kkb * 4 + i;
        Bs[kk][ni] = Bw[(size_t)(k0 + kk) * NDIM + n0 + ni];
      }
    }
    __syncthreads();
#pragma unroll
    for (int kk = 0; kk < 16; kk++) {
      float a[4], bb[4];
#pragma unroll
      for (int i = 0; i < 4; i++) a[i] = As[kk][ty + 16 * i];
#pragma unroll
      for (int j = 0; j < 4; j++) bb[j] = Bs[kk][tx + 16 * j];
#pragma unroll
      for (int i = 0; i < 4; i++)
#pragma unroll
        for (int j = 0; j < 4; j++) acc[i][j] = fmaf(a[i], bb[j], acc[i][j]);
    }
    __syncthreads();
  }
  if constexpr (!TRANSOUT) {
#pragma unroll
    for (int i = 0; i < 4; i++) {
      size_t m = m0 + ty + 16 * i;
#pragma unroll
      for (int j = 0; j < 4; j++) C[m * NDIM + n0 + tx + 16 * j] = acc[i][j];
    }
  } else {
    __shared__ float Cs[64][65];
#pragma unroll
    for (int i = 0; i < 4; i++)
#pragma unroll
      for (int j = 0; j < 4; j++) Cs[tx + 16 * j][ty + 16 * i] = acc[i][j];
    __syncthreads();
    int b = m0 >> 12, l0 = m0 & 4095;
    int li = tid & 63;
#pragma unroll
    for (int rr = 0; rr < 16; rr++) {
      int o = rr * 4 + (tid >> 6);
      C[(size_t)(b * CC + n0 + o) * CL + l0 + li] = Cs[o][li];
    }
  }
}

// ---------------------------------------------------------------------------
extern "C" void kernel_launch(void* const* d_in, const int* in_sizes, int n_in,
                              void* d_out, int out_size, void* d_ws, size_t ws_size,
                              hipStream_t stream) {
  const float* x          = (const float*)d_in[0];
  const float* gn_gamma   = (const float*)d_in[1];
  const float* gn_beta    = (const float*)d_in[2];
  const float* in_proj_w  = (const float*)d_in[3];
  const float* conv1d_w   = (const float*)d_in[4];
  const float* conv1d_b   = (const float*)d_in[5];
  const float* x_proj_w   = (const float*)d_in[6];
  const float* dt_proj_w  = (const float*)d_in[7];
  const float* dt_proj_b  = (const float*)d_in[8];
  const float* A_log      = (const float*)d_in[9];
  const float* Dskip      = (const float*)d_in[10];
  const float* le_w       = (const float*)d_in[11];
  const float* out_proj_w = (const float*)d_in[12];
  const float* proj_out_w = (const float*)d_in[13];
  float* out = (float*)d_out;

  float* ws     = (float*)d_ws;
  float* part   = ws + WS_PART;
  float* stat   = ws + WS_STAT;
  float* wT_in  = ws + WS_WTIN;
  float* wT_xp  = ws + WS_WTXP;
  float* wT_dt  = ws + WS_WTDT;
  float* wT_out = ws + WS_WTOUT;
  float* wT_po  = ws + WS_WTPO;
  float* u      = ws + WS_BIG;
  float* zb     = u + BIGSZ;
  float* uc     = zb + BIGSZ;
  float* delta  = uc + BIGSZ;
  float* yr     = delta + BIGSZ;
  float* dtb    = yr + BIGSZ;
  float* Bmb    = dtb + NBL * DTR;
  float* Cmb    = Bmb + NBL * NST;
  float* y2     = uc;      // reuse: uc dead after scan
  float* outseq = u;       // reuse: u dead after conv + scan phases
  // scan scratch aliases u (dead after conv_silu, reborn as outseq after scan)
  float* hend   = u;                         // 64*24576 = 1572864 floats
  float* Pbuf   = u + (size_t)NCHUNK * NELEM;
  float* hin    = u + 2 * (size_t)NCHUNK * NELEM;  // total 4718592 <= BIGSZ

  gn_partial<<<256, 256, 0, stream>>>(x, part);
  gn_final<<<1, 256, 0, stream>>>(part, stat);
  transpose_all<<<1092, 256, 0, stream>>>(in_proj_w, x_proj_w, dt_proj_w,
                                          out_proj_w, proj_out_w, ws);
  gemm_inproj<<<256 * 12, 256, 0, stream>>>(x, wT_in, stat, gn_gamma, gn_beta, u, zb);
  conv_silu<<<6144, 256, 0, stream>>>(u, conv1d_w, conv1d_b, uc);
  xproj<<<512, 256, 0, stream>>>(uc, wT_xp, dtb, Bmb, Cmb);
  dtproj<<<6144, 256, 0, stream>>>(dtb, wT_dt, dt_proj_b, delta);
  scan_partial<<<96 * 64, 256, 0, stream>>>(delta, uc, Bmb, A_log, hend, Pbuf);
  scan_combine<<<96, 256, 0, stream>>>(hend, Pbuf, hin);
  scan_final<<<96 * 64, 256, 0, stream>>>(delta, uc, Bmb, Cmb, A_log, Dskip,
                                          zb, hin, yr);
  le_conv<<<6144, 256, 0, stream>>>(yr, le_w, y2);
  gemm64<384, 192, false><<<256 * 3, 256, 0, stream>>>(y2, wT_out, outseq);
  gemm64<192, 192, true><<<256 * 3, 256, 0, stream>>>(outseq, wT_po, out);
}

// Round 4
// 510.588 us; speedup vs baseline: 3.0241x; 1.1505x over previous
//
#include <hip/hip_runtime.h>
#include <cstddef>

// Problem constants
constexpr int CB  = 4;
constexpr int CC  = 192;
constexpr int CH  = 64;
constexpr int CW  = 64;
constexpr int CL  = CH * CW;        // 4096
constexpr int DIN = 384;
constexpr int NST = 16;
constexpr int DTR = 12;

constexpr int NCHUNK = 64;          // chunks per sequence (= image rows)
constexpr int NELEM  = CB * DIN * NST; // 24576 independent (b,d,n) recurrences

// Workspace layout (in floats)
constexpr int WS_PART  = 0;                         // 512
constexpr int WS_STAT  = 512;                       // 8
constexpr int WS_WTIN  = 1024;                      // 192*768 = 147456
constexpr int WS_WTXP  = WS_WTIN + 192 * 768;       // 384*44  = 16896
constexpr int WS_WTDT  = WS_WTXP + 384 * 44;        // 12*384  = 4608
constexpr int WS_WTOUT = WS_WTDT + 12 * 384;        // 384*192 = 73728
constexpr int WS_WTPO  = WS_WTOUT + 384 * 192;      // 192*192 = 36864
constexpr int WS_BIG   = 281600;
constexpr size_t NBL   = (size_t)CB * CL;           // 16384
constexpr size_t BIGSZ = NBL * DIN;                 // 6291456 floats

__device__ __forceinline__ float sigm(float v) { return 1.f / (1.f + __expf(-v)); }
__device__ __forceinline__ float silu_f(float v) { return v * sigm(v); }
__device__ __forceinline__ float softplus_f(float v) { return v > 20.f ? v : log1pf(__expf(v)); }
template <int PAT>
__device__ __forceinline__ float quadswz(float v) {
  return __int_as_float(__builtin_amdgcn_ds_swizzle(__float_as_int(v), PAT));
}

// ---------------------------------------------------------------------------
// GroupNorm(1, C): per-batch mean/var over C*H*W, two-stage deterministic.
// ---------------------------------------------------------------------------
__global__ __launch_bounds__(256) void gn_partial(const float* __restrict__ x,
                                                  float* __restrict__ part) {
  int b = blockIdx.x >> 6;          // 64 blocks per batch
  int chunk = blockIdx.x & 63;
  const float* px = x + (size_t)b * CC * CL + (size_t)chunk * 12288;
  float s = 0.f, s2 = 0.f;
  for (int i = threadIdx.x; i < 12288 / 4; i += 256) {
    float4 v = ((const float4*)px)[i];
    s  += v.x + v.y + v.z + v.w;
    s2 += v.x * v.x + v.y * v.y + v.z * v.z + v.w * v.w;
  }
  __shared__ float ls[4], ls2[4];
  for (int off = 32; off; off >>= 1) { s += __shfl_down(s, off); s2 += __shfl_down(s2, off); }
  int wid = threadIdx.x >> 6, lane = threadIdx.x & 63;
  if (lane == 0) { ls[wid] = s; ls2[wid] = s2; }
  __syncthreads();
  if (threadIdx.x == 0) {
    float t = 0.f, t2 = 0.f;
    for (int i = 0; i < 4; i++) { t += ls[i]; t2 += ls2[i]; }
    part[blockIdx.x * 2] = t;
    part[blockIdx.x * 2 + 1] = t2;
  }
}

__global__ __launch_bounds__(256) void gn_final(const float* __restrict__ part,
                                                float* __restrict__ stat) {
  int b = threadIdx.x >> 6;   // wave id == batch
  int i = threadIdx.x & 63;
  float s = part[(b * 64 + i) * 2];
  float s2 = part[(b * 64 + i) * 2 + 1];
  for (int off = 32; off; off >>= 1) { s += __shfl_down(s, off); s2 += __shfl_down(s2, off); }
  if (i == 0) {
    float n = (float)(CC * CL);
    float mu = s / n;
    float var = s2 / n - mu * mu;
    stat[b * 2] = mu;
    stat[b * 2 + 1] = rsqrtf(var + 1e-5f);
  }
}

// ---------------------------------------------------------------------------
// Transpose all weight matrices into ws (coalesced B-tiles for the GEMMs).
// ---------------------------------------------------------------------------
__global__ __launch_bounds__(256) void transpose_all(
    const float* __restrict__ in_proj_w, const float* __restrict__ x_proj_w,
    const float* __restrict__ dt_proj_w, const float* __restrict__ out_proj_w,
    const float* __restrict__ proj_out_w, float* __restrict__ ws) {
  int idx = blockIdx.x * 256 + threadIdx.x;
  if (idx < 147456) {                 // wT_in[c][d] = in_proj_w[d][c]
    int c = idx / 768, d = idx % 768;
    ws[WS_WTIN + idx] = in_proj_w[d * 192 + c];
    return;
  }
  idx -= 147456;
  if (idx < 16896) {                  // wT_xp[k][e] = x_proj_w[e][k]
    int k = idx / 44, e = idx % 44;
    ws[WS_WTXP + idx] = x_proj_w[e * 384 + k];
    return;
  }
  idx -= 16896;
  if (idx < 4608) {                   // wT_dt[r][d] = dt_proj_w[d][r]
    int r = idx / 384, d = idx % 384;
    ws[WS_WTDT + idx] = dt_proj_w[d * 12 + r];
    return;
  }
  idx -= 4608;
  if (idx < 73728) {                  // wT_out[k][c] = out_proj_w[c][k]
    int k = idx / 192, c = idx % 192;
    ws[WS_WTOUT + idx] = out_proj_w[c * 384 + k];
    return;
  }
  idx -= 73728;
  if (idx < 36864) {                  // wT_po[c][o] = proj_out_w[o][c]
    int c = idx / 192, o = idx % 192;
    ws[WS_WTPO + idx] = proj_out_w[o * 192 + c];
  }
}

// ---------------------------------------------------------------------------
// in_proj GEMM: xn (computed on the fly from x + GN stats) @ wT_in.
// M=16384 (b,l raster), N=768, K=192. 64x64 tiles. Epilogue routes u (snake)
// and z (raster).
// ---------------------------------------------------------------------------
__global__ __launch_bounds__(256) void gemm_inproj(
    const float* __restrict__ x, const float* __restrict__ wT,
    const float* __restrict__ stat, const float* __restrict__ gamma,
    const float* __restrict__ beta, float* __restrict__ u, float* __restrict__ z) {
  int mt = blockIdx.x & 255, nt = blockIdx.x >> 8;   // nt 0..11
  int m0 = mt * 64, n0 = nt * 64;
  int b = m0 >> 12, l0 = m0 & 4095;
  float mu = stat[b * 2], rs = stat[b * 2 + 1];
  __shared__ float As[16][64];
  __shared__ float Bs[16][64];
  int tid = threadIdx.x;
  int ty = tid >> 4, tx = tid & 15;
  float acc[4][4] = {};
  for (int k0 = 0; k0 < 192; k0 += 16) {
    int mi = tid & 63, kkb = tid >> 6;
#pragma unroll
    for (int i = 0; i < 4; i++) {
      int kk = kkb * 4 + i;
      int c = k0 + kk;
      float xv = x[((size_t)(b * 192 + c) << 12) + l0 + mi];
      As[kk][mi] = (xv - mu) * rs * gamma[c] + beta[c];
      Bs[kk][mi] = wT[(size_t)c * 768 + n0 + mi];
    }
    __syncthreads();
#pragma unroll
    for (int kk = 0; kk < 16; kk++) {
      float a[4], bb[4];
#pragma unroll
      for (int i = 0; i < 4; i++) a[i] = As[kk][ty + 16 * i];
#pragma unroll
      for (int j = 0; j < 4; j++) bb[j] = Bs[kk][tx + 16 * j];
#pragma unroll
      for (int i = 0; i < 4; i++)
#pragma unroll
        for (int j = 0; j < 4; j++) acc[i][j] = fmaf(a[i], bb[j], acc[i][j]);
    }
    __syncthreads();
  }
  int hrow = l0 >> 6;
  bool odd = hrow & 1;
#pragma unroll
  for (int i = 0; i < 4; i++) {
    int w = ty + 16 * i;
    int ls = odd ? (hrow << 6) + (63 - w) : l0 + w;   // snake position
#pragma unroll
    for (int j = 0; j < 4; j++) {
      int d = n0 + tx + 16 * j;
      float v = acc[i][j];
      if (d < DIN)
        u[((size_t)(b << 12) + ls) * DIN + d] = v;
      else
        z[((size_t)(b << 12) + l0 + w) * DIN + (d - DIN)] = v;
    }
  }
}

// ---------------------------------------------------------------------------
// Causal depthwise conv1d (kernel 4) along snake sequence + SiLU.
// ---------------------------------------------------------------------------
__global__ __launch_bounds__(256) void conv_silu(
    const float* __restrict__ u, const float* __restrict__ cw,
    const float* __restrict__ cb, float* __restrict__ uc) {
  int gid = blockIdx.x * 256 + threadIdx.x;   // over 16384*96
  int g = gid % 96;
  int bl = gid / 96;
  int b = bl >> 12, l = bl & 4095;
  int d0 = g << 2;
  float4 acc = *(const float4*)&cb[d0];
#pragma unroll
  for (int k = 0; k < 4; k++) {
    int lk = l - 3 + k;
    if (lk >= 0) {
      const float4 v = *(const float4*)&u[((size_t)(b << 12) + lk) * DIN + d0];
      acc.x = fmaf(v.x, cw[(d0 + 0) * 4 + k], acc.x);
      acc.y = fmaf(v.y, cw[(d0 + 1) * 4 + k], acc.y);
      acc.z = fmaf(v.z, cw[(d0 + 2) * 4 + k], acc.z);
      acc.w = fmaf(v.w, cw[(d0 + 3) * 4 + k], acc.w);
    }
  }
  acc.x = silu_f(acc.x);
  acc.y = silu_f(acc.y);
  acc.z = silu_f(acc.z);
  acc.w = silu_f(acc.w);
  *(float4*)&uc[(size_t)bl * DIN + d0] = acc;
}

// ---------------------------------------------------------------------------
// x_proj: uc [16384,384] @ wT_xp [384,44] -> dt[12] / B[16] / C[16].
// ---------------------------------------------------------------------------
__global__ __launch_bounds__(256) void xproj(
    const float* __restrict__ uc, const float* __restrict__ wT,
    float* __restrict__ dtb, float* __restrict__ Bmb, float* __restrict__ Cmb) {
  __shared__ float As[64][33];
  __shared__ float Bs[64][48];
  int m0 = blockIdx.x << 5;
  int tid = threadIdx.x;
  int r = tid & 31, q = tid >> 5;
  float acc[6] = {};
  for (int k0 = 0; k0 < 384; k0 += 64) {
    int rl = tid >> 3, kl = (tid & 7) << 3;
    const float4 v0 = *(const float4*)&uc[(size_t)(m0 + rl) * DIN + k0 + kl];
    const float4 v1 = *(const float4*)&uc[(size_t)(m0 + rl) * DIN + k0 + kl + 4];
    As[kl + 0][rl] = v0.x; As[kl + 1][rl] = v0.y; As[kl + 2][rl] = v0.z; As[kl + 3][rl] = v0.w;
    As[kl + 4][rl] = v1.x; As[kl + 5][rl] = v1.y; As[kl + 6][rl] = v1.z; As[kl + 7][rl] = v1.w;
    for (int i = tid; i < 64 * 48; i += 256) {
      int kk = i / 48, nn = i % 48;
      Bs[kk][nn] = (nn < 44) ? wT[(size_t)(k0 + kk) * 44 + nn] : 0.f;
    }
    __syncthreads();
#pragma unroll 8
    for (int kk = 0; kk < 64; kk++) {
      float a = As[kk][r];
#pragma unroll
      for (int j = 0; j < 6; j++) acc[j] = fmaf(a, Bs[kk][q + 8 * j], acc[j]);
    }
    __syncthreads();
  }
  size_t m = m0 + r;
#pragma unroll
  for (int j = 0; j < 6; j++) {
    int n = q + 8 * j;
    if (n < 12) dtb[m * 12 + n] = acc[j];
    else if (n < 28) Bmb[m * 16 + (n - 12)] = acc[j];
    else if (n < 44) Cmb[m * 16 + (n - 28)] = acc[j];
  }
}

// ---------------------------------------------------------------------------
// dt_proj + softplus
// ---------------------------------------------------------------------------
__global__ __launch_bounds__(256) void dtproj(
    const float* __restrict__ dtb, const float* __restrict__ wT,
    const float* __restrict__ bias, float* __restrict__ delta) {
  int gid = blockIdx.x * 256 + threadIdx.x;   // 16384*96
  int g = gid % 96;
  int m = gid / 96;
  int d0 = g << 2;
  float4 acc = *(const float4*)&bias[d0];
  const float* dtr = &dtb[(size_t)m * 12];
#pragma unroll
  for (int r = 0; r < 12; r++) {
    float t = dtr[r];
    const float4 wv = *(const float4*)&wT[(size_t)r * DIN + d0];
    acc.x = fmaf(t, wv.x, acc.x);
    acc.y = fmaf(t, wv.y, acc.y);
    acc.z = fmaf(t, wv.z, acc.z);
    acc.w = fmaf(t, wv.w, acc.w);
  }
  acc.x = softplus_f(acc.x);
  acc.y = softplus_f(acc.y);
  acc.z = softplus_f(acc.z);
  acc.w = softplus_f(acc.w);
  *(float4*)&delta[(size_t)m * DIN + d0] = acc;
}

// ---------------------------------------------------------------------------
// Chunked selective scan, 4 n-states per thread.
// Block = (b, 64-d-group, chunk); 256 threads: dloc = t>>2 (0..63), q = t&3
// (states n = 4q..4q+3). Cross-lane y-reduce = 2 ds_swizzle within the quad.
// Phase A: local scan from h=0 -> h_end + decay P = exp(a * sum(delta)).
// Phase B: sequential combine over 64 chunks -> h_in.
// Phase C: redo with correct h_in; y kept in registers (yk[16], static idx),
//          gate/Dskip/un-snake epilogue once per chunk.
// ---------------------------------------------------------------------------
__global__ __launch_bounds__(256) void scan_partial(
    const float* __restrict__ delta, const float* __restrict__ uc,
    const float* __restrict__ Bmb, const float* __restrict__ A_log,
    float* __restrict__ hend, float* __restrict__ Pbuf) {
  int bid = blockIdx.x;
  int chunk = bid & 63, bg = bid >> 6;
  int b = bg / 6, g = bg % 6;
  int t = threadIdx.x;
  int dloc = t >> 2, q = t & 3;
  int d = g * 64 + dloc;
  __shared__ float sD[64][64], sU[64][64], sB[64][16];
  size_t baseBL = ((size_t)b << 12) + chunk * 64;
  {
    int row = t >> 2, cg = (t & 3) * 16;
    const float* dp = &delta[(baseBL + row) * DIN + g * 64 + cg];
    const float* up = &uc[(baseBL + row) * DIN + g * 64 + cg];
#pragma unroll
    for (int c = 0; c < 4; c++) {
      *(float4*)&sD[row][cg + 4 * c] = *(const float4*)&dp[4 * c];
      *(float4*)&sU[row][cg + 4 * c] = *(const float4*)&up[4 * c];
    }
    *(float4*)&sB[row][q * 4] = *(const float4*)&Bmb[(baseBL + row) * 16 + q * 4];
  }
  __syncthreads();
  float4 av = *(const float4*)&A_log[d * 16 + 4 * q];
  float a0 = -__expf(av.x), a1 = -__expf(av.y), a2 = -__expf(av.z), a3 = -__expf(av.w);
  float h0 = 0.f, h1 = 0.f, h2 = 0.f, h3 = 0.f, sdel = 0.f;
#pragma unroll 8
  for (int ll = 0; ll < 64; ll++) {
    float dv = sD[ll][dloc];
    float uv = sU[ll][dloc];
    float4 Bv = *(const float4*)&sB[ll][q * 4];
    float duv = dv * uv;
    h0 = fmaf(__expf(dv * a0), h0, duv * Bv.x);
    h1 = fmaf(__expf(dv * a1), h1, duv * Bv.y);
    h2 = fmaf(__expf(dv * a2), h2, duv * Bv.z);
    h3 = fmaf(__expf(dv * a3), h3, duv * Bv.w);
    sdel += dv;
  }
  size_t e = ((size_t)(b * DIN + d)) * 16 + 4 * q;
  float4 hv; hv.x = h0; hv.y = h1; hv.z = h2; hv.w = h3;
  *(float4*)&hend[(size_t)chunk * NELEM + e] = hv;
  float4 pv;
  pv.x = __expf(a0 * sdel); pv.y = __expf(a1 * sdel);
  pv.z = __expf(a2 * sdel); pv.w = __expf(a3 * sdel);
  *(float4*)&Pbuf[(size_t)chunk * NELEM + e] = pv;
}

__global__ __launch_bounds__(256) void scan_combine(
    const float* __restrict__ hend, const float* __restrict__ Pbuf,
    float* __restrict__ hin) {
  int e = blockIdx.x * 256 + threadIdx.x;   // 0..24575
  float h = 0.f;
  float Pc = Pbuf[e], Hc = hend[e];
#pragma unroll 8
  for (int c = 0; c < NCHUNK; c++) {
    float Pn = 0.f, Hn = 0.f;
    if (c < NCHUNK - 1) {
      Pn = Pbuf[(size_t)(c + 1) * NELEM + e];
      Hn = hend[(size_t)(c + 1) * NELEM + e];
    }
    hin[(size_t)c * NELEM + e] = h;
    h = fmaf(Pc, h, Hc);
    Pc = Pn; Hc = Hn;
  }
}

__global__ __launch_bounds__(256) void scan_final(
    const float* __restrict__ delta, const float* __restrict__ uc,
    const float* __restrict__ Bmb, const float* __restrict__ Cmb,
    const float* __restrict__ A_log, const float* __restrict__ Dskip,
    const float* __restrict__ z, const float* __restrict__ hin,
    float* __restrict__ yr) {
  int bid = blockIdx.x;
  int chunk = bid & 63, bg = bid >> 6;
  int b = bg / 6, g = bg % 6;
  int t = threadIdx.x;
  int dloc = t >> 2, q = t & 3;
  int d = g * 64 + dloc;
  __shared__ float sD[64][64], sU[64][64], sB[64][16], sC[64][16];
  size_t baseBL = ((size_t)b << 12) + chunk * 64;
  {
    int row = t >> 2, cg = (t & 3) * 16;
    const float* dp = &delta[(baseBL + row) * DIN + g * 64 + cg];
    const float* up = &uc[(baseBL + row) * DIN + g * 64 + cg];
#pragma unroll
    for (int c = 0; c < 4; c++) {
      *(float4*)&sD[row][cg + 4 * c] = *(const float4*)&dp[4 * c];
      *(float4*)&sU[row][cg + 4 * c] = *(const float4*)&up[4 * c];
    }
    *(float4*)&sB[row][q * 4] = *(const float4*)&Bmb[(baseBL + row) * 16 + q * 4];
    *(float4*)&sC[row][q * 4] = *(const float4*)&Cmb[(baseBL + row) * 16 + q * 4];
  }
  __syncthreads();
  float4 av = *(const float4*)&A_log[d * 16 + 4 * q];
  float a0 = -__expf(av.x), a1 = -__expf(av.y), a2 = -__expf(av.z), a3 = -__expf(av.w);
  size_t e = ((size_t)(b * DIN + d)) * 16 + 4 * q;
  float4 hv = *(const float4*)&hin[(size_t)chunk * NELEM + e];
  float h0 = hv.x, h1 = hv.y, h2 = hv.z, h3 = hv.w;
  float yk[16];
#pragma unroll
  for (int ll = 0; ll < 64; ll++) {
    float dv = sD[ll][dloc];
    float uv = sU[ll][dloc];
    float4 Bv = *(const float4*)&sB[ll][q * 4];
    float4 Cv = *(const float4*)&sC[ll][q * 4];
    float duv = dv * uv;
    h0 = fmaf(__expf(dv * a0), h0, duv * Bv.x);
    h1 = fmaf(__expf(dv * a1), h1, duv * Bv.y);
    h2 = fmaf(__expf(dv * a2), h2, duv * Bv.z);
    h3 = fmaf(__expf(dv * a3), h3, duv * Bv.w);
    float yp = h0 * Cv.x + h1 * Cv.y + h2 * Cv.z + h3 * Cv.w;
    yp += quadswz<0x041F>(yp);   // xor 1 within quad
    yp += quadswz<0x081F>(yp);   // xor 2 within quad -> all 4 lanes have sum
    if ((ll & 3) == q) yk[ll >> 2] = yp;
  }
  float dsk = Dskip[d];
  bool odd = chunk & 1;
#pragma unroll
  for (int i = 0; i < 16; i++) {
    int ll = 4 * i + q;
    int wr = odd ? 63 - ll : ll;          // raster column for snake step ll
    size_t ro = baseBL + wr;              // raster row offset (hrow == chunk)
    float uvll = sU[ll][dloc];
    float zv = z[ro * DIN + d];
    yr[ro * DIN + d] = (yk[i] + uvll * dsk) * silu_f(zv);
  }
}

// ---------------------------------------------------------------------------
// Depthwise 3x3 local enhancement + residual (raster space).
// ---------------------------------------------------------------------------
__global__ __launch_bounds__(256) void le_conv(
    const float* __restrict__ yr, const float* __restrict__ lw, float* __restrict__ y2) {
  int gid = blockIdx.x * 256 + threadIdx.x;   // 16384*96
  int g = gid % 96;
  int bl = gid / 96;
  int b = bl >> 12, l = bl & 4095;
  int hrow = l >> 6, w = l & 63;
  int d0 = g << 2;
  float4 acc = *(const float4*)&yr[(size_t)bl * DIN + d0];   // residual
#pragma unroll
  for (int ki = 0; ki < 3; ki++) {
    int hh = hrow + ki - 1;
    if ((unsigned)hh >= 64u) continue;
#pragma unroll
    for (int kj = 0; kj < 3; kj++) {
      int ww = w + kj - 1;
      if ((unsigned)ww >= 64u) continue;
      const float4 v = *(const float4*)&yr[((size_t)((b << 12) + (hh << 6) + ww)) * DIN + d0];
      int wi = ki * 3 + kj;
      acc.x = fmaf(v.x, lw[(d0 + 0) * 9 + wi], acc.x);
      acc.y = fmaf(v.y, lw[(d0 + 1) * 9 + wi], acc.y);
      acc.z = fmaf(v.z, lw[(d0 + 2) * 9 + wi], acc.z);
      acc.w = fmaf(v.w, lw[(d0 + 3) * 9 + wi], acc.w);
    }
  }
  *(float4*)&y2[(size_t)bl * DIN + d0] = acc;
}

// ---------------------------------------------------------------------------
// Generic 64x64-tile fp32 GEMM: C[M,N] = A[M,K] @ Bw[K,N] (Bw pre-transposed).
// TRANSOUT: write C transposed per batch into [B, N, 4096] layout (proj_out).
// ---------------------------------------------------------------------------
template <int KDIM, int NDIM, bool TRANSOUT>
__global__ __launch_bounds__(256) void gemm64(
    const float* __restrict__ A, const float* __restrict__ Bw, float* __restrict__ C) {
  int mt = blockIdx.x & 255, nt = blockIdx.x >> 8;
  int m0 = mt * 64, n0 = nt * 64;
  __shared__ float As[16][65];
  __shared__ float Bs[16][64];
  int tid = threadIdx.x;
  int ty = tid >> 4, tx = tid & 15;
  float acc[4][4] = {};
  for (int k0 = 0; k0 < KDIM; k0 += 16) {
    {
      int row = tid >> 2, ks = (tid & 3) * 4;
      const float4 v = *(const float4*)&A[(size_t)(m0 + row) * KDIM + k0 + ks];
      As[ks + 0][row] = v.x; As[ks + 1][row] = v.y; As[ks + 2][row] = v.z; As[ks + 3][row] = v.w;
    }
    {
      int ni = tid & 63, kkb = tid >> 6;
#pragma unroll
      for (int i = 0; i < 4; i++) {
        int kk = kkb * 4 + i;
        Bs[kk][ni] = Bw[(size_t)(k0 + kk) * NDIM + n0 + ni];
      }
    }
    __syncthreads();
#pragma unroll
    for (int kk = 0; kk < 16; kk++) {
      float a[4], bb[4];
#pragma unroll
      for (int i = 0; i < 4; i++) a[i] = As[kk][ty + 16 * i];
#pragma unroll
      for (int j = 0; j < 4; j++) bb[j] = Bs[kk][tx + 16 * j];
#pragma unroll
      for (int i = 0; i < 4; i++)
#pragma unroll
        for (int j = 0; j < 4; j++) acc[i][j] = fmaf(a[i], bb[j], acc[i][j]);
    }
    __syncthreads();
  }
  if constexpr (!TRANSOUT) {
#pragma unroll
    for (int i = 0; i < 4; i++) {
      size_t m = m0 + ty + 16 * i;
#pragma unroll
      for (int j = 0; j < 4; j++) C[m * NDIM + n0 + tx + 16 * j] = acc[i][j];
    }
  } else {
    __shared__ float Cs[64][65];
#pragma unroll
    for (int i = 0; i < 4; i++)
#pragma unroll
      for (int j = 0; j < 4; j++) Cs[tx + 16 * j][ty + 16 * i] = acc[i][j];
    __syncthreads();
    int b = m0 >> 12, l0 = m0 & 4095;
    int li = tid & 63;
#pragma unroll
    for (int rr = 0; rr < 16; rr++) {
      int o = rr * 4 + (tid >> 6);
      C[(size_t)(b * CC + n0 + o) * CL + l0 + li] = Cs[o][li];
    }
  }
}

// ---------------------------------------------------------------------------
extern "C" void kernel_launch(void* const* d_in, const int* in_sizes, int n_in,
                              void* d_out, int out_size, void* d_ws, size_t ws_size,
                              hipStream_t stream) {
  const float* x          = (const float*)d_in[0];
  const float* gn_gamma   = (const float*)d_in[1];
  const float* gn_beta    = (const float*)d_in[2];
  const float* in_proj_w  = (const float*)d_in[3];
  const float* conv1d_w   = (const float*)d_in[4];
  const float* conv1d_b   = (const float*)d_in[5];
  const float* x_proj_w   = (const float*)d_in[6];
  const float* dt_proj_w  = (const float*)d_in[7];
  const float* dt_proj_b  = (const float*)d_in[8];
  const float* A_log      = (const float*)d_in[9];
  const float* Dskip      = (const float*)d_in[10];
  const float* le_w       = (const float*)d_in[11];
  const float* out_proj_w = (const float*)d_in[12];
  const float* proj_out_w = (const float*)d_in[13];
  float* out = (float*)d_out;

  float* ws     = (float*)d_ws;
  float* part   = ws + WS_PART;
  float* stat   = ws + WS_STAT;
  float* wT_in  = ws + WS_WTIN;
  float* wT_xp  = ws + WS_WTXP;
  float* wT_dt  = ws + WS_WTDT;
  float* wT_out = ws + WS_WTOUT;
  float* wT_po  = ws + WS_WTPO;
  float* u      = ws + WS_BIG;
  float* zb     = u + BIGSZ;
  float* uc     = zb + BIGSZ;
  float* delta  = uc + BIGSZ;
  float* yr     = delta + BIGSZ;
  float* dtb    = yr + BIGSZ;
  float* Bmb    = dtb + NBL * DTR;
  float* Cmb    = Bmb + NBL * NST;
  float* y2     = uc;      // reuse: uc dead after scan
  float* outseq = u;       // reuse: u dead after conv + scan phases
  // scan scratch aliases u (dead after conv_silu, reborn as outseq after scan)
  float* hend   = u;                         // 64*24576 = 1572864 floats
  float* Pbuf   = u + (size_t)NCHUNK * NELEM;
  float* hin    = u + 2 * (size_t)NCHUNK * NELEM;  // total 4718592 <= BIGSZ

  gn_partial<<<256, 256, 0, stream>>>(x, part);
  gn_final<<<1, 256, 0, stream>>>(part, stat);
  transpose_all<<<1092, 256, 0, stream>>>(in_proj_w, x_proj_w, dt_proj_w,
                                          out_proj_w, proj_out_w, ws);
  gemm_inproj<<<256 * 12, 256, 0, stream>>>(x, wT_in, stat, gn_gamma, gn_beta, u, zb);
  conv_silu<<<6144, 256, 0, stream>>>(u, conv1d_w, conv1d_b, uc);
  xproj<<<512, 256, 0, stream>>>(uc, wT_xp, dtb, Bmb, Cmb);
  dtproj<<<6144, 256, 0, stream>>>(dtb, wT_dt, dt_proj_b, delta);
  scan_partial<<<1536, 256, 0, stream>>>(delta, uc, Bmb, A_log, hend, Pbuf);
  scan_combine<<<96, 256, 0, stream>>>(hend, Pbuf, hin);
  scan_final<<<1536, 256, 0, stream>>>(delta, uc, Bmb, Cmb, A_log, Dskip,
                                       zb, hin, yr);
  le_conv<<<6144, 256, 0, stream>>>(yr, le_w, y2);
  gemm64<384, 192, false><<<256 * 3, 256, 0, stream>>>(y2, wT_out, outseq);
  gemm64<192, 192, true><<<256 * 3, 256, 0, stream>>>(outseq, wT_po, out);
}

// Round 5
// 396.722 us; speedup vs baseline: 3.8921x; 1.2870x over previous
//
#include <hip/hip_runtime.h>
#include <cstddef>

// Problem constants
constexpr int CB  = 4;
constexpr int CC  = 192;
constexpr int CH  = 64;
constexpr int CW  = 64;
constexpr int CL  = CH * CW;        // 4096
constexpr int DIN = 384;
constexpr int NST = 16;
constexpr int DTR = 12;

constexpr int NCHUNK = 64;          // chunks per sequence (= image rows)
constexpr int NELEM  = CB * DIN * NST; // 24576 independent (b,d,n) recurrences

// Workspace layout (in floats)
constexpr int WS_PART  = 0;                          // 512
constexpr int WS_STAT  = 512;                        // 8
constexpr int WS_BFIN  = 1024;                       // 147456 f16 = 73728 fl
constexpr int WS_BFOUT = WS_BFIN + 73728;            // 73728 f16 = 36864 fl
constexpr int WS_BFPO  = WS_BFOUT + 36864;           // 36864 f16 = 18432 fl
constexpr int WS_WTXP  = WS_BFPO + 18432;            // 16896 fl
constexpr int WS_WTDT  = WS_WTXP + 16896;            // 4608 fl
constexpr int WS_BIG   = WS_WTDT + 4608;             // = 151552
constexpr size_t NBL   = (size_t)CB * CL;            // 16384
constexpr size_t BIGSZ = NBL * DIN;                  // 6291456 floats

using half8 = __attribute__((ext_vector_type(8))) _Float16;
using half4 = __attribute__((ext_vector_type(4))) _Float16;
using f32x4 = __attribute__((ext_vector_type(4))) float;

__device__ __forceinline__ float sigm(float v) { return 1.f / (1.f + __expf(-v)); }
__device__ __forceinline__ float silu_f(float v) { return v * sigm(v); }
__device__ __forceinline__ float softplus_f(float v) { return v > 20.f ? v : log1pf(__expf(v)); }
template <int PAT>
__device__ __forceinline__ float quadswz(float v) {
  return __int_as_float(__builtin_amdgcn_ds_swizzle(__float_as_int(v), PAT));
}

// ---------------------------------------------------------------------------
// GroupNorm(1, C): per-batch mean/var over C*H*W, two-stage deterministic.
// ---------------------------------------------------------------------------
__global__ __launch_bounds__(256) void gn_partial(const float* __restrict__ x,
                                                  float* __restrict__ part) {
  int b = blockIdx.x >> 6;          // 64 blocks per batch
  int chunk = blockIdx.x & 63;
  const float* px = x + (size_t)b * CC * CL + (size_t)chunk * 12288;
  float s = 0.f, s2 = 0.f;
  for (int i = threadIdx.x; i < 12288 / 4; i += 256) {
    float4 v = ((const float4*)px)[i];
    s  += v.x + v.y + v.z + v.w;
    s2 += v.x * v.x + v.y * v.y + v.z * v.z + v.w * v.w;
  }
  __shared__ float ls[4], ls2[4];
  for (int off = 32; off; off >>= 1) { s += __shfl_down(s, off); s2 += __shfl_down(s2, off); }
  int wid = threadIdx.x >> 6, lane = threadIdx.x & 63;
  if (lane == 0) { ls[wid] = s; ls2[wid] = s2; }
  __syncthreads();
  if (threadIdx.x == 0) {
    float t = 0.f, t2 = 0.f;
    for (int i = 0; i < 4; i++) { t += ls[i]; t2 += ls2[i]; }
    part[blockIdx.x * 2] = t;
    part[blockIdx.x * 2 + 1] = t2;
  }
}

__global__ __launch_bounds__(256) void gn_final(const float* __restrict__ part,
                                                float* __restrict__ stat) {
  int b = threadIdx.x >> 6;   // wave id == batch
  int i = threadIdx.x & 63;
  float s = part[(b * 64 + i) * 2];
  float s2 = part[(b * 64 + i) * 2 + 1];
  for (int off = 32; off; off >>= 1) { s += __shfl_down(s, off); s2 += __shfl_down(s2, off); }
  if (i == 0) {
    float n = (float)(CC * CL);
    float mu = s / n;
    float var = s2 / n - mu * mu;
    stat[b * 2] = mu;
    stat[b * 2 + 1] = rsqrtf(var + 1e-5f);
  }
}

// ---------------------------------------------------------------------------
// Weight prep: pack the three GEMM weights into fp16 MFMA B-fragment layout,
// plus fp32 transposes for xproj/dtproj.
// Frag layout: idx = ((nt*KS + ks)*4 + colq)*512 + lane*8 + j
//   col = nt*64 + colq*16 + (lane&15); k = ks*32 + (lane>>4)*8 + j
//   value = W[col*KDIM + k]
// ---------------------------------------------------------------------------
__device__ __forceinline__ void pack_frag(_Float16* dst, int idx, int KS,
                                          const float* __restrict__ W, int KDIM) {
  int j = idx & 7, lane = (idx >> 3) & 63, colq = (idx >> 9) & 3, rest = idx >> 11;
  int ks = rest % KS, nt = rest / KS;
  int col = nt * 64 + colq * 16 + (lane & 15);
  int k = ks * 32 + ((lane >> 4) << 3) + j;
  dst[idx] = (_Float16)W[(size_t)col * KDIM + k];
}

__global__ __launch_bounds__(256) void transpose_all(
    const float* __restrict__ in_proj_w, const float* __restrict__ x_proj_w,
    const float* __restrict__ dt_proj_w, const float* __restrict__ out_proj_w,
    const float* __restrict__ proj_out_w, float* __restrict__ ws) {
  int idx = blockIdx.x * 256 + threadIdx.x;
  if (idx < 147456) {                 // in_proj: 768 cols x 192 k, KS=6
    pack_frag((_Float16*)(ws + WS_BFIN), idx, 6, in_proj_w, 192);
    return;
  }
  idx -= 147456;
  if (idx < 73728) {                  // out_proj: 192 cols x 384 k, KS=12
    pack_frag((_Float16*)(ws + WS_BFOUT), idx, 12, out_proj_w, 384);
    return;
  }
  idx -= 73728;
  if (idx < 36864) {                  // proj_out: 192 cols x 192 k, KS=6
    pack_frag((_Float16*)(ws + WS_BFPO), idx, 6, proj_out_w, 192);
    return;
  }
  idx -= 36864;
  if (idx < 16896) {                  // wT_xp[k][e] = x_proj_w[e][k]
    int k = idx / 44, e = idx % 44;
    ws[WS_WTXP + idx] = x_proj_w[e * 384 + k];
    return;
  }
  idx -= 16896;
  if (idx < 4608) {                   // wT_dt[r][d] = dt_proj_w[d][r]
    int r = idx / 384, d = idx % 384;
    ws[WS_WTDT + idx] = dt_proj_w[d * 12 + r];
  }
}

// ---------------------------------------------------------------------------
// in_proj GEMM via fp16 MFMA: xn (GN fused on stage) @ W. M=16384, N=768,
// K=192. 64x64 tile, 4 waves (2x2), each 32x32 = 2x2 fragments.
// Epilogue routes u (snake) and z (raster).
// ---------------------------------------------------------------------------
__global__ __launch_bounds__(256) void gemm_inproj_mfma(
    const float* __restrict__ x, const _Float16* __restrict__ Bf,
    const float* __restrict__ stat, const float* __restrict__ gamma,
    const float* __restrict__ beta, float* __restrict__ u, float* __restrict__ z) {
  int mt = blockIdx.x & 255, nt = blockIdx.x >> 8;   // nt 0..11
  int m0 = mt * 64;
  int b = m0 >> 12, l0 = m0 & 4095;
  float mu = stat[b * 2], rs = stat[b * 2 + 1];
  __shared__ __align__(16) _Float16 Ah[64][200];
  int tid = threadIdx.x;
  int row = tid & 63, cq = tid >> 6;
  // Stage A (x is [c][l]-major; coalesced over l=row), fused GroupNorm.
#pragma unroll
  for (int i = 0; i < 12; i++) {
    int c0 = cq * 4 + i * 16;
    half4 h;
#pragma unroll
    for (int cc = 0; cc < 4; cc++) {
      int c = c0 + cc;
      float g = gamma[c] * rs;
      float bt = beta[c] - mu * g;
      float xv = x[((size_t)(b * 192 + c) << 12) + l0 + row];
      h[cc] = (_Float16)(xv * g + bt);
    }
    *(half4*)&Ah[row][c0] = h;
  }
  __syncthreads();
  int w = tid >> 6, lane = tid & 63;
  int wm = (w >> 1) * 32, wcol = w & 1;
  int r16 = lane & 15, kg = lane >> 4;
  f32x4 acc[2][2] = {};
#pragma unroll
  for (int ks = 0; ks < 6; ks++) {
    half8 a0 = *(const half8*)&Ah[wm + r16][ks * 32 + kg * 8];
    half8 a1 = *(const half8*)&Ah[wm + 16 + r16][ks * 32 + kg * 8];
    half8 b0 = *(const half8*)&Bf[(((size_t)(nt * 6 + ks) * 4 + wcol * 2 + 0) << 9) + lane * 8];
    half8 b1 = *(const half8*)&Bf[(((size_t)(nt * 6 + ks) * 4 + wcol * 2 + 1) << 9) + lane * 8];
    acc[0][0] = __builtin_amdgcn_mfma_f32_16x16x32_f16(a0, b0, acc[0][0], 0, 0, 0);
    acc[0][1] = __builtin_amdgcn_mfma_f32_16x16x32_f16(a0, b1, acc[0][1], 0, 0, 0);
    acc[1][0] = __builtin_amdgcn_mfma_f32_16x16x32_f16(a1, b0, acc[1][0], 0, 0, 0);
    acc[1][1] = __builtin_amdgcn_mfma_f32_16x16x32_f16(a1, b1, acc[1][1], 0, 0, 0);
  }
  int hrow = l0 >> 6;
  bool odd = hrow & 1;
#pragma unroll
  for (int mi = 0; mi < 2; mi++)
#pragma unroll
    for (int ni = 0; ni < 2; ni++)
#pragma unroll
      for (int r = 0; r < 4; r++) {
        int wloc = wm + mi * 16 + kg * 4 + r;
        int d = nt * 64 + wcol * 32 + ni * 16 + r16;
        float val = acc[mi][ni][r];
        if (d < DIN) {
          int ls = odd ? (hrow << 6) + 63 - wloc : l0 + wloc;
          u[((size_t)(b << 12) + ls) * DIN + d] = val;
        } else {
          z[((size_t)(b << 12) + l0 + wloc) * DIN + (d - DIN)] = val;
        }
      }
}

// ---------------------------------------------------------------------------
// Generic fp16-MFMA GEMM: C[M,N] = A[M,K] @ W; A fp32 row-major, W pre-packed
// frags. TRANSOUT: write transposed per batch into [B, N, 4096] (proj_out).
// ---------------------------------------------------------------------------
template <int KDIM, int NDIM, bool TRANSOUT>
__global__ __launch_bounds__(256) void gemm_mfma(
    const float* __restrict__ A, const _Float16* __restrict__ Bf,
    float* __restrict__ C) {
  constexpr int KS = KDIM / 32;
  int mt = blockIdx.x & 255, nt = blockIdx.x >> 8;
  int m0 = mt * 64, n0 = nt * 64;
  __shared__ __align__(16) _Float16 Ah[64][KDIM + 8];
  int tid = threadIdx.x;
  {
    int r16s = tid >> 4, kq = tid & 15;
#pragma unroll
    for (int rr = 0; rr < 4; rr++) {
      int rowi = r16s + rr * 16;
#pragma unroll
      for (int kk = 0; kk < KDIM / 64; kk++) {
        float4 v = *(const float4*)&A[(size_t)(m0 + rowi) * KDIM + kk * 64 + kq * 4];
        half4 h;
        h[0] = (_Float16)v.x; h[1] = (_Float16)v.y;
        h[2] = (_Float16)v.z; h[3] = (_Float16)v.w;
        *(half4*)&Ah[rowi][kk * 64 + kq * 4] = h;
      }
    }
  }
  __syncthreads();
  int w = tid >> 6, lane = tid & 63;
  int wm = (w >> 1) * 32, wcol = w & 1;
  int r16 = lane & 15, kg = lane >> 4;
  f32x4 acc[2][2] = {};
#pragma unroll
  for (int ks = 0; ks < KS; ks++) {
    half8 a0 = *(const half8*)&Ah[wm + r16][ks * 32 + kg * 8];
    half8 a1 = *(const half8*)&Ah[wm + 16 + r16][ks * 32 + kg * 8];
    half8 b0 = *(const half8*)&Bf[(((size_t)(nt * KS + ks) * 4 + wcol * 2 + 0) << 9) + lane * 8];
    half8 b1 = *(const half8*)&Bf[(((size_t)(nt * KS + ks) * 4 + wcol * 2 + 1) << 9) + lane * 8];
    acc[0][0] = __builtin_amdgcn_mfma_f32_16x16x32_f16(a0, b0, acc[0][0], 0, 0, 0);
    acc[0][1] = __builtin_amdgcn_mfma_f32_16x16x32_f16(a0, b1, acc[0][1], 0, 0, 0);
    acc[1][0] = __builtin_amdgcn_mfma_f32_16x16x32_f16(a1, b0, acc[1][0], 0, 0, 0);
    acc[1][1] = __builtin_amdgcn_mfma_f32_16x16x32_f16(a1, b1, acc[1][1], 0, 0, 0);
  }
  if constexpr (!TRANSOUT) {
#pragma unroll
    for (int mi = 0; mi < 2; mi++)
#pragma unroll
      for (int ni = 0; ni < 2; ni++)
#pragma unroll
        for (int r = 0; r < 4; r++) {
          int rowo = wm + mi * 16 + kg * 4 + r;
          int col = wcol * 32 + ni * 16 + r16;
          C[(size_t)(m0 + rowo) * NDIM + n0 + col] = acc[mi][ni][r];
        }
  } else {
    __shared__ float Cs[64][68];
#pragma unroll
    for (int mi = 0; mi < 2; mi++)
#pragma unroll
      for (int ni = 0; ni < 2; ni++)
#pragma unroll
        for (int r = 0; r < 4; r++)
          Cs[wcol * 32 + ni * 16 + r16][wm + mi * 16 + kg * 4 + r] = acc[mi][ni][r];
    __syncthreads();
    int b = m0 >> 12, l0 = m0 & 4095;
    int li = tid & 63;
#pragma unroll
    for (int rr = 0; rr < 16; rr++) {
      int o = rr * 4 + (tid >> 6);
      C[(size_t)(b * CC + n0 + o) * CL + l0 + li] = Cs[o][li];
    }
  }
}

// ---------------------------------------------------------------------------
// Causal depthwise conv1d (kernel 4) along snake sequence + SiLU.
// ---------------------------------------------------------------------------
__global__ __launch_bounds__(256) void conv_silu(
    const float* __restrict__ u, const float* __restrict__ cw,
    const float* __restrict__ cb, float* __restrict__ uc) {
  int gid = blockIdx.x * 256 + threadIdx.x;   // over 16384*96
  int g = gid % 96;
  int bl = gid / 96;
  int b = bl >> 12, l = bl & 4095;
  int d0 = g << 2;
  float4 acc = *(const float4*)&cb[d0];
#pragma unroll
  for (int k = 0; k < 4; k++) {
    int lk = l - 3 + k;
    if (lk >= 0) {
      const float4 v = *(const float4*)&u[((size_t)(b << 12) + lk) * DIN + d0];
      acc.x = fmaf(v.x, cw[(d0 + 0) * 4 + k], acc.x);
      acc.y = fmaf(v.y, cw[(d0 + 1) * 4 + k], acc.y);
      acc.z = fmaf(v.z, cw[(d0 + 2) * 4 + k], acc.z);
      acc.w = fmaf(v.w, cw[(d0 + 3) * 4 + k], acc.w);
    }
  }
  acc.x = silu_f(acc.x);
  acc.y = silu_f(acc.y);
  acc.z = silu_f(acc.z);
  acc.w = silu_f(acc.w);
  *(float4*)&uc[(size_t)bl * DIN + d0] = acc;
}

// ---------------------------------------------------------------------------
// x_proj: uc [16384,384] @ wT_xp [384,44] -> dt[12] / B[16] / C[16].
// ---------------------------------------------------------------------------
__global__ __launch_bounds__(256) void xproj(
    const float* __restrict__ uc, const float* __restrict__ wT,
    float* __restrict__ dtb, float* __restrict__ Bmb, float* __restrict__ Cmb) {
  __shared__ float As[64][33];
  __shared__ float Bs[64][48];
  int m0 = blockIdx.x << 5;
  int tid = threadIdx.x;
  int r = tid & 31, q = tid >> 5;
  float acc[6] = {};
  for (int k0 = 0; k0 < 384; k0 += 64) {
    int rl = tid >> 3, kl = (tid & 7) << 3;
    const float4 v0 = *(const float4*)&uc[(size_t)(m0 + rl) * DIN + k0 + kl];
    const float4 v1 = *(const float4*)&uc[(size_t)(m0 + rl) * DIN + k0 + kl + 4];
    As[kl + 0][rl] = v0.x; As[kl + 1][rl] = v0.y; As[kl + 2][rl] = v0.z; As[kl + 3][rl] = v0.w;
    As[kl + 4][rl] = v1.x; As[kl + 5][rl] = v1.y; As[kl + 6][rl] = v1.z; As[kl + 7][rl] = v1.w;
    for (int i = tid; i < 64 * 48; i += 256) {
      int kk = i / 48, nn = i % 48;
      Bs[kk][nn] = (nn < 44) ? wT[(size_t)(k0 + kk) * 44 + nn] : 0.f;
    }
    __syncthreads();
#pragma unroll 8
    for (int kk = 0; kk < 64; kk++) {
      float a = As[kk][r];
#pragma unroll
      for (int j = 0; j < 6; j++) acc[j] = fmaf(a, Bs[kk][q + 8 * j], acc[j]);
    }
    __syncthreads();
  }
  size_t m = m0 + r;
#pragma unroll
  for (int j = 0; j < 6; j++) {
    int n = q + 8 * j;
    if (n < 12) dtb[m * 12 + n] = acc[j];
    else if (n < 28) Bmb[m * 16 + (n - 12)] = acc[j];
    else if (n < 44) Cmb[m * 16 + (n - 28)] = acc[j];
  }
}

// ---------------------------------------------------------------------------
// dt_proj + softplus
// ---------------------------------------------------------------------------
__global__ __launch_bounds__(256) void dtproj(
    const float* __restrict__ dtb, const float* __restrict__ wT,
    const float* __restrict__ bias, float* __restrict__ delta) {
  int gid = blockIdx.x * 256 + threadIdx.x;   // 16384*96
  int g = gid % 96;
  int m = gid / 96;
  int d0 = g << 2;
  float4 acc = *(const float4*)&bias[d0];
  const float* dtr = &dtb[(size_t)m * 12];
#pragma unroll
  for (int r = 0; r < 12; r++) {
    float t = dtr[r];
    const float4 wv = *(const float4*)&wT[(size_t)r * DIN + d0];
    acc.x = fmaf(t, wv.x, acc.x);
    acc.y = fmaf(t, wv.y, acc.y);
    acc.z = fmaf(t, wv.z, acc.z);
    acc.w = fmaf(t, wv.w, acc.w);
  }
  acc.x = softplus_f(acc.x);
  acc.y = softplus_f(acc.y);
  acc.z = softplus_f(acc.z);
  acc.w = softplus_f(acc.w);
  *(float4*)&delta[(size_t)m * DIN + d0] = acc;
}

// ---------------------------------------------------------------------------
// Chunked selective scan, 4 n-states per thread (see Round-2 notes).
// ---------------------------------------------------------------------------
__global__ __launch_bounds__(256) void scan_partial(
    const float* __restrict__ delta, const float* __restrict__ uc,
    const float* __restrict__ Bmb, const float* __restrict__ A_log,
    float* __restrict__ hend, float* __restrict__ Pbuf) {
  int bid = blockIdx.x;
  int chunk = bid & 63, bg = bid >> 6;
  int b = bg / 6, g = bg % 6;
  int t = threadIdx.x;
  int dloc = t >> 2, q = t & 3;
  int d = g * 64 + dloc;
  __shared__ float sD[64][64], sU[64][64], sB[64][16];
  size_t baseBL = ((size_t)b << 12) + chunk * 64;
  {
    int row = t >> 2, cg = (t & 3) * 16;
    const float* dp = &delta[(baseBL + row) * DIN + g * 64 + cg];
    const float* up = &uc[(baseBL + row) * DIN + g * 64 + cg];
#pragma unroll
    for (int c = 0; c < 4; c++) {
      *(float4*)&sD[row][cg + 4 * c] = *(const float4*)&dp[4 * c];
      *(float4*)&sU[row][cg + 4 * c] = *(const float4*)&up[4 * c];
    }
    *(float4*)&sB[row][q * 4] = *(const float4*)&Bmb[(baseBL + row) * 16 + q * 4];
  }
  __syncthreads();
  float4 av = *(const float4*)&A_log[d * 16 + 4 * q];
  float a0 = -__expf(av.x), a1 = -__expf(av.y), a2 = -__expf(av.z), a3 = -__expf(av.w);
  float h0 = 0.f, h1 = 0.f, h2 = 0.f, h3 = 0.f, sdel = 0.f;
#pragma unroll 8
  for (int ll = 0; ll < 64; ll++) {
    float dv = sD[ll][dloc];
    float uv = sU[ll][dloc];
    float4 Bv = *(const float4*)&sB[ll][q * 4];
    float duv = dv * uv;
    h0 = fmaf(__expf(dv * a0), h0, duv * Bv.x);
    h1 = fmaf(__expf(dv * a1), h1, duv * Bv.y);
    h2 = fmaf(__expf(dv * a2), h2, duv * Bv.z);
    h3 = fmaf(__expf(dv * a3), h3, duv * Bv.w);
    sdel += dv;
  }
  size_t e = ((size_t)(b * DIN + d)) * 16 + 4 * q;
  float4 hv; hv.x = h0; hv.y = h1; hv.z = h2; hv.w = h3;
  *(float4*)&hend[(size_t)chunk * NELEM + e] = hv;
  float4 pv;
  pv.x = __expf(a0 * sdel); pv.y = __expf(a1 * sdel);
  pv.z = __expf(a2 * sdel); pv.w = __expf(a3 * sdel);
  *(float4*)&Pbuf[(size_t)chunk * NELEM + e] = pv;
}

__global__ __launch_bounds__(256) void scan_combine(
    const float* __restrict__ hend, const float* __restrict__ Pbuf,
    float* __restrict__ hin) {
  int e = blockIdx.x * 256 + threadIdx.x;   // 0..24575
  float h = 0.f;
  float Pc = Pbuf[e], Hc = hend[e];
#pragma unroll 8
  for (int c = 0; c < NCHUNK; c++) {
    float Pn = 0.f, Hn = 0.f;
    if (c < NCHUNK - 1) {
      Pn = Pbuf[(size_t)(c + 1) * NELEM + e];
      Hn = hend[(size_t)(c + 1) * NELEM + e];
    }
    hin[(size_t)c * NELEM + e] = h;
    h = fmaf(Pc, h, Hc);
    Pc = Pn; Hc = Hn;
  }
}

__global__ __launch_bounds__(256) void scan_final(
    const float* __restrict__ delta, const float* __restrict__ uc,
    const float* __restrict__ Bmb, const float* __restrict__ Cmb,
    const float* __restrict__ A_log, const float* __restrict__ Dskip,
    const float* __restrict__ z, const float* __restrict__ hin,
    float* __restrict__ yr) {
  int bid = blockIdx.x;
  int chunk = bid & 63, bg = bid >> 6;
  int b = bg / 6, g = bg % 6;
  int t = threadIdx.x;
  int dloc = t >> 2, q = t & 3;
  int d = g * 64 + dloc;
  __shared__ float sD[64][64], sU[64][64], sB[64][16], sC[64][16];
  size_t baseBL = ((size_t)b << 12) + chunk * 64;
  {
    int row = t >> 2, cg = (t & 3) * 16;
    const float* dp = &delta[(baseBL + row) * DIN + g * 64 + cg];
    const float* up = &uc[(baseBL + row) * DIN + g * 64 + cg];
#pragma unroll
    for (int c = 0; c < 4; c++) {
      *(float4*)&sD[row][cg + 4 * c] = *(const float4*)&dp[4 * c];
      *(float4*)&sU[row][cg + 4 * c] = *(const float4*)&up[4 * c];
    }
    *(float4*)&sB[row][q * 4] = *(const float4*)&Bmb[(baseBL + row) * 16 + q * 4];
    *(float4*)&sC[row][q * 4] = *(const float4*)&Cmb[(baseBL + row) * 16 + q * 4];
  }
  __syncthreads();
  float4 av = *(const float4*)&A_log[d * 16 + 4 * q];
  float a0 = -__expf(av.x), a1 = -__expf(av.y), a2 = -__expf(av.z), a3 = -__expf(av.w);
  size_t e = ((size_t)(b * DIN + d)) * 16 + 4 * q;
  float4 hv = *(const float4*)&hin[(size_t)chunk * NELEM + e];
  float h0 = hv.x, h1 = hv.y, h2 = hv.z, h3 = hv.w;
  float yk[16];
#pragma unroll
  for (int ll = 0; ll < 64; ll++) {
    float dv = sD[ll][dloc];
    float uv = sU[ll][dloc];
    float4 Bv = *(const float4*)&sB[ll][q * 4];
    float4 Cv = *(const float4*)&sC[ll][q * 4];
    float duv = dv * uv;
    h0 = fmaf(__expf(dv * a0), h0, duv * Bv.x);
    h1 = fmaf(__expf(dv * a1), h1, duv * Bv.y);
    h2 = fmaf(__expf(dv * a2), h2, duv * Bv.z);
    h3 = fmaf(__expf(dv * a3), h3, duv * Bv.w);
    float yp = h0 * Cv.x + h1 * Cv.y + h2 * Cv.z + h3 * Cv.w;
    yp += quadswz<0x041F>(yp);   // xor 1 within quad
    yp += quadswz<0x081F>(yp);   // xor 2 within quad -> all 4 lanes have sum
    if ((ll & 3) == q) yk[ll >> 2] = yp;
  }
  float dsk = Dskip[d];
  bool odd = chunk & 1;
#pragma unroll
  for (int i = 0; i < 16; i++) {
    int ll = 4 * i + q;
    int wr = odd ? 63 - ll : ll;          // raster column for snake step ll
    size_t ro = baseBL + wr;              // raster row offset (hrow == chunk)
    float uvll = sU[ll][dloc];
    float zv = z[ro * DIN + d];
    yr[ro * DIN + d] = (yk[i] + uvll * dsk) * silu_f(zv);
  }
}

// ---------------------------------------------------------------------------
// Depthwise 3x3 local enhancement + residual (raster space).
// ---------------------------------------------------------------------------
__global__ __launch_bounds__(256) void le_conv(
    const float* __restrict__ yr, const float* __restrict__ lw, float* __restrict__ y2) {
  int gid = blockIdx.x * 256 + threadIdx.x;   // 16384*96
  int g = gid % 96;
  int bl = gid / 96;
  int b = bl >> 12, l = bl & 4095;
  int hrow = l >> 6, w = l & 63;
  int d0 = g << 2;
  float4 acc = *(const float4*)&yr[(size_t)bl * DIN + d0];   // residual
#pragma unroll
  for (int ki = 0; ki < 3; ki++) {
    int hh = hrow + ki - 1;
    if ((unsigned)hh >= 64u) continue;
#pragma unroll
    for (int kj = 0; kj < 3; kj++) {
      int ww = w + kj - 1;
      if ((unsigned)ww >= 64u) continue;
      const float4 v = *(const float4*)&yr[((size_t)((b << 12) + (hh << 6) + ww)) * DIN + d0];
      int wi = ki * 3 + kj;
      acc.x = fmaf(v.x, lw[(d0 + 0) * 9 + wi], acc.x);
      acc.y = fmaf(v.y, lw[(d0 + 1) * 9 + wi], acc.y);
      acc.z = fmaf(v.z, lw[(d0 + 2) * 9 + wi], acc.z);
      acc.w = fmaf(v.w, lw[(d0 + 3) * 9 + wi], acc.w);
    }
  }
  *(float4*)&y2[(size_t)bl * DIN + d0] = acc;
}

// ---------------------------------------------------------------------------
extern "C" void kernel_launch(void* const* d_in, const int* in_sizes, int n_in,
                              void* d_out, int out_size, void* d_ws, size_t ws_size,
                              hipStream_t stream) {
  const float* x          = (const float*)d_in[0];
  const float* gn_gamma   = (const float*)d_in[1];
  const float* gn_beta    = (const float*)d_in[2];
  const float* in_proj_w  = (const float*)d_in[3];
  const float* conv1d_w   = (const float*)d_in[4];
  const float* conv1d_b   = (const float*)d_in[5];
  const float* x_proj_w   = (const float*)d_in[6];
  const float* dt_proj_w  = (const float*)d_in[7];
  const float* dt_proj_b  = (const float*)d_in[8];
  const float* A_log      = (const float*)d_in[9];
  const float* Dskip      = (const float*)d_in[10];
  const float* le_w       = (const float*)d_in[11];
  const float* out_proj_w = (const float*)d_in[12];
  const float* proj_out_w = (const float*)d_in[13];
  float* out = (float*)d_out;

  float* ws      = (float*)d_ws;
  float* part    = ws + WS_PART;
  float* stat    = ws + WS_STAT;
  _Float16* BfIn  = (_Float16*)(ws + WS_BFIN);
  _Float16* BfOut = (_Float16*)(ws + WS_BFOUT);
  _Float16* BfPo  = (_Float16*)(ws + WS_BFPO);
  float* wT_xp  = ws + WS_WTXP;
  float* wT_dt  = ws + WS_WTDT;
  float* u      = ws + WS_BIG;
  float* zb     = u + BIGSZ;
  float* uc     = zb + BIGSZ;
  float* delta  = uc + BIGSZ;
  float* yr     = delta + BIGSZ;
  float* dtb    = yr + BIGSZ;
  float* Bmb    = dtb + NBL * DTR;
  float* Cmb    = Bmb + NBL * NST;
  float* y2     = uc;      // reuse: uc dead after scan
  float* outseq = u;       // reuse: u dead after conv + scan phases
  // scan scratch aliases u (dead after conv_silu, reborn as outseq after scan)
  float* hend   = u;                         // 64*24576 = 1572864 floats
  float* Pbuf   = u + (size_t)NCHUNK * NELEM;
  float* hin    = u + 2 * (size_t)NCHUNK * NELEM;  // total 4718592 <= BIGSZ

  gn_partial<<<256, 256, 0, stream>>>(x, part);
  gn_final<<<1, 256, 0, stream>>>(part, stat);
  transpose_all<<<1092, 256, 0, stream>>>(in_proj_w, x_proj_w, dt_proj_w,
                                          out_proj_w, proj_out_w, ws);
  gemm_inproj_mfma<<<256 * 12, 256, 0, stream>>>(x, BfIn, stat, gn_gamma, gn_beta, u, zb);
  conv_silu<<<6144, 256, 0, stream>>>(u, conv1d_w, conv1d_b, uc);
  xproj<<<512, 256, 0, stream>>>(uc, wT_xp, dtb, Bmb, Cmb);
  dtproj<<<6144, 256, 0, stream>>>(dtb, wT_dt, dt_proj_b, delta);
  scan_partial<<<1536, 256, 0, stream>>>(delta, uc, Bmb, A_log, hend, Pbuf);
  scan_combine<<<96, 256, 0, stream>>>(hend, Pbuf, hin);
  scan_final<<<1536, 256, 0, stream>>>(delta, uc, Bmb, Cmb, A_log, Dskip,
                                       zb, hin, yr);
  le_conv<<<6144, 256, 0, stream>>>(yr, le_w, y2);
  gemm_mfma<384, 192, false><<<256 * 3, 256, 0, stream>>>(y2, BfOut, outseq);
  gemm_mfma<192, 192, true><<<256 * 3, 256, 0, stream>>>(outseq, BfPo, out);
}

// Round 6
// 351.477 us; speedup vs baseline: 4.3931x; 1.1287x over previous
//
#include <hip/hip_runtime.h>
#include <cstddef>

// Problem constants
constexpr int CB  = 4;
constexpr int CC  = 192;
constexpr int CH  = 64;
constexpr int CW  = 64;
constexpr int CL  = CH * CW;        // 4096
constexpr int DIN = 384;
constexpr int NST = 16;
constexpr int DTR = 12;

constexpr int NCHUNK = 64;          // chunks per sequence (= image rows)
constexpr int NELEM  = CB * DIN * NST; // 24576 independent (b,d,n) recurrences

// Workspace layout (in floats)
constexpr int WS_PART  = 0;                          // 512
constexpr int WS_STAT  = 512;                        // 8
constexpr int WS_BFIN  = 1024;                       // 147456 f16 = 73728 fl
constexpr int WS_BFOUT = WS_BFIN + 73728;            // 73728 f16 = 36864 fl
constexpr int WS_BFPO  = WS_BFOUT + 36864;           // 36864 f16 = 18432 fl
constexpr int WS_BFXF  = WS_BFPO + 18432;            // 172032 f16 = 86016 fl
constexpr int WS_BIG   = WS_BFXF + 86016;            // = 216064
constexpr size_t NBL   = (size_t)CB * CL;            // 16384
constexpr size_t BIGSZ = NBL * DIN;                  // 6291456 floats

using half8 = __attribute__((ext_vector_type(8))) _Float16;
using half4 = __attribute__((ext_vector_type(4))) _Float16;
using f32x4 = __attribute__((ext_vector_type(4))) float;

__device__ __forceinline__ float sigm(float v) { return 1.f / (1.f + __expf(-v)); }
__device__ __forceinline__ float silu_f(float v) { return v * sigm(v); }
__device__ __forceinline__ float softplus_f(float v) { return v > 20.f ? v : log1pf(__expf(v)); }
template <int PAT>
__device__ __forceinline__ float quadswz(float v) {
  return __int_as_float(__builtin_amdgcn_ds_swizzle(__float_as_int(v), PAT));
}

// ---------------------------------------------------------------------------
// GroupNorm(1, C): per-batch mean/var over C*H*W, two-stage deterministic.
// ---------------------------------------------------------------------------
__global__ __launch_bounds__(256) void gn_partial(const float* __restrict__ x,
                                                  float* __restrict__ part) {
  int b = blockIdx.x >> 6;          // 64 blocks per batch
  int chunk = blockIdx.x & 63;
  const float* px = x + (size_t)b * CC * CL + (size_t)chunk * 12288;
  float s = 0.f, s2 = 0.f;
  for (int i = threadIdx.x; i < 12288 / 4; i += 256) {
    float4 v = ((const float4*)px)[i];
    s  += v.x + v.y + v.z + v.w;
    s2 += v.x * v.x + v.y * v.y + v.z * v.z + v.w * v.w;
  }
  __shared__ float ls[4], ls2[4];
  for (int off = 32; off; off >>= 1) { s += __shfl_down(s, off); s2 += __shfl_down(s2, off); }
  int wid = threadIdx.x >> 6, lane = threadIdx.x & 63;
  if (lane == 0) { ls[wid] = s; ls2[wid] = s2; }
  __syncthreads();
  if (threadIdx.x == 0) {
    float t = 0.f, t2 = 0.f;
    for (int i = 0; i < 4; i++) { t += ls[i]; t2 += ls2[i]; }
    part[blockIdx.x * 2] = t;
    part[blockIdx.x * 2 + 1] = t2;
  }
}

__global__ __launch_bounds__(256) void gn_final(const float* __restrict__ part,
                                                float* __restrict__ stat) {
  int b = threadIdx.x >> 6;   // wave id == batch
  int i = threadIdx.x & 63;
  float s = part[(b * 64 + i) * 2];
  float s2 = part[(b * 64 + i) * 2 + 1];
  for (int off = 32; off; off >>= 1) { s += __shfl_down(s, off); s2 += __shfl_down(s2, off); }
  if (i == 0) {
    float n = (float)(CC * CL);
    float mu = s / n;
    float var = s2 / n - mu * mu;
    stat[b * 2] = mu;
    stat[b * 2 + 1] = rsqrtf(var + 1e-5f);
  }
}

// ---------------------------------------------------------------------------
// Weight prep. MFMA B-fragment layout:
//   idx = ((nt*KS + ks)*4 + colq)*512 + lane*8 + j
//   col = nt*64 + colq*16 + (lane&15); k = ks*32 + (lane>>4)*8 + j
// For the fused x_proj/dt_proj weight XF (KS=12, 448 cols):
//   col<384:  XF[k][col] = sum_r x_proj_w[r][k] * dt_proj_w[col][r]
//   384..415: B then C rows of x_proj_w (e = col-384+12 gives 12..43)
//   >=416:    zero pad
// ---------------------------------------------------------------------------
__device__ __forceinline__ void pack_frag(_Float16* dst, int idx, int KS,
                                          const float* __restrict__ W, int KDIM) {
  int j = idx & 7, lane = (idx >> 3) & 63, colq = (idx >> 9) & 3, rest = idx >> 11;
  int ks = rest % KS, nt = rest / KS;
  int col = nt * 64 + colq * 16 + (lane & 15);
  int k = ks * 32 + ((lane >> 4) << 3) + j;
  dst[idx] = (_Float16)W[(size_t)col * KDIM + k];
}

__device__ __forceinline__ void pack_xf(_Float16* dst, int idx,
                                        const float* __restrict__ xw,
                                        const float* __restrict__ dtw) {
  int j = idx & 7, lane = (idx >> 3) & 63, colq = (idx >> 9) & 3, rest = idx >> 11;
  int ks = rest % 12, nt = rest / 12;
  int col = nt * 64 + colq * 16 + (lane & 15);
  int k = ks * 32 + ((lane >> 4) << 3) + j;
  float v = 0.f;
  if (col < 384) {
#pragma unroll
    for (int r = 0; r < 12; r++)
      v += xw[r * 384 + k] * dtw[col * 12 + r];
  } else if (col < 416) {
    v = xw[(col - 384 + 12) * 384 + k];
  }
  dst[idx] = (_Float16)v;
}

__global__ __launch_bounds__(256) void transpose_all(
    const float* __restrict__ in_proj_w, const float* __restrict__ x_proj_w,
    const float* __restrict__ dt_proj_w, const float* __restrict__ out_proj_w,
    const float* __restrict__ proj_out_w, float* __restrict__ ws) {
  int idx = blockIdx.x * 256 + threadIdx.x;
  if (idx < 147456) {                 // in_proj: 768 cols x 192 k, KS=6
    pack_frag((_Float16*)(ws + WS_BFIN), idx, 6, in_proj_w, 192);
    return;
  }
  idx -= 147456;
  if (idx < 73728) {                  // out_proj: 192 cols x 384 k, KS=12
    pack_frag((_Float16*)(ws + WS_BFOUT), idx, 12, out_proj_w, 384);
    return;
  }
  idx -= 73728;
  if (idx < 36864) {                  // proj_out: 192 cols x 192 k, KS=6
    pack_frag((_Float16*)(ws + WS_BFPO), idx, 6, proj_out_w, 192);
    return;
  }
  idx -= 36864;
  if (idx < 172032) {                 // fused x_proj/dt_proj: 448 cols, KS=12
    pack_xf((_Float16*)(ws + WS_BFXF), idx, x_proj_w, dt_proj_w);
  }
}

// ---------------------------------------------------------------------------
// in_proj GEMM via fp16 MFMA: xn (GN fused on stage) @ W. M=16384, N=768,
// K=192. 64x64 tile, 4 waves (2x2), each 32x32 = 2x2 fragments.
// Epilogue routes u (snake) and z (raster).
// ---------------------------------------------------------------------------
__global__ __launch_bounds__(256) void gemm_inproj_mfma(
    const float* __restrict__ x, const _Float16* __restrict__ Bf,
    const float* __restrict__ stat, const float* __restrict__ gamma,
    const float* __restrict__ beta, float* __restrict__ u, float* __restrict__ z) {
  int mt = blockIdx.x & 255, nt = blockIdx.x >> 8;   // nt 0..11
  int m0 = mt * 64;
  int b = m0 >> 12, l0 = m0 & 4095;
  float mu = stat[b * 2], rs = stat[b * 2 + 1];
  __shared__ __align__(16) _Float16 Ah[64][200];
  int tid = threadIdx.x;
  int row = tid & 63, cq = tid >> 6;
  // Stage A (x is [c][l]-major; coalesced over l=row), fused GroupNorm.
#pragma unroll
  for (int i = 0; i < 12; i++) {
    int c0 = cq * 4 + i * 16;
    half4 h;
#pragma unroll
    for (int cc = 0; cc < 4; cc++) {
      int c = c0 + cc;
      float g = gamma[c] * rs;
      float bt = beta[c] - mu * g;
      float xv = x[((size_t)(b * 192 + c) << 12) + l0 + row];
      h[cc] = (_Float16)(xv * g + bt);
    }
    *(half4*)&Ah[row][c0] = h;
  }
  __syncthreads();
  int w = tid >> 6, lane = tid & 63;
  int wm = (w >> 1) * 32, wcol = w & 1;
  int r16 = lane & 15, kg = lane >> 4;
  f32x4 acc[2][2] = {};
#pragma unroll
  for (int ks = 0; ks < 6; ks++) {
    half8 a0 = *(const half8*)&Ah[wm + r16][ks * 32 + kg * 8];
    half8 a1 = *(const half8*)&Ah[wm + 16 + r16][ks * 32 + kg * 8];
    half8 b0 = *(const half8*)&Bf[(((size_t)(nt * 6 + ks) * 4 + wcol * 2 + 0) << 9) + lane * 8];
    half8 b1 = *(const half8*)&Bf[(((size_t)(nt * 6 + ks) * 4 + wcol * 2 + 1) << 9) + lane * 8];
    acc[0][0] = __builtin_amdgcn_mfma_f32_16x16x32_f16(a0, b0, acc[0][0], 0, 0, 0);
    acc[0][1] = __builtin_amdgcn_mfma_f32_16x16x32_f16(a0, b1, acc[0][1], 0, 0, 0);
    acc[1][0] = __builtin_amdgcn_mfma_f32_16x16x32_f16(a1, b0, acc[1][0], 0, 0, 0);
    acc[1][1] = __builtin_amdgcn_mfma_f32_16x16x32_f16(a1, b1, acc[1][1], 0, 0, 0);
  }
  int hrow = l0 >> 6;
  bool odd = hrow & 1;
#pragma unroll
  for (int mi = 0; mi < 2; mi++)
#pragma unroll
    for (int ni = 0; ni < 2; ni++)
#pragma unroll
      for (int r = 0; r < 4; r++) {
        int wloc = wm + mi * 16 + kg * 4 + r;
        int d = nt * 64 + wcol * 32 + ni * 16 + r16;
        float val = acc[mi][ni][r];
        if (d < DIN) {
          int ls = odd ? (hrow << 6) + 63 - wloc : l0 + wloc;
          u[((size_t)(b << 12) + ls) * DIN + d] = val;
        } else {
          z[((size_t)(b << 12) + l0 + wloc) * DIN + (d - DIN)] = val;
        }
      }
}

// ---------------------------------------------------------------------------
// Generic fp16-MFMA GEMM: C[M,N] = A[M,K] @ W; A fp32 row-major, W pre-packed
// frags. TRANSOUT: write transposed per batch into [B, N, 4096] (proj_out).
// ---------------------------------------------------------------------------
template <int KDIM, int NDIM, bool TRANSOUT>
__global__ __launch_bounds__(256) void gemm_mfma(
    const float* __restrict__ A, const _Float16* __restrict__ Bf,
    float* __restrict__ C) {
  constexpr int KS = KDIM / 32;
  int mt = blockIdx.x & 255, nt = blockIdx.x >> 8;
  int m0 = mt * 64, n0 = nt * 64;
  __shared__ __align__(16) _Float16 Ah[64][KDIM + 8];
  int tid = threadIdx.x;
  {
    int r16s = tid >> 4, kq = tid & 15;
#pragma unroll
    for (int rr = 0; rr < 4; rr++) {
      int rowi = r16s + rr * 16;
#pragma unroll
      for (int kk = 0; kk < KDIM / 64; kk++) {
        float4 v = *(const float4*)&A[(size_t)(m0 + rowi) * KDIM + kk * 64 + kq * 4];
        half4 h;
        h[0] = (_Float16)v.x; h[1] = (_Float16)v.y;
        h[2] = (_Float16)v.z; h[3] = (_Float16)v.w;
        *(half4*)&Ah[rowi][kk * 64 + kq * 4] = h;
      }
    }
  }
  __syncthreads();
  int w = tid >> 6, lane = tid & 63;
  int wm = (w >> 1) * 32, wcol = w & 1;
  int r16 = lane & 15, kg = lane >> 4;
  f32x4 acc[2][2] = {};
#pragma unroll
  for (int ks = 0; ks < KS; ks++) {
    half8 a0 = *(const half8*)&Ah[wm + r16][ks * 32 + kg * 8];
    half8 a1 = *(const half8*)&Ah[wm + 16 + r16][ks * 32 + kg * 8];
    half8 b0 = *(const half8*)&Bf[(((size_t)(nt * KS + ks) * 4 + wcol * 2 + 0) << 9) + lane * 8];
    half8 b1 = *(const half8*)&Bf[(((size_t)(nt * KS + ks) * 4 + wcol * 2 + 1) << 9) + lane * 8];
    acc[0][0] = __builtin_amdgcn_mfma_f32_16x16x32_f16(a0, b0, acc[0][0], 0, 0, 0);
    acc[0][1] = __builtin_amdgcn_mfma_f32_16x16x32_f16(a0, b1, acc[0][1], 0, 0, 0);
    acc[1][0] = __builtin_amdgcn_mfma_f32_16x16x32_f16(a1, b0, acc[1][0], 0, 0, 0);
    acc[1][1] = __builtin_amdgcn_mfma_f32_16x16x32_f16(a1, b1, acc[1][1], 0, 0, 0);
  }
  if constexpr (!TRANSOUT) {
#pragma unroll
    for (int mi = 0; mi < 2; mi++)
#pragma unroll
      for (int ni = 0; ni < 2; ni++)
#pragma unroll
        for (int r = 0; r < 4; r++) {
          int rowo = wm + mi * 16 + kg * 4 + r;
          int col = wcol * 32 + ni * 16 + r16;
          C[(size_t)(m0 + rowo) * NDIM + n0 + col] = acc[mi][ni][r];
        }
  } else {
    __shared__ float Cs[64][68];
#pragma unroll
    for (int mi = 0; mi < 2; mi++)
#pragma unroll
      for (int ni = 0; ni < 2; ni++)
#pragma unroll
        for (int r = 0; r < 4; r++)
          Cs[wcol * 32 + ni * 16 + r16][wm + mi * 16 + kg * 4 + r] = acc[mi][ni][r];
    __syncthreads();
    int b = m0 >> 12, l0 = m0 & 4095;
    int li = tid & 63;
#pragma unroll
    for (int rr = 0; rr < 16; rr++) {
      int o = rr * 4 + (tid >> 6);
      C[(size_t)(b * CC + n0 + o) * CL + l0 + li] = Cs[o][li];
    }
  }
}

// ---------------------------------------------------------------------------
// Fused x_proj + dt_proj via fp16 MFMA: uc @ XF[384,448].
// Epilogue: col<384 -> delta = softplus(acc + dt_bias); 384..399 -> Bmb;
// 400..415 -> Cmb; rest pad.
// ---------------------------------------------------------------------------
__global__ __launch_bounds__(256) void xfull_gemm(
    const float* __restrict__ uc, const _Float16* __restrict__ Bf,
    const float* __restrict__ dt_bias, float* __restrict__ delta,
    float* __restrict__ Bmb, float* __restrict__ Cmb) {
  int mt = blockIdx.x & 255, nt = blockIdx.x >> 8;   // nt 0..6
  int m0 = mt * 64;
  __shared__ __align__(16) _Float16 Ah[64][392];
  int tid = threadIdx.x;
  {
    int r16s = tid >> 4, kq = tid & 15;
#pragma unroll
    for (int rr = 0; rr < 4; rr++) {
      int rowi = r16s + rr * 16;
#pragma unroll
      for (int kk = 0; kk < 6; kk++) {
        float4 v = *(const float4*)&uc[(size_t)(m0 + rowi) * DIN + kk * 64 + kq * 4];
        half4 h;
        h[0] = (_Float16)v.x; h[1] = (_Float16)v.y;
        h[2] = (_Float16)v.z; h[3] = (_Float16)v.w;
        *(half4*)&Ah[rowi][kk * 64 + kq * 4] = h;
      }
    }
  }
  __syncthreads();
  int w = tid >> 6, lane = tid & 63;
  int wm = (w >> 1) * 32, wcol = w & 1;
  int r16 = lane & 15, kg = lane >> 4;
  f32x4 acc[2][2] = {};
#pragma unroll
  for (int ks = 0; ks < 12; ks++) {
    half8 a0 = *(const half8*)&Ah[wm + r16][ks * 32 + kg * 8];
    half8 a1 = *(const half8*)&Ah[wm + 16 + r16][ks * 32 + kg * 8];
    half8 b0 = *(const half8*)&Bf[(((size_t)(nt * 12 + ks) * 4 + wcol * 2 + 0) << 9) + lane * 8];
    half8 b1 = *(const half8*)&Bf[(((size_t)(nt * 12 + ks) * 4 + wcol * 2 + 1) << 9) + lane * 8];
    acc[0][0] = __builtin_amdgcn_mfma_f32_16x16x32_f16(a0, b0, acc[0][0], 0, 0, 0);
    acc[0][1] = __builtin_amdgcn_mfma_f32_16x16x32_f16(a0, b1, acc[0][1], 0, 0, 0);
    acc[1][0] = __builtin_amdgcn_mfma_f32_16x16x32_f16(a1, b0, acc[1][0], 0, 0, 0);
    acc[1][1] = __builtin_amdgcn_mfma_f32_16x16x32_f16(a1, b1, acc[1][1], 0, 0, 0);
  }
#pragma unroll
  for (int mi = 0; mi < 2; mi++)
#pragma unroll
    for (int ni = 0; ni < 2; ni++)
#pragma unroll
      for (int r = 0; r < 4; r++) {
        size_t m = m0 + wm + mi * 16 + kg * 4 + r;
        int gc = nt * 64 + wcol * 32 + ni * 16 + r16;
        float val = acc[mi][ni][r];
        if (gc < 384)
          delta[m * DIN + gc] = softplus_f(val + dt_bias[gc]);
        else if (gc < 400)
          Bmb[m * 16 + (gc - 384)] = val;
        else if (gc < 416)
          Cmb[m * 16 + (gc - 400)] = val;
      }
}

// ---------------------------------------------------------------------------
// Causal depthwise conv1d (kernel 4) along snake sequence + SiLU.
// ---------------------------------------------------------------------------
__global__ __launch_bounds__(256) void conv_silu(
    const float* __restrict__ u, const float* __restrict__ cw,
    const float* __restrict__ cb, float* __restrict__ uc) {
  int gid = blockIdx.x * 256 + threadIdx.x;   // over 16384*96
  int g = gid % 96;
  int bl = gid / 96;
  int b = bl >> 12, l = bl & 4095;
  int d0 = g << 2;
  float4 acc = *(const float4*)&cb[d0];
#pragma unroll
  for (int k = 0; k < 4; k++) {
    int lk = l - 3 + k;
    if (lk >= 0) {
      const float4 v = *(const float4*)&u[((size_t)(b << 12) + lk) * DIN + d0];
      acc.x = fmaf(v.x, cw[(d0 + 0) * 4 + k], acc.x);
      acc.y = fmaf(v.y, cw[(d0 + 1) * 4 + k], acc.y);
      acc.z = fmaf(v.z, cw[(d0 + 2) * 4 + k], acc.z);
      acc.w = fmaf(v.w, cw[(d0 + 3) * 4 + k], acc.w);
    }
  }
  acc.x = silu_f(acc.x);
  acc.y = silu_f(acc.y);
  acc.z = silu_f(acc.z);
  acc.w = silu_f(acc.w);
  *(float4*)&uc[(size_t)bl * DIN + d0] = acc;
}

// ---------------------------------------------------------------------------
// Chunked selective scan, 4 n-states per thread (see Round-2 notes).
// ---------------------------------------------------------------------------
__global__ __launch_bounds__(256) void scan_partial(
    const float* __restrict__ delta, const float* __restrict__ uc,
    const float* __restrict__ Bmb, const float* __restrict__ A_log,
    float* __restrict__ hend, float* __restrict__ Pbuf) {
  int bid = blockIdx.x;
  int chunk = bid & 63, bg = bid >> 6;
  int b = bg / 6, g = bg % 6;
  int t = threadIdx.x;
  int dloc = t >> 2, q = t & 3;
  int d = g * 64 + dloc;
  __shared__ float sD[64][64], sU[64][64], sB[64][16];
  size_t baseBL = ((size_t)b << 12) + chunk * 64;
  {
    int row = t >> 2, cg = (t & 3) * 16;
    const float* dp = &delta[(baseBL + row) * DIN + g * 64 + cg];
    const float* up = &uc[(baseBL + row) * DIN + g * 64 + cg];
#pragma unroll
    for (int c = 0; c < 4; c++) {
      *(float4*)&sD[row][cg + 4 * c] = *(const float4*)&dp[4 * c];
      *(float4*)&sU[row][cg + 4 * c] = *(const float4*)&up[4 * c];
    }
    *(float4*)&sB[row][q * 4] = *(const float4*)&Bmb[(baseBL + row) * 16 + q * 4];
  }
  __syncthreads();
  float4 av = *(const float4*)&A_log[d * 16 + 4 * q];
  float a0 = -__expf(av.x), a1 = -__expf(av.y), a2 = -__expf(av.z), a3 = -__expf(av.w);
  float h0 = 0.f, h1 = 0.f, h2 = 0.f, h3 = 0.f, sdel = 0.f;
#pragma unroll 8
  for (int ll = 0; ll < 64; ll++) {
    float dv = sD[ll][dloc];
    float uv = sU[ll][dloc];
    float4 Bv = *(const float4*)&sB[ll][q * 4];
    float duv = dv * uv;
    h0 = fmaf(__expf(dv * a0), h0, duv * Bv.x);
    h1 = fmaf(__expf(dv * a1), h1, duv * Bv.y);
    h2 = fmaf(__expf(dv * a2), h2, duv * Bv.z);
    h3 = fmaf(__expf(dv * a3), h3, duv * Bv.w);
    sdel += dv;
  }
  size_t e = ((size_t)(b * DIN + d)) * 16 + 4 * q;
  float4 hv; hv.x = h0; hv.y = h1; hv.z = h2; hv.w = h3;
  *(float4*)&hend[(size_t)chunk * NELEM + e] = hv;
  float4 pv;
  pv.x = __expf(a0 * sdel); pv.y = __expf(a1 * sdel);
  pv.z = __expf(a2 * sdel); pv.w = __expf(a3 * sdel);
  *(float4*)&Pbuf[(size_t)chunk * NELEM + e] = pv;
}

__global__ __launch_bounds__(256) void scan_combine(
    const float* __restrict__ hend, const float* __restrict__ Pbuf,
    float* __restrict__ hin) {
  int e = blockIdx.x * 256 + threadIdx.x;   // 0..24575
  float h = 0.f;
  float Pc = Pbuf[e], Hc = hend[e];
#pragma unroll 8
  for (int c = 0; c < NCHUNK; c++) {
    float Pn = 0.f, Hn = 0.f;
    if (c < NCHUNK - 1) {
      Pn = Pbuf[(size_t)(c + 1) * NELEM + e];
      Hn = hend[(size_t)(c + 1) * NELEM + e];
    }
    hin[(size_t)c * NELEM + e] = h;
    h = fmaf(Pc, h, Hc);
    Pc = Pn; Hc = Hn;
  }
}

__global__ __launch_bounds__(256) void scan_final(
    const float* __restrict__ delta, const float* __restrict__ uc,
    const float* __restrict__ Bmb, const float* __restrict__ Cmb,
    const float* __restrict__ A_log, const float* __restrict__ Dskip,
    const float* __restrict__ z, const float* __restrict__ hin,
    float* __restrict__ yr) {
  int bid = blockIdx.x;
  int chunk = bid & 63, bg = bid >> 6;
  int b = bg / 6, g = bg % 6;
  int t = threadIdx.x;
  int dloc = t >> 2, q = t & 3;
  int d = g * 64 + dloc;
  __shared__ float sD[64][64], sU[64][64], sB[64][16], sC[64][16];
  size_t baseBL = ((size_t)b << 12) + chunk * 64;
  {
    int row = t >> 2, cg = (t & 3) * 16;
    const float* dp = &delta[(baseBL + row) * DIN + g * 64 + cg];
    const float* up = &uc[(baseBL + row) * DIN + g * 64 + cg];
#pragma unroll
    for (int c = 0; c < 4; c++) {
      *(float4*)&sD[row][cg + 4 * c] = *(const float4*)&dp[4 * c];
      *(float4*)&sU[row][cg + 4 * c] = *(const float4*)&up[4 * c];
    }
    *(float4*)&sB[row][q * 4] = *(const float4*)&Bmb[(baseBL + row) * 16 + q * 4];
    *(float4*)&sC[row][q * 4] = *(const float4*)&Cmb[(baseBL + row) * 16 + q * 4];
  }
  __syncthreads();
  float4 av = *(const float4*)&A_log[d * 16 + 4 * q];
  float a0 = -__expf(av.x), a1 = -__expf(av.y), a2 = -__expf(av.z), a3 = -__expf(av.w);
  size_t e = ((size_t)(b * DIN + d)) * 16 + 4 * q;
  float4 hv = *(const float4*)&hin[(size_t)chunk * NELEM + e];
  float h0 = hv.x, h1 = hv.y, h2 = hv.z, h3 = hv.w;
  float yk[16];
#pragma unroll
  for (int ll = 0; ll < 64; ll++) {
    float dv = sD[ll][dloc];
    float uv = sU[ll][dloc];
    float4 Bv = *(const float4*)&sB[ll][q * 4];
    float4 Cv = *(const float4*)&sC[ll][q * 4];
    float duv = dv * uv;
    h0 = fmaf(__expf(dv * a0), h0, duv * Bv.x);
    h1 = fmaf(__expf(dv * a1), h1, duv * Bv.y);
    h2 = fmaf(__expf(dv * a2), h2, duv * Bv.z);
    h3 = fmaf(__expf(dv * a3), h3, duv * Bv.w);
    float yp = h0 * Cv.x + h1 * Cv.y + h2 * Cv.z + h3 * Cv.w;
    yp += quadswz<0x041F>(yp);   // xor 1 within quad
    yp += quadswz<0x081F>(yp);   // xor 2 within quad -> all 4 lanes have sum
    if ((ll & 3) == q) yk[ll >> 2] = yp;
  }
  float dsk = Dskip[d];
  bool odd = chunk & 1;
#pragma unroll
  for (int i = 0; i < 16; i++) {
    int ll = 4 * i + q;
    int wr = odd ? 63 - ll : ll;          // raster column for snake step ll
    size_t ro = baseBL + wr;              // raster row offset (hrow == chunk)
    float uvll = sU[ll][dloc];
    float zv = z[ro * DIN + d];
    yr[ro * DIN + d] = (yk[i] + uvll * dsk) * silu_f(zv);
  }
}

// ---------------------------------------------------------------------------
// Depthwise 3x3 local enhancement + residual (raster space).
// ---------------------------------------------------------------------------
__global__ __launch_bounds__(256) void le_conv(
    const float* __restrict__ yr, const float* __restrict__ lw, float* __restrict__ y2) {
  int gid = blockIdx.x * 256 + threadIdx.x;   // 16384*96
  int g = gid % 96;
  int bl = gid / 96;
  int b = bl >> 12, l = bl & 4095;
  int hrow = l >> 6, w = l & 63;
  int d0 = g << 2;
  float4 acc = *(const float4*)&yr[(size_t)bl * DIN + d0];   // residual
#pragma unroll
  for (int ki = 0; ki < 3; ki++) {
    int hh = hrow + ki - 1;
    if ((unsigned)hh >= 64u) continue;
#pragma unroll
    for (int kj = 0; kj < 3; kj++) {
      int ww = w + kj - 1;
      if ((unsigned)ww >= 64u) continue;
      const float4 v = *(const float4*)&yr[((size_t)((b << 12) + (hh << 6) + ww)) * DIN + d0];
      int wi = ki * 3 + kj;
      acc.x = fmaf(v.x, lw[(d0 + 0) * 9 + wi], acc.x);
      acc.y = fmaf(v.y, lw[(d0 + 1) * 9 + wi], acc.y);
      acc.z = fmaf(v.z, lw[(d0 + 2) * 9 + wi], acc.z);
      acc.w = fmaf(v.w, lw[(d0 + 3) * 9 + wi], acc.w);
    }
  }
  *(float4*)&y2[(size_t)bl * DIN + d0] = acc;
}

// ---------------------------------------------------------------------------
extern "C" void kernel_launch(void* const* d_in, const int* in_sizes, int n_in,
                              void* d_out, int out_size, void* d_ws, size_t ws_size,
                              hipStream_t stream) {
  const float* x          = (const float*)d_in[0];
  const float* gn_gamma   = (const float*)d_in[1];
  const float* gn_beta    = (const float*)d_in[2];
  const float* in_proj_w  = (const float*)d_in[3];
  const float* conv1d_w   = (const float*)d_in[4];
  const float* conv1d_b   = (const float*)d_in[5];
  const float* x_proj_w   = (const float*)d_in[6];
  const float* dt_proj_w  = (const float*)d_in[7];
  const float* dt_proj_b  = (const float*)d_in[8];
  const float* A_log      = (const float*)d_in[9];
  const float* Dskip      = (const float*)d_in[10];
  const float* le_w       = (const float*)d_in[11];
  const float* out_proj_w = (const float*)d_in[12];
  const float* proj_out_w = (const float*)d_in[13];
  float* out = (float*)d_out;

  float* ws      = (float*)d_ws;
  float* part    = ws + WS_PART;
  float* stat    = ws + WS_STAT;
  _Float16* BfIn  = (_Float16*)(ws + WS_BFIN);
  _Float16* BfOut = (_Float16*)(ws + WS_BFOUT);
  _Float16* BfPo  = (_Float16*)(ws + WS_BFPO);
  _Float16* BfXf  = (_Float16*)(ws + WS_BFXF);
  float* u      = ws + WS_BIG;
  float* zb     = u + BIGSZ;
  float* uc     = zb + BIGSZ;
  float* delta  = uc + BIGSZ;
  float* yr     = delta + BIGSZ;
  float* Bmb    = yr + BIGSZ;
  float* Cmb    = Bmb + NBL * NST;
  float* y2     = uc;      // reuse: uc dead after scan
  float* outseq = u;       // reuse: u dead after conv + scan phases
  // scan scratch aliases u (dead after conv_silu, reborn as outseq after scan)
  float* hend   = u;                         // 64*24576 = 1572864 floats
  float* Pbuf   = u + (size_t)NCHUNK * NELEM;
  float* hin    = u + 2 * (size_t)NCHUNK * NELEM;  // total 4718592 <= BIGSZ

  gn_partial<<<256, 256, 0, stream>>>(x, part);
  gn_final<<<1, 256, 0, stream>>>(part, stat);
  transpose_all<<<1680, 256, 0, stream>>>(in_proj_w, x_proj_w, dt_proj_w,
                                          out_proj_w, proj_out_w, ws);
  gemm_inproj_mfma<<<256 * 12, 256, 0, stream>>>(x, BfIn, stat, gn_gamma, gn_beta, u, zb);
  conv_silu<<<6144, 256, 0, stream>>>(u, conv1d_w, conv1d_b, uc);
  xfull_gemm<<<256 * 7, 256, 0, stream>>>(uc, BfXf, dt_proj_b, delta, Bmb, Cmb);
  scan_partial<<<1536, 256, 0, stream>>>(delta, uc, Bmb, A_log, hend, Pbuf);
  scan_combine<<<96, 256, 0, stream>>>(hend, Pbuf, hin);
  scan_final<<<1536, 256, 0, stream>>>(delta, uc, Bmb, Cmb, A_log, Dskip,
                                       zb, hin, yr);
  le_conv<<<6144, 256, 0, stream>>>(yr, le_w, y2);
  gemm_mfma<384, 192, false><<<256 * 3, 256, 0, stream>>>(y2, BfOut, outseq);
  gemm_mfma<192, 192, true><<<256 * 3, 256, 0, stream>>>(outseq, BfPo, out);
}

// Round 7
// 269.922 us; speedup vs baseline: 5.7205x; 1.3021x over previous
//
#include <hip/hip_runtime.h>
#include <cstddef>

// Problem constants
constexpr int CB  = 4;
constexpr int CC  = 192;
constexpr int CH  = 64;
constexpr int CW  = 64;
constexpr int CL  = CH * CW;        // 4096
constexpr int DIN = 384;
constexpr int NST = 16;
constexpr int DTR = 12;

constexpr int NCHUNK = 64;          // chunks per sequence (= image rows)
constexpr int NELEM  = CB * DIN * NST; // 24576 independent (b,d,n) recurrences

// Workspace layout (in floats)
constexpr int WS_PART  = 0;                          // 512
constexpr int WS_STAT  = 512;                        // 8
constexpr int WS_BFIN  = 1024;                       // 147456 f16 = 73728 fl
constexpr int WS_BFOUT = WS_BFIN + 73728;            // 73728 f16 = 36864 fl
constexpr int WS_BFPO  = WS_BFOUT + 36864;           // 36864 f16 = 18432 fl
constexpr int WS_BFXF  = WS_BFPO + 18432;            // 172032 f16 = 86016 fl
constexpr int WS_LWT   = WS_BFXF + 86016;            // 3456 fl (lwT[9][384])
constexpr int WS_BIG   = WS_LWT + 3456;              // = 219520
constexpr size_t NBL   = (size_t)CB * CL;            // 16384
constexpr size_t BIGSZ = NBL * DIN;                  // 6291456 floats

using half8 = __attribute__((ext_vector_type(8))) _Float16;
using half4 = __attribute__((ext_vector_type(4))) _Float16;
using f32x4 = __attribute__((ext_vector_type(4))) float;

__device__ __forceinline__ float sigm(float v) { return 1.f / (1.f + __expf(-v)); }
__device__ __forceinline__ float silu_f(float v) { return v * sigm(v); }
__device__ __forceinline__ float softplus_f(float v) { return v > 20.f ? v : log1pf(__expf(v)); }
template <int PAT>
__device__ __forceinline__ float quadswz(float v) {
  return __int_as_float(__builtin_amdgcn_ds_swizzle(__float_as_int(v), PAT));
}

// ---------------------------------------------------------------------------
// GroupNorm(1, C): per-batch mean/var over C*H*W, two-stage deterministic.
// ---------------------------------------------------------------------------
__global__ __launch_bounds__(256) void gn_partial(const float* __restrict__ x,
                                                  float* __restrict__ part) {
  int b = blockIdx.x >> 6;          // 64 blocks per batch
  int chunk = blockIdx.x & 63;
  const float* px = x + (size_t)b * CC * CL + (size_t)chunk * 12288;
  float s = 0.f, s2 = 0.f;
  for (int i = threadIdx.x; i < 12288 / 4; i += 256) {
    float4 v = ((const float4*)px)[i];
    s  += v.x + v.y + v.z + v.w;
    s2 += v.x * v.x + v.y * v.y + v.z * v.z + v.w * v.w;
  }
  __shared__ float ls[4], ls2[4];
  for (int off = 32; off; off >>= 1) { s += __shfl_down(s, off); s2 += __shfl_down(s2, off); }
  int wid = threadIdx.x >> 6, lane = threadIdx.x & 63;
  if (lane == 0) { ls[wid] = s; ls2[wid] = s2; }
  __syncthreads();
  if (threadIdx.x == 0) {
    float t = 0.f, t2 = 0.f;
    for (int i = 0; i < 4; i++) { t += ls[i]; t2 += ls2[i]; }
    part[blockIdx.x * 2] = t;
    part[blockIdx.x * 2 + 1] = t2;
  }
}

__global__ __launch_bounds__(256) void gn_final(const float* __restrict__ part,
                                                float* __restrict__ stat) {
  int b = threadIdx.x >> 6;   // wave id == batch
  int i = threadIdx.x & 63;
  float s = part[(b * 64 + i) * 2];
  float s2 = part[(b * 64 + i) * 2 + 1];
  for (int off = 32; off; off >>= 1) { s += __shfl_down(s, off); s2 += __shfl_down(s2, off); }
  if (i == 0) {
    float n = (float)(CC * CL);
    float mu = s / n;
    float var = s2 / n - mu * mu;
    stat[b * 2] = mu;
    stat[b * 2 + 1] = rsqrtf(var + 1e-5f);
  }
}

// ---------------------------------------------------------------------------
// Weight prep. MFMA B-fragment layout:
//   idx = ((nt*KS + ks)*4 + colq)*512 + lane*8 + j
//   col = nt*64 + colq*16 + (lane&15); k = ks*32 + (lane>>4)*8 + j
// ---------------------------------------------------------------------------
__device__ __forceinline__ void pack_frag(_Float16* dst, int idx, int KS,
                                          const float* __restrict__ W, int KDIM) {
  int j = idx & 7, lane = (idx >> 3) & 63, colq = (idx >> 9) & 3, rest = idx >> 11;
  int ks = rest % KS, nt = rest / KS;
  int col = nt * 64 + colq * 16 + (lane & 15);
  int k = ks * 32 + ((lane >> 4) << 3) + j;
  dst[idx] = (_Float16)W[(size_t)col * KDIM + k];
}

__device__ __forceinline__ void pack_xf(_Float16* dst, int idx,
                                        const float* __restrict__ xw,
                                        const float* __restrict__ dtw) {
  int j = idx & 7, lane = (idx >> 3) & 63, colq = (idx >> 9) & 3, rest = idx >> 11;
  int ks = rest % 12, nt = rest / 12;
  int col = nt * 64 + colq * 16 + (lane & 15);
  int k = ks * 32 + ((lane >> 4) << 3) + j;
  float v = 0.f;
  if (col < 384) {
#pragma unroll
    for (int r = 0; r < 12; r++)
      v += xw[r * 384 + k] * dtw[col * 12 + r];
  } else if (col < 416) {
    v = xw[(col - 384 + 12) * 384 + k];
  }
  dst[idx] = (_Float16)v;
}

__global__ __launch_bounds__(256) void transpose_all(
    const float* __restrict__ in_proj_w, const float* __restrict__ x_proj_w,
    const float* __restrict__ dt_proj_w, const float* __restrict__ out_proj_w,
    const float* __restrict__ proj_out_w, const float* __restrict__ le_w,
    float* __restrict__ ws) {
  int idx = blockIdx.x * 256 + threadIdx.x;
  if (idx < 147456) {                 // in_proj: 768 cols x 192 k, KS=6
    pack_frag((_Float16*)(ws + WS_BFIN), idx, 6, in_proj_w, 192);
    return;
  }
  idx -= 147456;
  if (idx < 73728) {                  // out_proj: 192 cols x 384 k, KS=12
    pack_frag((_Float16*)(ws + WS_BFOUT), idx, 12, out_proj_w, 384);
    return;
  }
  idx -= 73728;
  if (idx < 36864) {                  // proj_out: 192 cols x 192 k, KS=6
    pack_frag((_Float16*)(ws + WS_BFPO), idx, 6, proj_out_w, 192);
    return;
  }
  idx -= 36864;
  if (idx < 172032) {                 // fused x_proj/dt_proj: 448 cols, KS=12
    pack_xf((_Float16*)(ws + WS_BFXF), idx, x_proj_w, dt_proj_w);
    return;
  }
  idx -= 172032;
  if (idx < 3456) {                   // lwT[t9][d] = le_w[d*9 + t9]
    int t9 = idx / 384, d = idx % 384;
    ws[WS_LWT + idx] = le_w[d * 9 + t9];
  }
}

// ---------------------------------------------------------------------------
// in_proj GEMM via fp16 MFMA: xn (GN fused on stage) @ W. M=16384, N=768,
// K=192. 64x64 tile, 4 waves (2x2), each 32x32 = 2x2 fragments.
// Epilogue routes u (snake) and z (raster).
// ---------------------------------------------------------------------------
__global__ __launch_bounds__(256) void gemm_inproj_mfma(
    const float* __restrict__ x, const _Float16* __restrict__ Bf,
    const float* __restrict__ stat, const float* __restrict__ gamma,
    const float* __restrict__ beta, float* __restrict__ u, float* __restrict__ z) {
  int mt = blockIdx.x & 255, nt = blockIdx.x >> 8;   // nt 0..11
  int m0 = mt * 64;
  int b = m0 >> 12, l0 = m0 & 4095;
  float mu = stat[b * 2], rs = stat[b * 2 + 1];
  __shared__ __align__(16) _Float16 Ah[64][200];
  int tid = threadIdx.x;
  int row = tid & 63, cq = tid >> 6;
  // Stage A (x is [c][l]-major; coalesced over l=row), fused GroupNorm.
#pragma unroll
  for (int i = 0; i < 12; i++) {
    int c0 = cq * 4 + i * 16;
    half4 h;
#pragma unroll
    for (int cc = 0; cc < 4; cc++) {
      int c = c0 + cc;
      float g = gamma[c] * rs;
      float bt = beta[c] - mu * g;
      float xv = x[((size_t)(b * 192 + c) << 12) + l0 + row];
      h[cc] = (_Float16)(xv * g + bt);
    }
    *(half4*)&Ah[row][c0] = h;
  }
  __syncthreads();
  int w = tid >> 6, lane = tid & 63;
  int wm = (w >> 1) * 32, wcol = w & 1;
  int r16 = lane & 15, kg = lane >> 4;
  f32x4 acc[2][2] = {};
#pragma unroll
  for (int ks = 0; ks < 6; ks++) {
    half8 a0 = *(const half8*)&Ah[wm + r16][ks * 32 + kg * 8];
    half8 a1 = *(const half8*)&Ah[wm + 16 + r16][ks * 32 + kg * 8];
    half8 b0 = *(const half8*)&Bf[(((size_t)(nt * 6 + ks) * 4 + wcol * 2 + 0) << 9) + lane * 8];
    half8 b1 = *(const half8*)&Bf[(((size_t)(nt * 6 + ks) * 4 + wcol * 2 + 1) << 9) + lane * 8];
    acc[0][0] = __builtin_amdgcn_mfma_f32_16x16x32_f16(a0, b0, acc[0][0], 0, 0, 0);
    acc[0][1] = __builtin_amdgcn_mfma_f32_16x16x32_f16(a0, b1, acc[0][1], 0, 0, 0);
    acc[1][0] = __builtin_amdgcn_mfma_f32_16x16x32_f16(a1, b0, acc[1][0], 0, 0, 0);
    acc[1][1] = __builtin_amdgcn_mfma_f32_16x16x32_f16(a1, b1, acc[1][1], 0, 0, 0);
  }
  int hrow = l0 >> 6;
  bool odd = hrow & 1;
#pragma unroll
  for (int mi = 0; mi < 2; mi++)
#pragma unroll
    for (int ni = 0; ni < 2; ni++)
#pragma unroll
      for (int r = 0; r < 4; r++) {
        int wloc = wm + mi * 16 + kg * 4 + r;
        int d = nt * 64 + wcol * 32 + ni * 16 + r16;
        float val = acc[mi][ni][r];
        if (d < DIN) {
          int ls = odd ? (hrow << 6) + 63 - wloc : l0 + wloc;
          u[((size_t)(b << 12) + ls) * DIN + d] = val;
        } else {
          z[((size_t)(b << 12) + l0 + wloc) * DIN + (d - DIN)] = val;
        }
      }
}

// ---------------------------------------------------------------------------
// Generic fp16-MFMA GEMM: C[M,N] = A[M,K] @ W; A fp32 row-major, W pre-packed
// frags. TRANSOUT: write transposed per batch into [B, N, 4096] (proj_out).
// ---------------------------------------------------------------------------
template <int KDIM, int NDIM, bool TRANSOUT>
__global__ __launch_bounds__(256) void gemm_mfma(
    const float* __restrict__ A, const _Float16* __restrict__ Bf,
    float* __restrict__ C) {
  constexpr int KS = KDIM / 32;
  int mt = blockIdx.x & 255, nt = blockIdx.x >> 8;
  int m0 = mt * 64, n0 = nt * 64;
  __shared__ __align__(16) _Float16 Ah[64][KDIM + 8];
  int tid = threadIdx.x;
  {
    int r16s = tid >> 4, kq = tid & 15;
#pragma unroll
    for (int rr = 0; rr < 4; rr++) {
      int rowi = r16s + rr * 16;
#pragma unroll
      for (int kk = 0; kk < KDIM / 64; kk++) {
        float4 v = *(const float4*)&A[(size_t)(m0 + rowi) * KDIM + kk * 64 + kq * 4];
        half4 h;
        h[0] = (_Float16)v.x; h[1] = (_Float16)v.y;
        h[2] = (_Float16)v.z; h[3] = (_Float16)v.w;
        *(half4*)&Ah[rowi][kk * 64 + kq * 4] = h;
      }
    }
  }
  __syncthreads();
  int w = tid >> 6, lane = tid & 63;
  int wm = (w >> 1) * 32, wcol = w & 1;
  int r16 = lane & 15, kg = lane >> 4;
  f32x4 acc[2][2] = {};
#pragma unroll
  for (int ks = 0; ks < KS; ks++) {
    half8 a0 = *(const half8*)&Ah[wm + r16][ks * 32 + kg * 8];
    half8 a1 = *(const half8*)&Ah[wm + 16 + r16][ks * 32 + kg * 8];
    half8 b0 = *(const half8*)&Bf[(((size_t)(nt * KS + ks) * 4 + wcol * 2 + 0) << 9) + lane * 8];
    half8 b1 = *(const half8*)&Bf[(((size_t)(nt * KS + ks) * 4 + wcol * 2 + 1) << 9) + lane * 8];
    acc[0][0] = __builtin_amdgcn_mfma_f32_16x16x32_f16(a0, b0, acc[0][0], 0, 0, 0);
    acc[0][1] = __builtin_amdgcn_mfma_f32_16x16x32_f16(a0, b1, acc[0][1], 0, 0, 0);
    acc[1][0] = __builtin_amdgcn_mfma_f32_16x16x32_f16(a1, b0, acc[1][0], 0, 0, 0);
    acc[1][1] = __builtin_amdgcn_mfma_f32_16x16x32_f16(a1, b1, acc[1][1], 0, 0, 0);
  }
  if constexpr (!TRANSOUT) {
#pragma unroll
    for (int mi = 0; mi < 2; mi++)
#pragma unroll
      for (int ni = 0; ni < 2; ni++)
#pragma unroll
        for (int r = 0; r < 4; r++) {
          int rowo = wm + mi * 16 + kg * 4 + r;
          int col = wcol * 32 + ni * 16 + r16;
          C[(size_t)(m0 + rowo) * NDIM + n0 + col] = acc[mi][ni][r];
        }
  } else {
    __shared__ float Cs[64][68];
#pragma unroll
    for (int mi = 0; mi < 2; mi++)
#pragma unroll
      for (int ni = 0; ni < 2; ni++)
#pragma unroll
        for (int r = 0; r < 4; r++)
          Cs[wcol * 32 + ni * 16 + r16][wm + mi * 16 + kg * 4 + r] = acc[mi][ni][r];
    __syncthreads();
    int b = m0 >> 12, l0 = m0 & 4095;
    int li = tid & 63;
#pragma unroll
    for (int rr = 0; rr < 16; rr++) {
      int o = rr * 4 + (tid >> 6);
      C[(size_t)(b * CC + n0 + o) * CL + l0 + li] = Cs[o][li];
    }
  }
}

// ---------------------------------------------------------------------------
// Fused x_proj + dt_proj via fp16 MFMA: uc @ XF[384,448].
// Epilogue: col<384 -> delta = softplus(acc + dt_bias); 384..399 -> Bmb;
// 400..415 -> Cmb; rest pad.
// ---------------------------------------------------------------------------
__global__ __launch_bounds__(256) void xfull_gemm(
    const float* __restrict__ uc, const _Float16* __restrict__ Bf,
    const float* __restrict__ dt_bias, float* __restrict__ delta,
    float* __restrict__ Bmb, float* __restrict__ Cmb) {
  int mt = blockIdx.x & 255, nt = blockIdx.x >> 8;   // nt 0..6
  int m0 = mt * 64;
  __shared__ __align__(16) _Float16 Ah[64][392];
  int tid = threadIdx.x;
  {
    int r16s = tid >> 4, kq = tid & 15;
#pragma unroll
    for (int rr = 0; rr < 4; rr++) {
      int rowi = r16s + rr * 16;
#pragma unroll
      for (int kk = 0; kk < 6; kk++) {
        float4 v = *(const float4*)&uc[(size_t)(m0 + rowi) * DIN + kk * 64 + kq * 4];
        half4 h;
        h[0] = (_Float16)v.x; h[1] = (_Float16)v.y;
        h[2] = (_Float16)v.z; h[3] = (_Float16)v.w;
        *(half4*)&Ah[rowi][kk * 64 + kq * 4] = h;
      }
    }
  }
  __syncthreads();
  int w = tid >> 6, lane = tid & 63;
  int wm = (w >> 1) * 32, wcol = w & 1;
  int r16 = lane & 15, kg = lane >> 4;
  f32x4 acc[2][2] = {};
#pragma unroll
  for (int ks = 0; ks < 12; ks++) {
    half8 a0 = *(const half8*)&Ah[wm + r16][ks * 32 + kg * 8];
    half8 a1 = *(const half8*)&Ah[wm + 16 + r16][ks * 32 + kg * 8];
    half8 b0 = *(const half8*)&Bf[(((size_t)(nt * 12 + ks) * 4 + wcol * 2 + 0) << 9) + lane * 8];
    half8 b1 = *(const half8*)&Bf[(((size_t)(nt * 12 + ks) * 4 + wcol * 2 + 1) << 9) + lane * 8];
    acc[0][0] = __builtin_amdgcn_mfma_f32_16x16x32_f16(a0, b0, acc[0][0], 0, 0, 0);
    acc[0][1] = __builtin_amdgcn_mfma_f32_16x16x32_f16(a0, b1, acc[0][1], 0, 0, 0);
    acc[1][0] = __builtin_amdgcn_mfma_f32_16x16x32_f16(a1, b0, acc[1][0], 0, 0, 0);
    acc[1][1] = __builtin_amdgcn_mfma_f32_16x16x32_f16(a1, b1, acc[1][1], 0, 0, 0);
  }
#pragma unroll
  for (int mi = 0; mi < 2; mi++)
#pragma unroll
    for (int ni = 0; ni < 2; ni++)
#pragma unroll
      for (int r = 0; r < 4; r++) {
        size_t m = m0 + wm + mi * 16 + kg * 4 + r;
        int gc = nt * 64 + wcol * 32 + ni * 16 + r16;
        float val = acc[mi][ni][r];
        if (gc < 384)
          delta[m * DIN + gc] = softplus_f(val + dt_bias[gc]);
        else if (gc < 400)
          Bmb[m * 16 + (gc - 384)] = val;
        else if (gc < 416)
          Cmb[m * 16 + (gc - 400)] = val;
      }
}

// ---------------------------------------------------------------------------
// Causal depthwise conv1d (kernel 4) + SiLU, LDS-tiled: each element of u is
// read from global exactly once. Block = (b, 64-l tile, 64-d group).
// Thread owns 4 consecutive l rows, 7-entry sliding register window.
// ---------------------------------------------------------------------------
__global__ __launch_bounds__(256) void conv_silu_tiled(
    const float* __restrict__ u, const float* __restrict__ cw,
    const float* __restrict__ cb, float* __restrict__ uc) {
  int bid = blockIdx.x;               // b*64*6
  int dg = bid % 6;
  int lt = (bid / 6) % 64;
  int b  = bid / (6 * 64);
  int d0 = dg * 64;
  int l0 = lt * 64;
  __shared__ float S[67][68];         // row = l0-3 .. l0+63; 64 d + pad
  int t = threadIdx.x;
  for (int idx = t; idx < 67 * 16; idx += 256) {
    int row = idx >> 4, c4i = idx & 15;
    int l = l0 + row - 3;
    float4 v = make_float4(0.f, 0.f, 0.f, 0.f);
    if (l >= 0)
      v = *(const float4*)&u[((size_t)((b << 12) + l)) * DIN + d0 + c4i * 4];
    *(float4*)&S[row][c4i * 4] = v;
  }
  __syncthreads();
  int c4 = t & 15, j0 = (t >> 4) << 2;     // 4 consecutive output rows
  int dd = d0 + c4 * 4;
  float4 cwv[4];
#pragma unroll
  for (int i = 0; i < 4; i++) cwv[i] = *(const float4*)&cw[(dd + i) * 4];
  float4 bias = *(const float4*)&cb[dd];
  float4 win[7];
#pragma unroll
  for (int k = 0; k < 7; k++) win[k] = *(float4*)&S[j0 + k][c4 * 4];
#pragma unroll
  for (int j = 0; j < 4; j++) {
    float4 acc = bias;
#pragma unroll
    for (int k = 0; k < 4; k++) {
      float4 v = win[j + k];
      acc.x = fmaf(v.x, ((const float*)&cwv[0])[k], acc.x);
      acc.y = fmaf(v.y, ((const float*)&cwv[1])[k], acc.y);
      acc.z = fmaf(v.z, ((const float*)&cwv[2])[k], acc.z);
      acc.w = fmaf(v.w, ((const float*)&cwv[3])[k], acc.w);
    }
    acc.x = silu_f(acc.x);
    acc.y = silu_f(acc.y);
    acc.z = silu_f(acc.z);
    acc.w = silu_f(acc.w);
    *(float4*)&uc[((size_t)((b << 12) + l0 + j0 + j)) * DIN + dd] = acc;
  }
}

// ---------------------------------------------------------------------------
// Chunked selective scan, 4 n-states per thread (see Round-2 notes).
// ---------------------------------------------------------------------------
__global__ __launch_bounds__(256) void scan_partial(
    const float* __restrict__ delta, const float* __restrict__ uc,
    const float* __restrict__ Bmb, const float* __restrict__ A_log,
    float* __restrict__ hend, float* __restrict__ Pbuf) {
  int bid = blockIdx.x;
  int chunk = bid & 63, bg = bid >> 6;
  int b = bg / 6, g = bg % 6;
  int t = threadIdx.x;
  int dloc = t >> 2, q = t & 3;
  int d = g * 64 + dloc;
  __shared__ float sD[64][64], sU[64][64], sB[64][16];
  size_t baseBL = ((size_t)b << 12) + chunk * 64;
  {
    int row = t >> 2, cg = (t & 3) * 16;
    const float* dp = &delta[(baseBL + row) * DIN + g * 64 + cg];
    const float* up = &uc[(baseBL + row) * DIN + g * 64 + cg];
#pragma unroll
    for (int c = 0; c < 4; c++) {
      *(float4*)&sD[row][cg + 4 * c] = *(const float4*)&dp[4 * c];
      *(float4*)&sU[row][cg + 4 * c] = *(const float4*)&up[4 * c];
    }
    *(float4*)&sB[row][q * 4] = *(const float4*)&Bmb[(baseBL + row) * 16 + q * 4];
  }
  __syncthreads();
  float4 av = *(const float4*)&A_log[d * 16 + 4 * q];
  float a0 = -__expf(av.x), a1 = -__expf(av.y), a2 = -__expf(av.z), a3 = -__expf(av.w);
  float h0 = 0.f, h1 = 0.f, h2 = 0.f, h3 = 0.f, sdel = 0.f;
#pragma unroll 8
  for (int ll = 0; ll < 64; ll++) {
    float dv = sD[ll][dloc];
    float uv = sU[ll][dloc];
    float4 Bv = *(const float4*)&sB[ll][q * 4];
    float duv = dv * uv;
    h0 = fmaf(__expf(dv * a0), h0, duv * Bv.x);
    h1 = fmaf(__expf(dv * a1), h1, duv * Bv.y);
    h2 = fmaf(__expf(dv * a2), h2, duv * Bv.z);
    h3 = fmaf(__expf(dv * a3), h3, duv * Bv.w);
    sdel += dv;
  }
  size_t e = ((size_t)(b * DIN + d)) * 16 + 4 * q;
  float4 hv; hv.x = h0; hv.y = h1; hv.z = h2; hv.w = h3;
  *(float4*)&hend[(size_t)chunk * NELEM + e] = hv;
  float4 pv;
  pv.x = __expf(a0 * sdel); pv.y = __expf(a1 * sdel);
  pv.z = __expf(a2 * sdel); pv.w = __expf(a3 * sdel);
  *(float4*)&Pbuf[(size_t)chunk * NELEM + e] = pv;
}

__global__ __launch_bounds__(256) void scan_combine(
    const float* __restrict__ hend, const float* __restrict__ Pbuf,
    float* __restrict__ hin) {
  int e = blockIdx.x * 256 + threadIdx.x;   // 0..24575
  float h = 0.f;
  float Pc = Pbuf[e], Hc = hend[e];
#pragma unroll 8
  for (int c = 0; c < NCHUNK; c++) {
    float Pn = 0.f, Hn = 0.f;
    if (c < NCHUNK - 1) {
      Pn = Pbuf[(size_t)(c + 1) * NELEM + e];
      Hn = hend[(size_t)(c + 1) * NELEM + e];
    }
    hin[(size_t)c * NELEM + e] = h;
    h = fmaf(Pc, h, Hc);
    Pc = Pn; Hc = Hn;
  }
}

__global__ __launch_bounds__(256) void scan_final(
    const float* __restrict__ delta, const float* __restrict__ uc,
    const float* __restrict__ Bmb, const float* __restrict__ Cmb,
    const float* __restrict__ A_log, const float* __restrict__ Dskip,
    const float* __restrict__ z, const float* __restrict__ hin,
    float* __restrict__ yr) {
  int bid = blockIdx.x;
  int chunk = bid & 63, bg = bid >> 6;
  int b = bg / 6, g = bg % 6;
  int t = threadIdx.x;
  int dloc = t >> 2, q = t & 3;
  int d = g * 64 + dloc;
  __shared__ float sD[64][64], sU[64][64], sB[64][16], sC[64][16];
  size_t baseBL = ((size_t)b << 12) + chunk * 64;
  {
    int row = t >> 2, cg = (t & 3) * 16;
    const float* dp = &delta[(baseBL + row) * DIN + g * 64 + cg];
    const float* up = &uc[(baseBL + row) * DIN + g * 64 + cg];
#pragma unroll
    for (int c = 0; c < 4; c++) {
      *(float4*)&sD[row][cg + 4 * c] = *(const float4*)&dp[4 * c];
      *(float4*)&sU[row][cg + 4 * c] = *(const float4*)&up[4 * c];
    }
    *(float4*)&sB[row][q * 4] = *(const float4*)&Bmb[(baseBL + row) * 16 + q * 4];
    *(float4*)&sC[row][q * 4] = *(const float4*)&Cmb[(baseBL + row) * 16 + q * 4];
  }
  __syncthreads();
  float4 av = *(const float4*)&A_log[d * 16 + 4 * q];
  float a0 = -__expf(av.x), a1 = -__expf(av.y), a2 = -__expf(av.z), a3 = -__expf(av.w);
  size_t e = ((size_t)(b * DIN + d)) * 16 + 4 * q;
  float4 hv = *(const float4*)&hin[(size_t)chunk * NELEM + e];
  float h0 = hv.x, h1 = hv.y, h2 = hv.z, h3 = hv.w;
  float yk[16];
#pragma unroll
  for (int ll = 0; ll < 64; ll++) {
    float dv = sD[ll][dloc];
    float uv = sU[ll][dloc];
    float4 Bv = *(const float4*)&sB[ll][q * 4];
    float4 Cv = *(const float4*)&sC[ll][q * 4];
    float duv = dv * uv;
    h0 = fmaf(__expf(dv * a0), h0, duv * Bv.x);
    h1 = fmaf(__expf(dv * a1), h1, duv * Bv.y);
    h2 = fmaf(__expf(dv * a2), h2, duv * Bv.z);
    h3 = fmaf(__expf(dv * a3), h3, duv * Bv.w);
    float yp = h0 * Cv.x + h1 * Cv.y + h2 * Cv.z + h3 * Cv.w;
    yp += quadswz<0x041F>(yp);   // xor 1 within quad
    yp += quadswz<0x081F>(yp);   // xor 2 within quad -> all 4 lanes have sum
    if ((ll & 3) == q) yk[ll >> 2] = yp;
  }
  float dsk = Dskip[d];
  bool odd = chunk & 1;
#pragma unroll
  for (int i = 0; i < 16; i++) {
    int ll = 4 * i + q;
    int wr = odd ? 63 - ll : ll;          // raster column for snake step ll
    size_t ro = baseBL + wr;              // raster row offset (hrow == chunk)
    float uvll = sU[ll][dloc];
    float zv = z[ro * DIN + d];
    yr[ro * DIN + d] = (yk[i] + uvll * dsk) * silu_f(zv);
  }
}

// ---------------------------------------------------------------------------
// Depthwise 3x3 local enhancement + residual, LDS-tiled.
// Block = (b, 4-h-row tile, 16-d group). LDS [6 h][66 w][20] (d padded).
// ---------------------------------------------------------------------------
__global__ __launch_bounds__(256) void le_conv_tiled(
    const float* __restrict__ yr, const float* __restrict__ lwT,
    float* __restrict__ y2) {
  int bid = blockIdx.x;               // ((b*16 + ht)*24 + dg)
  int dg = bid % 24;
  int ht = (bid / 24) % 16;
  int b  = bid / (24 * 16);
  int d0 = dg * 16;
  int h0 = ht * 4;
  __shared__ float S[6][66][20];
  int t = threadIdx.x;
  int dq = t & 3, w = t >> 2;
#pragma unroll
  for (int r = 0; r < 6; r++) {
    int hh = h0 - 1 + r;
    float4 v = make_float4(0.f, 0.f, 0.f, 0.f);
    if (hh >= 0 && hh < 64)
      v = *(const float4*)&yr[((size_t)((b << 12) + (hh << 6) + w)) * DIN + d0 + dq * 4];
    *(float4*)&S[r][w + 1][dq * 4] = v;
    if (w == 0)  *(float4*)&S[r][0][dq * 4]  = make_float4(0.f, 0.f, 0.f, 0.f);
    if (w == 63) *(float4*)&S[r][65][dq * 4] = make_float4(0.f, 0.f, 0.f, 0.f);
  }
  __syncthreads();
  float4 wv[9];
#pragma unroll
  for (int i = 0; i < 9; i++)
    wv[i] = *(const float4*)&lwT[i * DIN + d0 + dq * 4];
#pragma unroll
  for (int hr = 0; hr < 4; hr++) {
    float4 acc = *(float4*)&S[hr + 1][w + 1][dq * 4];   // residual
#pragma unroll
    for (int ki = 0; ki < 3; ki++)
#pragma unroll
      for (int kj = 0; kj < 3; kj++) {
        float4 v = *(float4*)&S[hr + ki][w + kj][dq * 4];
        float4 c = wv[ki * 3 + kj];
        acc.x = fmaf(v.x, c.x, acc.x);
        acc.y = fmaf(v.y, c.y, acc.y);
        acc.z = fmaf(v.z, c.z, acc.z);
        acc.w = fmaf(v.w, c.w, acc.w);
      }
    int l = ((h0 + hr) << 6) + w;
    *(float4*)&y2[((size_t)((b << 12) + l)) * DIN + d0 + dq * 4] = acc;
  }
}

// ---------------------------------------------------------------------------
extern "C" void kernel_launch(void* const* d_in, const int* in_sizes, int n_in,
                              void* d_out, int out_size, void* d_ws, size_t ws_size,
                              hipStream_t stream) {
  const float* x          = (const float*)d_in[0];
  const float* gn_gamma   = (const float*)d_in[1];
  const float* gn_beta    = (const float*)d_in[2];
  const float* in_proj_w  = (const float*)d_in[3];
  const float* conv1d_w   = (const float*)d_in[4];
  const float* conv1d_b   = (const float*)d_in[5];
  const float* x_proj_w   = (const float*)d_in[6];
  const float* dt_proj_w  = (const float*)d_in[7];
  const float* dt_proj_b  = (const float*)d_in[8];
  const float* A_log      = (const float*)d_in[9];
  const float* Dskip      = (const float*)d_in[10];
  const float* le_w       = (const float*)d_in[11];
  const float* out_proj_w = (const float*)d_in[12];
  const float* proj_out_w = (const float*)d_in[13];
  float* out = (float*)d_out;

  float* ws      = (float*)d_ws;
  float* part    = ws + WS_PART;
  float* stat    = ws + WS_STAT;
  _Float16* BfIn  = (_Float16*)(ws + WS_BFIN);
  _Float16* BfOut = (_Float16*)(ws + WS_BFOUT);
  _Float16* BfPo  = (_Float16*)(ws + WS_BFPO);
  _Float16* BfXf  = (_Float16*)(ws + WS_BFXF);
  float* lwT    = ws + WS_LWT;
  float* u      = ws + WS_BIG;
  float* zb     = u + BIGSZ;
  float* uc     = zb + BIGSZ;
  float* delta  = uc + BIGSZ;
  float* yr     = delta + BIGSZ;
  float* Bmb    = yr + BIGSZ;
  float* Cmb    = Bmb + NBL * NST;
  float* y2     = uc;      // reuse: uc dead after scan
  float* outseq = u;       // reuse: u dead after conv + scan phases
  // scan scratch aliases u (dead after conv_silu, reborn as outseq after scan)
  float* hend   = u;                         // 64*24576 = 1572864 floats
  float* Pbuf   = u + (size_t)NCHUNK * NELEM;
  float* hin    = u + 2 * (size_t)NCHUNK * NELEM;  // total 4718592 <= BIGSZ

  gn_partial<<<256, 256, 0, stream>>>(x, part);
  gn_final<<<1, 256, 0, stream>>>(part, stat);
  transpose_all<<<1694, 256, 0, stream>>>(in_proj_w, x_proj_w, dt_proj_w,
                                          out_proj_w, proj_out_w, le_w, ws);
  gemm_inproj_mfma<<<256 * 12, 256, 0, stream>>>(x, BfIn, stat, gn_gamma, gn_beta, u, zb);
  conv_silu_tiled<<<1536, 256, 0, stream>>>(u, conv1d_w, conv1d_b, uc);
  xfull_gemm<<<256 * 7, 256, 0, stream>>>(uc, BfXf, dt_proj_b, delta, Bmb, Cmb);
  scan_partial<<<1536, 256, 0, stream>>>(delta, uc, Bmb, A_log, hend, Pbuf);
  scan_combine<<<96, 256, 0, stream>>>(hend, Pbuf, hin);
  scan_final<<<1536, 256, 0, stream>>>(delta, uc, Bmb, Cmb, A_log, Dskip,
                                       zb, hin, yr);
  le_conv_tiled<<<1536, 256, 0, stream>>>(yr, lwT, y2);
  gemm_mfma<384, 192, false><<<256 * 3, 256, 0, stream>>>(y2, BfOut, outseq);
  gemm_mfma<192, 192, true><<<256 * 3, 256, 0, stream>>>(outseq, BfPo, out);
}

// Round 8
// 261.916 us; speedup vs baseline: 5.8954x; 1.0306x over previous
//
#include <hip/hip_runtime.h>
#include <cstddef>

// Problem constants
constexpr int CB  = 4;
constexpr int CC  = 192;
constexpr int CH  = 64;
constexpr int CW  = 64;
constexpr int CL  = CH * CW;        // 4096
constexpr int DIN = 384;
constexpr int NST = 16;
constexpr int DTR = 12;

constexpr int NCHUNK = 64;          // chunks per sequence (= image rows)
constexpr int NELEM  = CB * DIN * NST; // 24576 independent (b,d,n) recurrences

// Workspace layout (in floats)
constexpr int WS_PART  = 0;                          // 512
constexpr int WS_STAT  = 512;                        // 8
constexpr int WS_BFIN  = 1024;                       // 147456 f16 = 73728 fl
constexpr int WS_BFOUT = WS_BFIN + 73728;            // 73728 f16 = 36864 fl
constexpr int WS_BFPO  = WS_BFOUT + 36864;           // 36864 f16 = 18432 fl
constexpr int WS_BFXF  = WS_BFPO + 18432;            // 172032 f16 = 86016 fl
constexpr int WS_LWT   = WS_BFXF + 86016;            // 3456 fl (lwT[9][384])
constexpr int WS_BIG   = WS_LWT + 3456;              // = 219520
constexpr size_t NBL   = (size_t)CB * CL;            // 16384
constexpr size_t BIGSZ = NBL * DIN;                  // 6291456 floats

using half8 = __attribute__((ext_vector_type(8))) _Float16;
using half4 = __attribute__((ext_vector_type(4))) _Float16;
using f32x4 = __attribute__((ext_vector_type(4))) float;

__device__ __forceinline__ float sigm(float v) { return 1.f / (1.f + __expf(-v)); }
__device__ __forceinline__ float silu_f(float v) { return v * sigm(v); }
__device__ __forceinline__ float softplus_f(float v) { return v > 20.f ? v : log1pf(__expf(v)); }
template <int PAT>
__device__ __forceinline__ float quadswz(float v) {
  return __int_as_float(__builtin_amdgcn_ds_swizzle(__float_as_int(v), PAT));
}

// A-fragment index: value = A[m][k], k = ks*32 + kg*8 + j, lane = kg*16 + r16.
__device__ __forceinline__ size_t afrag_idx(int m, int k, int KS) {
  int m16 = m >> 4, r16 = m & 15;
  int ks = k >> 5, kg = (k & 31) >> 3, j = k & 7;
  return (((size_t)(m16 * KS + ks)) << 9) + (size_t)(((kg << 4) + r16) << 3) + j;
}

// ---------------------------------------------------------------------------
// GroupNorm(1, C): per-batch mean/var over C*H*W, two-stage deterministic.
// ---------------------------------------------------------------------------
__global__ __launch_bounds__(256) void gn_partial(const float* __restrict__ x,
                                                  float* __restrict__ part) {
  int b = blockIdx.x >> 6;          // 64 blocks per batch
  int chunk = blockIdx.x & 63;
  const float* px = x + (size_t)b * CC * CL + (size_t)chunk * 12288;
  float s = 0.f, s2 = 0.f;
  for (int i = threadIdx.x; i < 12288 / 4; i += 256) {
    float4 v = ((const float4*)px)[i];
    s  += v.x + v.y + v.z + v.w;
    s2 += v.x * v.x + v.y * v.y + v.z * v.z + v.w * v.w;
  }
  __shared__ float ls[4], ls2[4];
  for (int off = 32; off; off >>= 1) { s += __shfl_down(s, off); s2 += __shfl_down(s2, off); }
  int wid = threadIdx.x >> 6, lane = threadIdx.x & 63;
  if (lane == 0) { ls[wid] = s; ls2[wid] = s2; }
  __syncthreads();
  if (threadIdx.x == 0) {
    float t = 0.f, t2 = 0.f;
    for (int i = 0; i < 4; i++) { t += ls[i]; t2 += ls2[i]; }
    part[blockIdx.x * 2] = t;
    part[blockIdx.x * 2 + 1] = t2;
  }
}

__global__ __launch_bounds__(256) void gn_final(const float* __restrict__ part,
                                                float* __restrict__ stat) {
  int b = threadIdx.x >> 6;   // wave id == batch
  int i = threadIdx.x & 63;
  float s = part[(b * 64 + i) * 2];
  float s2 = part[(b * 64 + i) * 2 + 1];
  for (int off = 32; off; off >>= 1) { s += __shfl_down(s, off); s2 += __shfl_down(s2, off); }
  if (i == 0) {
    float n = (float)(CC * CL);
    float mu = s / n;
    float var = s2 / n - mu * mu;
    stat[b * 2] = mu;
    stat[b * 2 + 1] = rsqrtf(var + 1e-5f);
  }
}

// ---------------------------------------------------------------------------
// Weight prep. MFMA B-fragment layout:
//   idx = ((nt*KS + ks)*4 + colq)*512 + lane*8 + j
//   col = nt*64 + colq*16 + (lane&15); k = ks*32 + (lane>>4)*8 + j
// ---------------------------------------------------------------------------
__device__ __forceinline__ void pack_frag(_Float16* dst, int idx, int KS,
                                          const float* __restrict__ W, int KDIM) {
  int j = idx & 7, lane = (idx >> 3) & 63, colq = (idx >> 9) & 3, rest = idx >> 11;
  int ks = rest % KS, nt = rest / KS;
  int col = nt * 64 + colq * 16 + (lane & 15);
  int k = ks * 32 + ((lane >> 4) << 3) + j;
  dst[idx] = (_Float16)W[(size_t)col * KDIM + k];
}

__device__ __forceinline__ void pack_xf(_Float16* dst, int idx,
                                        const float* __restrict__ xw,
                                        const float* __restrict__ dtw) {
  int j = idx & 7, lane = (idx >> 3) & 63, colq = (idx >> 9) & 3, rest = idx >> 11;
  int ks = rest % 12, nt = rest / 12;
  int col = nt * 64 + colq * 16 + (lane & 15);
  int k = ks * 32 + ((lane >> 4) << 3) + j;
  float v = 0.f;
  if (col < 384) {
#pragma unroll
    for (int r = 0; r < 12; r++)
      v += xw[r * 384 + k] * dtw[col * 12 + r];
  } else if (col < 416) {
    v = xw[(col - 384 + 12) * 384 + k];
  }
  dst[idx] = (_Float16)v;
}

__global__ __launch_bounds__(256) void transpose_all(
    const float* __restrict__ in_proj_w, const float* __restrict__ x_proj_w,
    const float* __restrict__ dt_proj_w, const float* __restrict__ out_proj_w,
    const float* __restrict__ proj_out_w, const float* __restrict__ le_w,
    float* __restrict__ ws) {
  int idx = blockIdx.x * 256 + threadIdx.x;
  if (idx < 147456) {                 // in_proj: 768 cols x 192 k, KS=6
    pack_frag((_Float16*)(ws + WS_BFIN), idx, 6, in_proj_w, 192);
    return;
  }
  idx -= 147456;
  if (idx < 73728) {                  // out_proj: 192 cols x 384 k, KS=12
    pack_frag((_Float16*)(ws + WS_BFOUT), idx, 12, out_proj_w, 384);
    return;
  }
  idx -= 73728;
  if (idx < 36864) {                  // proj_out: 192 cols x 192 k, KS=6
    pack_frag((_Float16*)(ws + WS_BFPO), idx, 6, proj_out_w, 192);
    return;
  }
  idx -= 36864;
  if (idx < 172032) {                 // fused x_proj/dt_proj: 448 cols, KS=12
    pack_xf((_Float16*)(ws + WS_BFXF), idx, x_proj_w, dt_proj_w);
    return;
  }
  idx -= 172032;
  if (idx < 3456) {                   // lwT[t9][d] = le_w[d*9 + t9]
    int t9 = idx / 384, d = idx % 384;
    ws[WS_LWT + idx] = le_w[d * 9 + t9];
  }
}

// ---------------------------------------------------------------------------
// in_proj GEMM via fp16 MFMA: xn (GN fused on stage) @ W. M=16384, N=768,
// K=192. 64x64 tile, 4 waves (2x2), each 32x32 = 2x2 fragments.
// Epilogue routes u (snake) and z (raster).
// ---------------------------------------------------------------------------
__global__ __launch_bounds__(256) void gemm_inproj_mfma(
    const float* __restrict__ x, const _Float16* __restrict__ Bf,
    const float* __restrict__ stat, const float* __restrict__ gamma,
    const float* __restrict__ beta, float* __restrict__ u, float* __restrict__ z) {
  int mt = blockIdx.x & 255, nt = blockIdx.x >> 8;   // nt 0..11
  int m0 = mt * 64;
  int b = m0 >> 12, l0 = m0 & 4095;
  float mu = stat[b * 2], rs = stat[b * 2 + 1];
  __shared__ __align__(16) _Float16 Ah[64][200];
  int tid = threadIdx.x;
  int row = tid & 63, cq = tid >> 6;
  // Stage A (x is [c][l]-major; coalesced over l=row), fused GroupNorm.
#pragma unroll
  for (int i = 0; i < 12; i++) {
    int c0 = cq * 4 + i * 16;
    half4 h;
#pragma unroll
    for (int cc = 0; cc < 4; cc++) {
      int c = c0 + cc;
      float g = gamma[c] * rs;
      float bt = beta[c] - mu * g;
      float xv = x[((size_t)(b * 192 + c) << 12) + l0 + row];
      h[cc] = (_Float16)(xv * g + bt);
    }
    *(half4*)&Ah[row][c0] = h;
  }
  __syncthreads();
  int w = tid >> 6, lane = tid & 63;
  int wm = (w >> 1) * 32, wcol = w & 1;
  int r16 = lane & 15, kg = lane >> 4;
  f32x4 acc[2][2] = {};
#pragma unroll
  for (int ks = 0; ks < 6; ks++) {
    half8 a0 = *(const half8*)&Ah[wm + r16][ks * 32 + kg * 8];
    half8 a1 = *(const half8*)&Ah[wm + 16 + r16][ks * 32 + kg * 8];
    half8 b0 = *(const half8*)&Bf[(((size_t)(nt * 6 + ks) * 4 + wcol * 2 + 0) << 9) + lane * 8];
    half8 b1 = *(const half8*)&Bf[(((size_t)(nt * 6 + ks) * 4 + wcol * 2 + 1) << 9) + lane * 8];
    acc[0][0] = __builtin_amdgcn_mfma_f32_16x16x32_f16(a0, b0, acc[0][0], 0, 0, 0);
    acc[0][1] = __builtin_amdgcn_mfma_f32_16x16x32_f16(a0, b1, acc[0][1], 0, 0, 0);
    acc[1][0] = __builtin_amdgcn_mfma_f32_16x16x32_f16(a1, b0, acc[1][0], 0, 0, 0);
    acc[1][1] = __builtin_amdgcn_mfma_f32_16x16x32_f16(a1, b1, acc[1][1], 0, 0, 0);
  }
  int hrow = l0 >> 6;
  bool odd = hrow & 1;
#pragma unroll
  for (int mi = 0; mi < 2; mi++)
#pragma unroll
    for (int ni = 0; ni < 2; ni++)
#pragma unroll
      for (int r = 0; r < 4; r++) {
        int wloc = wm + mi * 16 + kg * 4 + r;
        int d = nt * 64 + wcol * 32 + ni * 16 + r16;
        float val = acc[mi][ni][r];
        if (d < DIN) {
          int ls = odd ? (hrow << 6) + 63 - wloc : l0 + wloc;
          u[((size_t)(b << 12) + ls) * DIN + d] = val;
        } else {
          z[((size_t)(b << 12) + l0 + wloc) * DIN + (d - DIN)] = val;
        }
      }
}

// ---------------------------------------------------------------------------
// Fused x_proj + dt_proj, LDS-free: A-frags direct from uc_h (global, L2-hot).
// Epilogue: col<384 -> delta = softplus(acc + dt_bias); 384..399 -> Bmb;
// 400..415 -> Cmb; rest pad.
// ---------------------------------------------------------------------------
__global__ __launch_bounds__(256) void xfull_direct(
    const _Float16* __restrict__ Af, const _Float16* __restrict__ Bf,
    const float* __restrict__ dt_bias, float* __restrict__ delta,
    float* __restrict__ Bmb, float* __restrict__ Cmb) {
  int mt = blockIdx.x & 255, nt = blockIdx.x >> 8;   // nt 0..6
  int m0 = mt * 64;
  int tid = threadIdx.x;
  int w = tid >> 6, lane = tid & 63;
  int wm = (w >> 1) * 32, wcol = w & 1;
  int r16 = lane & 15, kg = lane >> 4;
  int m16a = (m0 + wm) >> 4;
  f32x4 acc[2][2] = {};
#pragma unroll
  for (int ks = 0; ks < 12; ks++) {
    half8 a0 = *(const half8*)&Af[(((size_t)(m16a * 12 + ks)) << 9) + lane * 8];
    half8 a1 = *(const half8*)&Af[(((size_t)((m16a + 1) * 12 + ks)) << 9) + lane * 8];
    half8 b0 = *(const half8*)&Bf[(((size_t)(nt * 12 + ks) * 4 + wcol * 2 + 0) << 9) + lane * 8];
    half8 b1 = *(const half8*)&Bf[(((size_t)(nt * 12 + ks) * 4 + wcol * 2 + 1) << 9) + lane * 8];
    acc[0][0] = __builtin_amdgcn_mfma_f32_16x16x32_f16(a0, b0, acc[0][0], 0, 0, 0);
    acc[0][1] = __builtin_amdgcn_mfma_f32_16x16x32_f16(a0, b1, acc[0][1], 0, 0, 0);
    acc[1][0] = __builtin_amdgcn_mfma_f32_16x16x32_f16(a1, b0, acc[1][0], 0, 0, 0);
    acc[1][1] = __builtin_amdgcn_mfma_f32_16x16x32_f16(a1, b1, acc[1][1], 0, 0, 0);
  }
#pragma unroll
  for (int mi = 0; mi < 2; mi++)
#pragma unroll
    for (int ni = 0; ni < 2; ni++)
#pragma unroll
      for (int r = 0; r < 4; r++) {
        size_t m = m0 + wm + mi * 16 + kg * 4 + r;
        int gc = nt * 64 + wcol * 32 + ni * 16 + r16;
        float val = acc[mi][ni][r];
        if (gc < 384)
          delta[m * DIN + gc] = softplus_f(val + dt_bias[gc]);
        else if (gc < 400)
          Bmb[m * 16 + (gc - 384)] = val;
        else if (gc < 416)
          Cmb[m * 16 + (gc - 400)] = val;
      }
}

// ---------------------------------------------------------------------------
// out_proj, LDS-free A (y2_h frags). Epilogue restages through LDS and emits
// outseq_h in A-frag layout (KS'=6) for proj_out.
// ---------------------------------------------------------------------------
__global__ __launch_bounds__(256) void gemm_out_direct(
    const _Float16* __restrict__ Af, const _Float16* __restrict__ Bf,
    _Float16* __restrict__ outh) {
  int mt = blockIdx.x & 255, nt = blockIdx.x >> 8;   // nt 0..2
  int m0 = mt * 64;
  int tid = threadIdx.x;
  int w = tid >> 6, lane = tid & 63;
  int wm = (w >> 1) * 32, wcol = w & 1;
  int r16 = lane & 15, kg = lane >> 4;
  int m16a = (m0 + wm) >> 4;
  f32x4 acc[2][2] = {};
#pragma unroll
  for (int ks = 0; ks < 12; ks++) {
    half8 a0 = *(const half8*)&Af[(((size_t)(m16a * 12 + ks)) << 9) + lane * 8];
    half8 a1 = *(const half8*)&Af[(((size_t)((m16a + 1) * 12 + ks)) << 9) + lane * 8];
    half8 b0 = *(const half8*)&Bf[(((size_t)(nt * 12 + ks) * 4 + wcol * 2 + 0) << 9) + lane * 8];
    half8 b1 = *(const half8*)&Bf[(((size_t)(nt * 12 + ks) * 4 + wcol * 2 + 1) << 9) + lane * 8];
    acc[0][0] = __builtin_amdgcn_mfma_f32_16x16x32_f16(a0, b0, acc[0][0], 0, 0, 0);
    acc[0][1] = __builtin_amdgcn_mfma_f32_16x16x32_f16(a0, b1, acc[0][1], 0, 0, 0);
    acc[1][0] = __builtin_amdgcn_mfma_f32_16x16x32_f16(a1, b0, acc[1][0], 0, 0, 0);
    acc[1][1] = __builtin_amdgcn_mfma_f32_16x16x32_f16(a1, b1, acc[1][1], 0, 0, 0);
  }
  __shared__ float Cs[64][69];
#pragma unroll
  for (int mi = 0; mi < 2; mi++)
#pragma unroll
    for (int ni = 0; ni < 2; ni++)
#pragma unroll
      for (int r = 0; r < 4; r++)
        Cs[wm + mi * 16 + kg * 4 + r][wcol * 32 + ni * 16 + r16] = acc[mi][ni][r];
  __syncthreads();
  // emit fp16 A-frags for the next GEMM (KDIM'=192, KS'=6)
  int pair = tid >> 5, l32 = tid & 31;
  int mi2 = pair >> 1, ksl = pair & 1;
#pragma unroll
  for (int it = 0; it < 2; it++) {
    int lane2 = l32 + it * 32;
    int r16b = lane2 & 15, kgb = lane2 >> 4;
    int rowl = mi2 * 16 + r16b;
    int coll = ksl * 32 + kgb * 8;
    half8 h;
#pragma unroll
    for (int jj = 0; jj < 8; jj++) h[jj] = (_Float16)Cs[rowl][coll + jj];
    size_t m16o = (size_t)((m0 >> 4) + mi2);
    int kso = nt * 2 + ksl;
    *(half8*)&outh[((m16o * 6 + kso) << 9) + lane2 * 8] = h;
  }
}

// ---------------------------------------------------------------------------
// proj_out, LDS-free A (outseq_h frags). Transposed per-batch store to
// [B, C, 4096] via LDS.
// ---------------------------------------------------------------------------
__global__ __launch_bounds__(256) void gemm_po_direct(
    const _Float16* __restrict__ Af, const _Float16* __restrict__ Bf,
    float* __restrict__ C) {
  int mt = blockIdx.x & 255, nt = blockIdx.x >> 8;   // nt 0..2
  int m0 = mt * 64, n0 = nt * 64;
  int tid = threadIdx.x;
  int w = tid >> 6, lane = tid & 63;
  int wm = (w >> 1) * 32, wcol = w & 1;
  int r16 = lane & 15, kg = lane >> 4;
  int m16a = (m0 + wm) >> 4;
  f32x4 acc[2][2] = {};
#pragma unroll
  for (int ks = 0; ks < 6; ks++) {
    half8 a0 = *(const half8*)&Af[(((size_t)(m16a * 6 + ks)) << 9) + lane * 8];
    half8 a1 = *(const half8*)&Af[(((size_t)((m16a + 1) * 6 + ks)) << 9) + lane * 8];
    half8 b0 = *(const half8*)&Bf[(((size_t)(nt * 6 + ks) * 4 + wcol * 2 + 0) << 9) + lane * 8];
    half8 b1 = *(const half8*)&Bf[(((size_t)(nt * 6 + ks) * 4 + wcol * 2 + 1) << 9) + lane * 8];
    acc[0][0] = __builtin_amdgcn_mfma_f32_16x16x32_f16(a0, b0, acc[0][0], 0, 0, 0);
    acc[0][1] = __builtin_amdgcn_mfma_f32_16x16x32_f16(a0, b1, acc[0][1], 0, 0, 0);
    acc[1][0] = __builtin_amdgcn_mfma_f32_16x16x32_f16(a1, b0, acc[1][0], 0, 0, 0);
    acc[1][1] = __builtin_amdgcn_mfma_f32_16x16x32_f16(a1, b1, acc[1][1], 0, 0, 0);
  }
  __shared__ float Cs[64][69];
#pragma unroll
  for (int mi = 0; mi < 2; mi++)
#pragma unroll
    for (int ni = 0; ni < 2; ni++)
#pragma unroll
      for (int r = 0; r < 4; r++)
        Cs[wcol * 32 + ni * 16 + r16][wm + mi * 16 + kg * 4 + r] = acc[mi][ni][r];
  __syncthreads();
  int b = m0 >> 12, l0 = m0 & 4095;
  int li = tid & 63;
#pragma unroll
  for (int rr = 0; rr < 16; rr++) {
    int o = rr * 4 + (tid >> 6);
    C[(size_t)(b * CC + n0 + o) * CL + l0 + li] = Cs[o][li];
  }
}

// ---------------------------------------------------------------------------
// Causal depthwise conv1d (kernel 4) + SiLU, LDS-tiled. Writes fp32 uc (for
// the scan) and fp16 uc_h in MFMA A-frag layout (for xfull_direct).
// ---------------------------------------------------------------------------
__global__ __launch_bounds__(256) void conv_silu_tiled(
    const float* __restrict__ u, const float* __restrict__ cw,
    const float* __restrict__ cb, float* __restrict__ uc,
    _Float16* __restrict__ uc_h) {
  int bid = blockIdx.x;               // b*64*6
  int dg = bid % 6;
  int lt = (bid / 6) % 64;
  int b  = bid / (6 * 64);
  int d0 = dg * 64;
  int l0 = lt * 64;
  __shared__ float S[67][68];         // row = l0-3 .. l0+63; 64 d + pad
  int t = threadIdx.x;
  for (int idx = t; idx < 67 * 16; idx += 256) {
    int row = idx >> 4, c4i = idx & 15;
    int l = l0 + row - 3;
    float4 v = make_float4(0.f, 0.f, 0.f, 0.f);
    if (l >= 0)
      v = *(const float4*)&u[((size_t)((b << 12) + l)) * DIN + d0 + c4i * 4];
    *(float4*)&S[row][c4i * 4] = v;
  }
  __syncthreads();
  int c4 = t & 15, j0 = (t >> 4) << 2;     // 4 consecutive output rows
  int dd = d0 + c4 * 4;
  float4 cwv[4];
#pragma unroll
  for (int i = 0; i < 4; i++) cwv[i] = *(const float4*)&cw[(dd + i) * 4];
  float4 bias = *(const float4*)&cb[dd];
  float4 win[7];
#pragma unroll
  for (int k = 0; k < 7; k++) win[k] = *(float4*)&S[j0 + k][c4 * 4];
#pragma unroll
  for (int j = 0; j < 4; j++) {
    float4 acc = bias;
#pragma unroll
    for (int k = 0; k < 4; k++) {
      float4 v = win[j + k];
      acc.x = fmaf(v.x, ((const float*)&cwv[0])[k], acc.x);
      acc.y = fmaf(v.y, ((const float*)&cwv[1])[k], acc.y);
      acc.z = fmaf(v.z, ((const float*)&cwv[2])[k], acc.z);
      acc.w = fmaf(v.w, ((const float*)&cwv[3])[k], acc.w);
    }
    acc.x = silu_f(acc.x);
    acc.y = silu_f(acc.y);
    acc.z = silu_f(acc.z);
    acc.w = silu_f(acc.w);
    int l = l0 + j0 + j;
    int m = (b << 12) + l;
    *(float4*)&uc[(size_t)m * DIN + dd] = acc;
    half4 h;
    h[0] = (_Float16)acc.x; h[1] = (_Float16)acc.y;
    h[2] = (_Float16)acc.z; h[3] = (_Float16)acc.w;
    *(half4*)&uc_h[afrag_idx(m, dd, 12)] = h;
  }
}

// ---------------------------------------------------------------------------
// Chunked selective scan, 4 n-states per thread (see Round-2 notes).
// ---------------------------------------------------------------------------
__global__ __launch_bounds__(256) void scan_partial(
    const float* __restrict__ delta, const float* __restrict__ uc,
    const float* __restrict__ Bmb, const float* __restrict__ A_log,
    float* __restrict__ hend, float* __restrict__ Pbuf) {
  int bid = blockIdx.x;
  int chunk = bid & 63, bg = bid >> 6;
  int b = bg / 6, g = bg % 6;
  int t = threadIdx.x;
  int dloc = t >> 2, q = t & 3;
  int d = g * 64 + dloc;
  __shared__ float sD[64][64], sU[64][64], sB[64][16];
  size_t baseBL = ((size_t)b << 12) + chunk * 64;
  {
    int row = t >> 2, cg = (t & 3) * 16;
    const float* dp = &delta[(baseBL + row) * DIN + g * 64 + cg];
    const float* up = &uc[(baseBL + row) * DIN + g * 64 + cg];
#pragma unroll
    for (int c = 0; c < 4; c++) {
      *(float4*)&sD[row][cg + 4 * c] = *(const float4*)&dp[4 * c];
      *(float4*)&sU[row][cg + 4 * c] = *(const float4*)&up[4 * c];
    }
    *(float4*)&sB[row][q * 4] = *(const float4*)&Bmb[(baseBL + row) * 16 + q * 4];
  }
  __syncthreads();
  float4 av = *(const float4*)&A_log[d * 16 + 4 * q];
  float a0 = -__expf(av.x), a1 = -__expf(av.y), a2 = -__expf(av.z), a3 = -__expf(av.w);
  float h0 = 0.f, h1 = 0.f, h2 = 0.f, h3 = 0.f, sdel = 0.f;
#pragma unroll 8
  for (int ll = 0; ll < 64; ll++) {
    float dv = sD[ll][dloc];
    float uv = sU[ll][dloc];
    float4 Bv = *(const float4*)&sB[ll][q * 4];
    float duv = dv * uv;
    h0 = fmaf(__expf(dv * a0), h0, duv * Bv.x);
    h1 = fmaf(__expf(dv * a1), h1, duv * Bv.y);
    h2 = fmaf(__expf(dv * a2), h2, duv * Bv.z);
    h3 = fmaf(__expf(dv * a3), h3, duv * Bv.w);
    sdel += dv;
  }
  size_t e = ((size_t)(b * DIN + d)) * 16 + 4 * q;
  float4 hv; hv.x = h0; hv.y = h1; hv.z = h2; hv.w = h3;
  *(float4*)&hend[(size_t)chunk * NELEM + e] = hv;
  float4 pv;
  pv.x = __expf(a0 * sdel); pv.y = __expf(a1 * sdel);
  pv.z = __expf(a2 * sdel); pv.w = __expf(a3 * sdel);
  *(float4*)&Pbuf[(size_t)chunk * NELEM + e] = pv;
}

__global__ __launch_bounds__(256) void scan_combine(
    const float* __restrict__ hend, const float* __restrict__ Pbuf,
    float* __restrict__ hin) {
  int e = blockIdx.x * 256 + threadIdx.x;   // 0..24575
  float h = 0.f;
  float Pc = Pbuf[e], Hc = hend[e];
#pragma unroll 8
  for (int c = 0; c < NCHUNK; c++) {
    float Pn = 0.f, Hn = 0.f;
    if (c < NCHUNK - 1) {
      Pn = Pbuf[(size_t)(c + 1) * NELEM + e];
      Hn = hend[(size_t)(c + 1) * NELEM + e];
    }
    hin[(size_t)c * NELEM + e] = h;
    h = fmaf(Pc, h, Hc);
    Pc = Pn; Hc = Hn;
  }
}

__global__ __launch_bounds__(256) void scan_final(
    const float* __restrict__ delta, const float* __restrict__ uc,
    const float* __restrict__ Bmb, const float* __restrict__ Cmb,
    const float* __restrict__ A_log, const float* __restrict__ Dskip,
    const float* __restrict__ z, const float* __restrict__ hin,
    float* __restrict__ yr) {
  int bid = blockIdx.x;
  int chunk = bid & 63, bg = bid >> 6;
  int b = bg / 6, g = bg % 6;
  int t = threadIdx.x;
  int dloc = t >> 2, q = t & 3;
  int d = g * 64 + dloc;
  __shared__ float sD[64][64], sU[64][64], sB[64][16], sC[64][16];
  size_t baseBL = ((size_t)b << 12) + chunk * 64;
  {
    int row = t >> 2, cg = (t & 3) * 16;
    const float* dp = &delta[(baseBL + row) * DIN + g * 64 + cg];
    const float* up = &uc[(baseBL + row) * DIN + g * 64 + cg];
#pragma unroll
    for (int c = 0; c < 4; c++) {
      *(float4*)&sD[row][cg + 4 * c] = *(const float4*)&dp[4 * c];
      *(float4*)&sU[row][cg + 4 * c] = *(const float4*)&up[4 * c];
    }
    *(float4*)&sB[row][q * 4] = *(const float4*)&Bmb[(baseBL + row) * 16 + q * 4];
    *(float4*)&sC[row][q * 4] = *(const float4*)&Cmb[(baseBL + row) * 16 + q * 4];
  }
  __syncthreads();
  float4 av = *(const float4*)&A_log[d * 16 + 4 * q];
  float a0 = -__expf(av.x), a1 = -__expf(av.y), a2 = -__expf(av.z), a3 = -__expf(av.w);
  size_t e = ((size_t)(b * DIN + d)) * 16 + 4 * q;
  float4 hv = *(const float4*)&hin[(size_t)chunk * NELEM + e];
  float h0 = hv.x, h1 = hv.y, h2 = hv.z, h3 = hv.w;
  float yk[16];
#pragma unroll
  for (int ll = 0; ll < 64; ll++) {
    float dv = sD[ll][dloc];
    float uv = sU[ll][dloc];
    float4 Bv = *(const float4*)&sB[ll][q * 4];
    float4 Cv = *(const float4*)&sC[ll][q * 4];
    float duv = dv * uv;
    h0 = fmaf(__expf(dv * a0), h0, duv * Bv.x);
    h1 = fmaf(__expf(dv * a1), h1, duv * Bv.y);
    h2 = fmaf(__expf(dv * a2), h2, duv * Bv.z);
    h3 = fmaf(__expf(dv * a3), h3, duv * Bv.w);
    float yp = h0 * Cv.x + h1 * Cv.y + h2 * Cv.z + h3 * Cv.w;
    yp += quadswz<0x041F>(yp);   // xor 1 within quad
    yp += quadswz<0x081F>(yp);   // xor 2 within quad -> all 4 lanes have sum
    if ((ll & 3) == q) yk[ll >> 2] = yp;
  }
  float dsk = Dskip[d];
  bool odd = chunk & 1;
#pragma unroll
  for (int i = 0; i < 16; i++) {
    int ll = 4 * i + q;
    int wr = odd ? 63 - ll : ll;          // raster column for snake step ll
    size_t ro = baseBL + wr;              // raster row offset (hrow == chunk)
    float uvll = sU[ll][dloc];
    float zv = z[ro * DIN + d];
    yr[ro * DIN + d] = (yk[i] + uvll * dsk) * silu_f(zv);
  }
}

// ---------------------------------------------------------------------------
// Depthwise 3x3 local enhancement + residual, LDS-tiled. Emits ONLY fp16
// A-frag layout (y2_h) for out_proj. Pad 24 -> 4-way banking (was 8-way).
// ---------------------------------------------------------------------------
__global__ __launch_bounds__(256) void le_conv_tiled(
    const float* __restrict__ yr, const float* __restrict__ lwT,
    _Float16* __restrict__ y2h) {
  int bid = blockIdx.x;               // ((b*16 + ht)*24 + dg)
  int dg = bid % 24;
  int ht = (bid / 24) % 16;
  int b  = bid / (24 * 16);
  int d0 = dg * 16;
  int h0 = ht * 4;
  __shared__ float S[6][66][24];
  int t = threadIdx.x;
  int dq = t & 3, w = t >> 2;
#pragma unroll
  for (int r = 0; r < 6; r++) {
    int hh = h0 - 1 + r;
    float4 v = make_float4(0.f, 0.f, 0.f, 0.f);
    if (hh >= 0 && hh < 64)
      v = *(const float4*)&yr[((size_t)((b << 12) + (hh << 6) + w)) * DIN + d0 + dq * 4];
    *(float4*)&S[r][w + 1][dq * 4] = v;
    if (w == 0)  *(float4*)&S[r][0][dq * 4]  = make_float4(0.f, 0.f, 0.f, 0.f);
    if (w == 63) *(float4*)&S[r][65][dq * 4] = make_float4(0.f, 0.f, 0.f, 0.f);
  }
  __syncthreads();
  float4 wv[9];
#pragma unroll
  for (int i = 0; i < 9; i++)
    wv[i] = *(const float4*)&lwT[i * DIN + d0 + dq * 4];
#pragma unroll
  for (int hr = 0; hr < 4; hr++) {
    float4 acc = *(float4*)&S[hr + 1][w + 1][dq * 4];   // residual
#pragma unroll
    for (int ki = 0; ki < 3; ki++)
#pragma unroll
      for (int kj = 0; kj < 3; kj++) {
        float4 v = *(float4*)&S[hr + ki][w + kj][dq * 4];
        float4 c = wv[ki * 3 + kj];
        acc.x = fmaf(v.x, c.x, acc.x);
        acc.y = fmaf(v.y, c.y, acc.y);
        acc.z = fmaf(v.z, c.z, acc.z);
        acc.w = fmaf(v.w, c.w, acc.w);
      }
    int l = ((h0 + hr) << 6) + w;
    int m = (b << 12) + l;
    half4 h;
    h[0] = (_Float16)acc.x; h[1] = (_Float16)acc.y;
    h[2] = (_Float16)acc.z; h[3] = (_Float16)acc.w;
    *(half4*)&y2h[afrag_idx(m, d0 + dq * 4, 12)] = h;
  }
}

// ---------------------------------------------------------------------------
extern "C" void kernel_launch(void* const* d_in, const int* in_sizes, int n_in,
                              void* d_out, int out_size, void* d_ws, size_t ws_size,
                              hipStream_t stream) {
  const float* x          = (const float*)d_in[0];
  const float* gn_gamma   = (const float*)d_in[1];
  const float* gn_beta    = (const float*)d_in[2];
  const float* in_proj_w  = (const float*)d_in[3];
  const float* conv1d_w   = (const float*)d_in[4];
  const float* conv1d_b   = (const float*)d_in[5];
  const float* x_proj_w   = (const float*)d_in[6];
  const float* dt_proj_w  = (const float*)d_in[7];
  const float* dt_proj_b  = (const float*)d_in[8];
  const float* A_log      = (const float*)d_in[9];
  const float* Dskip      = (const float*)d_in[10];
  const float* le_w       = (const float*)d_in[11];
  const float* out_proj_w = (const float*)d_in[12];
  const float* proj_out_w = (const float*)d_in[13];
  float* out = (float*)d_out;

  float* ws      = (float*)d_ws;
  float* part    = ws + WS_PART;
  float* stat    = ws + WS_STAT;
  _Float16* BfIn  = (_Float16*)(ws + WS_BFIN);
  _Float16* BfOut = (_Float16*)(ws + WS_BFOUT);
  _Float16* BfPo  = (_Float16*)(ws + WS_BFPO);
  _Float16* BfXf  = (_Float16*)(ws + WS_BFXF);
  float* lwT    = ws + WS_LWT;
  float* u      = ws + WS_BIG;
  float* zb     = u + BIGSZ;
  float* uc     = zb + BIGSZ;
  float* delta  = uc + BIGSZ;
  float* yr     = delta + BIGSZ;
  float* Bmb    = yr + BIGSZ;
  float* Cmb    = Bmb + NBL * NST;
  // fp16 frag buffers aliased into temporally-dead fp32 regions:
  _Float16* uc_h = (_Float16*)yr;     // live conv_silu -> xfull (yr written later)
  _Float16* y2h  = (_Float16*)delta;  // live le_conv -> out_proj (delta dead)
  _Float16* outh = (_Float16*)zb;     // live out_proj -> proj_out (z dead)
  // scan scratch aliases u (dead after conv_silu)
  float* hend   = u;                         // 64*24576 = 1572864 floats
  float* Pbuf   = u + (size_t)NCHUNK * NELEM;
  float* hin    = u + 2 * (size_t)NCHUNK * NELEM;  // total 4718592 <= BIGSZ

  gn_partial<<<256, 256, 0, stream>>>(x, part);
  gn_final<<<1, 256, 0, stream>>>(part, stat);
  transpose_all<<<1694, 256, 0, stream>>>(in_proj_w, x_proj_w, dt_proj_w,
                                          out_proj_w, proj_out_w, le_w, ws);
  gemm_inproj_mfma<<<256 * 12, 256, 0, stream>>>(x, BfIn, stat, gn_gamma, gn_beta, u, zb);
  conv_silu_tiled<<<1536, 256, 0, stream>>>(u, conv1d_w, conv1d_b, uc, uc_h);
  xfull_direct<<<256 * 7, 256, 0, stream>>>(uc_h, BfXf, dt_proj_b, delta, Bmb, Cmb);
  scan_partial<<<1536, 256, 0, stream>>>(delta, uc, Bmb, A_log, hend, Pbuf);
  scan_combine<<<96, 256, 0, stream>>>(hend, Pbuf, hin);
  scan_final<<<1536, 256, 0, stream>>>(delta, uc, Bmb, Cmb, A_log, Dskip,
                                       zb, hin, yr);
  le_conv_tiled<<<1536, 256, 0, stream>>>(yr, lwT, y2h);
  gemm_out_direct<<<256 * 3, 256, 0, stream>>>(y2h, BfOut, outh);
  gemm_po_direct<<<256 * 3, 256, 0, stream>>>(outh, BfPo, out);
}